// Round 7
// baseline (1389.652 us; speedup 1.0000x reference)
//
#include <hip/hip_runtime.h>
#include <hip/hip_bf16.h>

typedef __hip_bfloat16 bf16;

#define NN 20000
#define EE 160000
#define ET (NN + EE)

__device__ __forceinline__ float bf2f(bf16 v){ return __bfloat162float(v); }
__device__ __forceinline__ float raw2f(unsigned short u){ return __uint_as_float(((unsigned)u) << 16); }

// dtype-generic load/store helpers
__device__ __forceinline__ void ld4(const float* p, float* d){
  float4 u = *(const float4*)p; d[0]=u.x; d[1]=u.y; d[2]=u.z; d[3]=u.w;
}
__device__ __forceinline__ void ld4(const bf16* p, float* d){
  ushort4 u = *(const ushort4*)(const void*)p;
  d[0]=raw2f(u.x); d[1]=raw2f(u.y); d[2]=raw2f(u.z); d[3]=raw2f(u.w);
}
__device__ __forceinline__ void st4(float* p, const float* v){
  *(float4*)p = make_float4(v[0],v[1],v[2],v[3]);
}
__device__ __forceinline__ void st4(bf16* p, const float* v){
  ushort4 o;
  { bf16 h=__float2bfloat16(v[0]); o.x=*(unsigned short*)&h; }
  { bf16 h=__float2bfloat16(v[1]); o.y=*(unsigned short*)&h; }
  { bf16 h=__float2bfloat16(v[2]); o.z=*(unsigned short*)&h; }
  { bf16 h=__float2bfloat16(v[3]); o.w=*(unsigned short*)&h; }
  *(ushort4*)(void*)p = o;
}
__device__ __forceinline__ float ldf(const float* p, size_t i){ return p[i]; }
__device__ __forceinline__ float ldf(const bf16* p, size_t i){ return bf2f(p[i]); }
__device__ __forceinline__ void stf(float* p, size_t i, float v){ p[i] = v; }
__device__ __forceinline__ void stf(bf16* p, size_t i, float v){ p[i] = __float2bfloat16(v); }

// ---------------- per-buffer dtype detection ----------------
struct Ptrs { const void* p[18]; int n[18]; };

__global__ void k_detect(Ptrs P, int* __restrict__ flags){
  int b = blockIdx.x;            // 0..17
  int t = threadIdx.x;           // 64
  if (b == 1){
    const int* e = (const int*)P.p[1];
    int odd = e[2*t + 1];
    unsigned long long m2 = __ballot(odd != 0);
    if (t == 0){ flags[1] = (m2 == 0ULL) ? 1 : 0; }
    return;
  }
  const unsigned* w = (const unsigned*)P.p[b];
  int nwords = P.n[b] / 2;
  unsigned v = w[t % nwords];
  int e8 = (v >> 7) & 0xFF;
  int looks = (e8 >= 100 && e8 <= 140) ? 1 : 0;
  unsigned long long mz = __ballot(v == 0u);
  unsigned long long ml = __ballot(looks);
  if (t == 0){
    int nz = __popcll(mz);
    int nonz = 64 - nz;
    int nl = __popcll(ml);
    flags[8+b] = (nonz > 0 && 2*nl >= nonz) ? 0 : 1;
  }
}

__global__ void k_cvt(const void* __restrict__ raw, bf16* __restrict__ dst, int n,
                      const int* __restrict__ flags, int fi){
  int i = blockIdx.x*256 + threadIdx.x;
  if (i >= n) return;
  if (flags[8+fi]) dst[i] = __float2bfloat16(((const float*)raw)[i]);
  else             dst[i] = ((const bf16*)raw)[i];
}

struct P13 { const void* src[13]; int off[13]; int n[13]; int fi[13]; };
__global__ void k_cvt_params(P13 p, float* __restrict__ dst, const int* __restrict__ flags){
  int b = blockIdx.x;
  const void* s = p.src[b];
  int n = p.n[b];
  float* d = dst + p.off[b];
  int f = flags[8 + p.fi[b]];
  for (int i = threadIdx.x; i < n; i += 256)
    d[i] = f ? ((const float*)s)[i] : bf2f(((const bf16*)s)[i]);
}

__global__ void k_cvte(const int* __restrict__ raw, int* __restrict__ dst,
                       const int* __restrict__ flags){
  int i = blockIdx.x*256 + threadIdx.x;
  if (i >= 2*EE) return;
  dst[i] = flags[1] ? raw[2*i] : raw[i];
}

// ---------------- CSR build (device-verified R3) ----------------
__global__ void k_init_counts(int* __restrict__ counts){
  int i = blockIdx.x*256 + threadIdx.x;
  if (i < NN) counts[i] = 1;
}

__global__ void k_hist(const int* __restrict__ ei, int* __restrict__ counts){
  int e = blockIdx.x*256 + threadIdx.x;
  if (e < EE){
    int d = ei[EE + e];
    if (d >= 0 && d < NN) atomicAdd(&counts[d], 1);
  }
}

__global__ __launch_bounds__(1024) void k_scan(const int* __restrict__ counts, int* __restrict__ rp){
  __shared__ int buf[1024];
  __shared__ int carry;
  int t = threadIdx.x;
  if (t == 0) carry = 0;
  __syncthreads();
  for (int base = 0; base < NN; base += 1024){
    int i = base + t;
    int v = (i < NN) ? counts[i] : 0;
    buf[t] = v;
    __syncthreads();
    for (int o = 1; o < 1024; o <<= 1){
      int add = (t >= o) ? buf[t - o] : 0;
      __syncthreads();
      buf[t] += add;
      __syncthreads();
    }
    if (i < NN) rp[i] = carry + buf[t] - v;
    __syncthreads();
    if (t == 0) carry += buf[1023];
    __syncthreads();
  }
  if (t == 0) rp[NN] = carry;
}

__global__ void k_selfloop(const int* __restrict__ rp, int* __restrict__ cursor, int* __restrict__ col){
  int i = blockIdx.x*256 + threadIdx.x;
  if (i < NN){ int p = rp[i]; col[p] = i; cursor[i] = p + 1; }
}

__global__ void k_scatter(const int* __restrict__ ei, int* __restrict__ cursor, int* __restrict__ col){
  int e = blockIdx.x*256 + threadIdx.x;
  if (e < EE){
    int s = ei[e], d = ei[EE + e];
    if (d >= 0 && d < NN){
      int pos = atomicAdd(&cursor[d], 1);
      col[pos] = s;
    }
  }
}

__global__ void k_zero2(float* __restrict__ a, float* __restrict__ b, int n){
  int i = blockIdx.x*256 + threadIdx.x;
  if (i < n){ a[i] = 0.f; b[i] = 0.f; }
}

// ---------------- tiled GEMM + fused fp32 es/ed ----------------
// Y[r,m] = sum_k X[r,k]*W[k,m]; es[r,h] += sum_m Y*as[m]; ed likewise (fp32 atomics).
// 64x64 tile; h = c0/C is block-uniform (C = M/H, multiple of 64).
template <typename XT, typename YT>
__global__ __launch_bounds__(256) void k_gemm(const XT* __restrict__ X, const bf16* __restrict__ W,
    YT* __restrict__ Y, const float* __restrict__ as, const float* __restrict__ ad,
    float* __restrict__ es, float* __restrict__ ed,
    int n, int K, int M, int C, int H){
  __shared__ float Xs[16][68];
  __shared__ float Ws[16][68];
  int tid = threadIdx.x;
  int tx = tid & 15, ty = tid >> 4;
  int r0 = blockIdx.x * 64, c0 = blockIdx.y * 64;
  int xr = tid >> 2;
  int xk = (tid & 3) * 4;
  int wk = tid >> 4;
  int wc = (tid & 15) * 4;
  float acc[4][4] = {{0.f,0.f,0.f,0.f},{0.f,0.f,0.f,0.f},{0.f,0.f,0.f,0.f},{0.f,0.f,0.f,0.f}};
  for (int k0 = 0; k0 < K; k0 += 16){
    int gr = r0 + xr;
    float xv[4];
    if (gr < n) ld4(X + (size_t)gr*K + k0 + xk, xv);
    else { xv[0]=xv[1]=xv[2]=xv[3]=0.f; }
    Xs[xk+0][xr]=xv[0]; Xs[xk+1][xr]=xv[1]; Xs[xk+2][xr]=xv[2]; Xs[xk+3][xr]=xv[3];
    float wv[4];
    ld4(W + (size_t)(k0+wk)*M + c0 + wc, wv);
    Ws[wk][wc+0]=wv[0]; Ws[wk][wc+1]=wv[1]; Ws[wk][wc+2]=wv[2]; Ws[wk][wc+3]=wv[3];
    __syncthreads();
    #pragma unroll
    for (int kk = 0; kk < 16; kk++){
      float a[4], b[4];
      #pragma unroll
      for (int i=0;i<4;i++) a[i] = Xs[kk][ty*4+i];
      #pragma unroll
      for (int j=0;j<4;j++) b[j] = Ws[kk][tx*4+j];
      #pragma unroll
      for (int i=0;i<4;i++)
        #pragma unroll
        for (int j=0;j<4;j++)
          acc[i][j] += a[i]*b[j];
    }
    __syncthreads();
  }
  // epilogue: store Y + fused es/ed
  int cbase = c0 + tx*4;
  float asv[4], adv[4];
  #pragma unroll
  for (int j=0;j<4;j++){ asv[j]=as[cbase+j]; adv[j]=ad[cbase+j]; }
  int h = c0 / C;
  #pragma unroll
  for (int i=0;i<4;i++){
    int row = r0 + ty*4 + i;
    if (row < n) st4(Y + (size_t)row*M + cbase, acc[i]);
    float pe = 0.f, pd = 0.f;
    #pragma unroll
    for (int j=0;j<4;j++){ pe += acc[i][j]*asv[j]; pd += acc[i][j]*adv[j]; }
    #pragma unroll
    for (int o=8;o>0;o>>=1){ pe += __shfl_xor(pe, o, 16); pd += __shfl_xor(pd, o, 16); }
    if (tx == 0 && row < n){
      atomicAdd(&es[row*H+h], pe);
      atomicAdd(&ed[row*H+h], pd);
    }
  }
}

// ---------------- per-edge alpha ----------------
__global__ void k_alpha(const int* __restrict__ rp, const int* __restrict__ col,
    const float* __restrict__ es, const float* __restrict__ ed,
    float* __restrict__ alpha, int H){
  int idx = blockIdx.x*256 + threadIdx.x;
  if (idx >= NN*H) return;
  int n = idx / H, h = idx - n*H;
  int e0 = rp[n], e1 = rp[n+1];
  float edv = ed[idx];
  float m = -1e30f;
  for (int e = e0; e < e1; e++){
    float v = es[col[e]*H + h] + edv;
    v = v > 0.f ? v : 0.2f*v;
    m = fmaxf(m, v);
  }
  float den = 0.f;
  for (int e = e0; e < e1; e++){
    float v = es[col[e]*H + h] + edv;
    v = v > 0.f ? v : 0.2f*v;
    den += __expf(v - m);
  }
  float rdv = 1.f/(den + 1e-16f);
  for (int e = e0; e < e1; e++){
    float v = es[col[e]*H + h] + edv;
    v = v > 0.f ? v : 0.2f*v;
    alpha[e*H + h] = __expf(v - m) * rdv;
  }
}

// ---------------- aggregate + bias + LN + ELU (layers 1,2) ----------------
template <typename XT, typename AT>
__global__ __launch_bounds__(256) void k_aggln(const int* __restrict__ rp, const int* __restrict__ col,
    const XT* __restrict__ xw, const float* __restrict__ alpha,
    const float* __restrict__ bias, const float* __restrict__ gam, const float* __restrict__ bet,
    AT* __restrict__ act){
  int n = blockIdx.x, t = threadIdx.x;
  __shared__ float sal[64][4];
  __shared__ int ssrc[64];
  float acc[4] = {0.f,0.f,0.f,0.f};
  int e0 = rp[n], e1 = rp[n+1];
  for (int base = e0; base < e1; base += 64){
    int cnt = min(64, e1 - base);
    if (t < cnt){
      int e = base + t;
      ssrc[t] = col[e];
      #pragma unroll
      for (int h=0;h<4;h++) sal[t][h] = alpha[e*4+h];
    }
    __syncthreads();
    for (int j = 0; j < cnt; j++){
      int s = ssrc[j];
      const XT* row = xw + (size_t)s*1024;
      #pragma unroll
      for (int h=0;h<4;h++) acc[h] += sal[j][h] * ldf(row, h*256+t);
    }
    __syncthreads();
  }
  #pragma unroll
  for (int h=0;h<4;h++) acc[h] += bias[h*256+t];
  float s1 = acc[0]+acc[1]+acc[2]+acc[3];
  float s2 = acc[0]*acc[0]+acc[1]*acc[1]+acc[2]*acc[2]+acc[3]*acc[3];
  __shared__ float ls1[256], ls2[256];
  ls1[t] = s1; ls2[t] = s2;
  __syncthreads();
  for (int o = 128; o > 0; o >>= 1){
    if (t < o){ ls1[t] += ls1[t+o]; ls2[t] += ls2[t+o]; }
    __syncthreads();
  }
  float mu  = ls1[0] * (1.f/1024.f);
  float var = ls2[0] * (1.f/1024.f) - mu*mu;
  float rstd = rsqrtf(fmaxf(var, 0.f) + 1e-5f);
  #pragma unroll
  for (int h=0;h<4;h++){
    int cc = h*256 + t;
    float v = (acc[h]-mu)*rstd*gam[cc] + bet[cc];
    v = v > 0.f ? v : (__expf(v) - 1.f);
    stf(act, (size_t)n*1024 + cc, v);
  }
}

// ---------------- layer-3 aggregate + bias -> d_out (fp32) ----------------
template <typename XT>
__global__ __launch_bounds__(256) void k_agg3(const int* __restrict__ rp, const int* __restrict__ col,
    const XT* __restrict__ xw, const float* __restrict__ alpha,
    const float* __restrict__ bias, float* __restrict__ out){
  int n = blockIdx.x, t = threadIdx.x;
  __shared__ float sal[64];
  __shared__ int ssrc[64];
  float a0 = 0.f, a1 = 0.f;
  int e0 = rp[n], e1 = rp[n+1];
  for (int base = e0; base < e1; base += 64){
    int cnt = min(64, e1 - base);
    if (t < cnt){
      int e = base + t;
      ssrc[t] = col[e];
      sal[t] = alpha[e];
    }
    __syncthreads();
    for (int j = 0; j < cnt; j++){
      int s = ssrc[j];
      const XT* row = xw + (size_t)s*512;
      float al = sal[j];
      a0 += al * ldf(row, t);
      a1 += al * ldf(row, 256 + t);
    }
    __syncthreads();
  }
  out[(size_t)n*512 + t]       = a0 + bias[t];
  out[(size_t)n*512 + 256 + t] = a1 + bias[256+t];
}

__global__ void k_wssmall(float* __restrict__ out, float code){
  if (threadIdx.x == 0) out[0] = code;
}

// ---------------- launch ----------------
extern "C" void kernel_launch(void* const* d_in, const int* in_sizes, int n_in,
                              void* d_out, int out_size, void* d_ws, size_t ws_size,
                              hipStream_t stream){
  float* out = (float*)d_out;
  char* ws = (char*)d_ws;

  static const int EXP_SZ[18] = {2560000, 320000, 131072, 1024,1024,1024,1024,1024,
                                 1048576, 1024,1024,1024,1024,1024,
                                 524288, 512,512,512};
  if (n_in != 18){ k_wssmall<<<1,64,0,stream>>>(out, 500.0f*301.0f); return; }
  for (int i = 0; i < 18; i++)
    if (in_sizes[i] != EXP_SZ[i]){ k_wssmall<<<1,64,0,stream>>>(out, 500.0f*302.0f); return; }
  if (out_size != NN*512){ k_wssmall<<<1,64,0,stream>>>(out, 500.0f*303.0f); return; }

  const size_t NEED_A = 178095488;   // fp32 intermediates
  const size_t NEED_B = 93215360;    // bf16 intermediates (verified available in R3)
  bool bigws = (ws_size >= NEED_A);
  if (ws_size < NEED_B){ k_wssmall<<<1,64,0,stream>>>(out, 500.0f*304.0f); return; }

  const int TB = 256;
  int gbN = (NN + TB - 1)/TB;
  int gbE = (EE + TB - 1)/TB;

  // common small buffers (path-dependent offsets)
  bf16 *Xc, *W1c, *W2c, *W3c;
  float *xw_f = nullptr, *act_f = nullptr;
  bf16 *xw_h = nullptr, *act_h = nullptr;
  float *prm, *es, *ed, *alpha;
  int *flags, *eic, *rp, *cur, *col;

  if (bigws){
    xw_f  = (float*)(ws);                       // 81,920,000
    act_f = (float*)(ws + 81920000);            // 81,920,000 -> 163,840,000
    Xc    = (bf16*) (ws + 163840000);           // 5,120,000  -> 168,960,000
    W1c   = (bf16*) (ws + 168960000);           // 262,144    -> 169,222,144
    W2c   = (bf16*) (ws + 169222144);           // 2,097,152  -> 171,319,296
    W3c   = (bf16*) (ws + 171319296);           // 1,048,576  -> 172,367,872
    prm   = (float*)(ws + 172367872);           // 47,104     -> 172,414,976
    flags = (int*)  (ws + 172414976);           // 256        -> 172,415,232
    eic   = (int*)  (ws + 172415232);           // 1,280,000  -> 173,695,232
    es    = (float*)(ws + 173695232);           // 320,000    -> 174,015,232
    ed    = (float*)(ws + 174015232);           // 320,000    -> 174,335,232
    rp    = (int*)  (ws + 174335232);           // 80,128     -> 174,415,360
    cur   = (int*)  (ws + 174415360);           // 80,128     -> 174,495,488
    col   = (int*)  (ws + 174495488);           // 720,000    -> 175,215,488
    alpha = (float*)(ws + 175215488);           // 2,880,000  -> 178,095,488
  } else {
    xw_h  = (bf16*) (ws);                       // 40,960,000
    act_h = (bf16*) (ws + 40960000);            // -> 81,920,000
    Xc    = (bf16*) (ws + 81920000);            // 5,120,000  -> 87,040,000
    alpha = (float*)(ws + 81920000);            // aliases Xc (Xc dead after layer-1 GEMM)
    W1c   = (bf16*) (ws + 87040000);            // -> 87,302,144
    W2c   = (bf16*) (ws + 87302144);            // -> 89,399,296
    W3c   = (bf16*) (ws + 89399296);            // -> 90,447,872
    prm   = (float*)(ws + 90447872);            // -> 90,494,976
    flags = (int*)  (ws + 90494976);            // -> 90,495,232
    eic   = (int*)  (ws + 90495232);            // -> 91,775,232
    es    = (float*)(ws + 91775232);            // -> 92,095,232
    cur   = (int*)  (ws + 91775232);            // aliases es (CSR done before es zeroed)
    ed    = (float*)(ws + 92095232);            // -> 92,415,232
    rp    = (int*)  (ws + 92415232);            // -> 92,495,360
    col   = (int*)  (ws + 92495360);            // -> 93,215,360
  }

  float *as1=prm+0, *ad1=prm+1024, *b1=prm+2048, *lg1=prm+3072, *lb1=prm+4096;
  float *as2=prm+5120, *ad2=prm+6144, *b2=prm+7168, *lg2=prm+8192, *lb2=prm+9216;
  float *as3=prm+10240, *ad3=prm+10752, *b3=prm+11264;

  // ---- detect & canonicalize ----
  {
    Ptrs P;
    for (int i=0;i<18;i++){ P.p[i]=d_in[i]; P.n[i]=in_sizes[i]; }
    k_detect<<<18, 64, 0, stream>>>(P, flags);
  }
  k_cvt<<<(NN*128+255)/256, TB, 0, stream>>>(d_in[0], Xc, NN*128, flags, 0);
  k_cvt<<<(128*1024+255)/256, TB, 0, stream>>>(d_in[2], W1c, 128*1024, flags, 2);
  k_cvt<<<(1024*1024+255)/256, TB, 0, stream>>>(d_in[8], W2c, 1024*1024, flags, 8);
  k_cvt<<<(1024*512+255)/256, TB, 0, stream>>>(d_in[14], W3c, 1024*512, flags, 14);
  {
    P13 p;
    const int idx[13] = {3,4,5,6,7, 9,10,11,12,13, 15,16,17};
    const int off[13] = {0,1024,2048,3072,4096, 5120,6144,7168,8192,9216, 10240,10752,11264};
    const int nn [13] = {1024,1024,1024,1024,1024, 1024,1024,1024,1024,1024, 512,512,512};
    for (int i=0;i<13;i++){ p.src[i]=d_in[idx[i]]; p.off[i]=off[i]; p.n[i]=nn[i]; p.fi[i]=idx[i]; }
    k_cvt_params<<<13, TB, 0, stream>>>(p, prm, flags);
  }
  k_cvte<<<(2*EE+255)/256, TB, 0, stream>>>((const int*)d_in[1], eic, flags);

  // ---- CSR ----
  k_init_counts<<<gbN, TB, 0, stream>>>(cur);
  k_hist<<<gbE, TB, 0, stream>>>(eic, cur);
  k_scan<<<1, 1024, 0, stream>>>(cur, rp);
  k_selfloop<<<gbN, TB, 0, stream>>>(rp, cur, col);
  k_scatter<<<gbE, TB, 0, stream>>>(eic, cur, col);

  dim3 g1((NN+63)/64, 1024/64);
  dim3 g3((NN+63)/64, 512/64);

  if (bigws){
    // ===== Path A: fp32 intermediates =====
    k_zero2<<<(NN*4+255)/256, TB, 0, stream>>>(es, ed, NN*4);
    k_gemm<bf16,float><<<g1, TB, 0, stream>>>(Xc, W1c, xw_f, as1, ad1, es, ed, NN, 128, 1024, 256, 4);
    k_alpha<<<(NN*4+TB-1)/TB, TB, 0, stream>>>(rp, col, es, ed, alpha, 4);
    k_aggln<float,float><<<NN, TB, 0, stream>>>(rp, col, xw_f, alpha, b1, lg1, lb1, act_f);

    k_zero2<<<(NN*4+255)/256, TB, 0, stream>>>(es, ed, NN*4);
    k_gemm<float,float><<<g1, TB, 0, stream>>>(act_f, W2c, xw_f, as2, ad2, es, ed, NN, 1024, 1024, 256, 4);
    k_alpha<<<(NN*4+TB-1)/TB, TB, 0, stream>>>(rp, col, es, ed, alpha, 4);
    k_aggln<float,float><<<NN, TB, 0, stream>>>(rp, col, xw_f, alpha, b2, lg2, lb2, act_f);

    k_zero2<<<(NN+255)/256, TB, 0, stream>>>(es, ed, NN);
    k_gemm<float,float><<<g3, TB, 0, stream>>>(act_f, W3c, xw_f, as3, ad3, es, ed, NN, 1024, 512, 512, 1);
    k_alpha<<<gbN, TB, 0, stream>>>(rp, col, es, ed, alpha, 1);
    k_agg3<float><<<NN, TB, 0, stream>>>(rp, col, xw_f, alpha, b3, out);
  } else {
    // ===== Path B: bf16 intermediates, fp32 fused logits =====
    k_zero2<<<(NN*4+255)/256, TB, 0, stream>>>(es, ed, NN*4);
    k_gemm<bf16,bf16><<<g1, TB, 0, stream>>>(Xc, W1c, xw_h, as1, ad1, es, ed, NN, 128, 1024, 256, 4);
    k_alpha<<<(NN*4+TB-1)/TB, TB, 0, stream>>>(rp, col, es, ed, alpha, 4); // overwrites Xc (dead)
    k_aggln<bf16,bf16><<<NN, TB, 0, stream>>>(rp, col, xw_h, alpha, b1, lg1, lb1, act_h);

    k_zero2<<<(NN*4+255)/256, TB, 0, stream>>>(es, ed, NN*4);
    k_gemm<bf16,bf16><<<g1, TB, 0, stream>>>(act_h, W2c, xw_h, as2, ad2, es, ed, NN, 1024, 1024, 256, 4);
    k_alpha<<<(NN*4+TB-1)/TB, TB, 0, stream>>>(rp, col, es, ed, alpha, 4);
    k_aggln<bf16,bf16><<<NN, TB, 0, stream>>>(rp, col, xw_h, alpha, b2, lg2, lb2, act_h);

    k_zero2<<<(NN+255)/256, TB, 0, stream>>>(es, ed, NN);
    k_gemm<bf16,bf16><<<g3, TB, 0, stream>>>(act_h, W3c, xw_h, as3, ad3, es, ed, NN, 1024, 512, 512, 1);
    k_alpha<<<gbN, TB, 0, stream>>>(rp, col, es, ed, alpha, 1);
    k_agg3<bf16><<<NN, TB, 0, stream>>>(rp, col, xw_h, alpha, b3, out);
  }
}

// Round 9
// 586.199 us; speedup vs baseline: 2.3706x; 2.3706x over previous
//
#include <hip/hip_runtime.h>
#include <hip/hip_bf16.h>

typedef __hip_bfloat16 bf16;
typedef __attribute__((ext_vector_type(8))) short short8;
typedef __attribute__((ext_vector_type(4))) float float4v;

#define NN 20000
#define EE 160000
#define ET (NN + EE)

__device__ __forceinline__ float bf2f(bf16 v){ return __bfloat162float(v); }
__device__ __forceinline__ float raw2f(unsigned short u){ return __uint_as_float(((unsigned)u) << 16); }

// ---------------- per-buffer dtype detection ----------------
struct Ptrs { const void* p[18]; int n[18]; };

__global__ void k_detect(Ptrs P, int* __restrict__ flags){
  int b = blockIdx.x;            // 0..17
  int t = threadIdx.x;           // 64
  if (b == 1){
    const int* e = (const int*)P.p[1];
    int odd = e[2*t + 1];
    unsigned long long m2 = __ballot(odd != 0);
    if (t == 0){ flags[1] = (m2 == 0ULL) ? 1 : 0; }
    return;
  }
  const unsigned* w = (const unsigned*)P.p[b];
  int nwords = P.n[b] / 2;
  unsigned v = w[t % nwords];
  int e8 = (v >> 7) & 0xFF;
  int looks = (e8 >= 100 && e8 <= 140) ? 1 : 0;
  unsigned long long mz = __ballot(v == 0u);
  unsigned long long ml = __ballot(looks);
  if (t == 0){
    int nz = __popcll(mz);
    int nonz = 64 - nz;
    int nl = __popcll(ml);
    flags[8+b] = (nonz > 0 && 2*nl >= nonz) ? 0 : 1;
  }
}

__global__ void k_cvt(const void* __restrict__ raw, bf16* __restrict__ dst, int n,
                      const int* __restrict__ flags, int fi){
  int i = blockIdx.x*256 + threadIdx.x;
  if (i >= n) return;
  if (flags[8+fi]) dst[i] = __float2bfloat16(((const float*)raw)[i]);
  else             dst[i] = ((const bf16*)raw)[i];
}

struct P13 { const void* src[13]; int off[13]; int n[13]; int fi[13]; };
__global__ void k_cvt_params(P13 p, float* __restrict__ dst, const int* __restrict__ flags){
  int b = blockIdx.x;
  const void* s = p.src[b];
  int n = p.n[b];
  float* d = dst + p.off[b];
  int f = flags[8 + p.fi[b]];
  for (int i = threadIdx.x; i < n; i += 256)
    d[i] = f ? ((const float*)s)[i] : bf2f(((const bf16*)s)[i]);
}

__global__ void k_cvte(const int* __restrict__ raw, int* __restrict__ dst,
                       const int* __restrict__ flags){
  int i = blockIdx.x*256 + threadIdx.x;
  if (i >= 2*EE) return;
  dst[i] = flags[1] ? raw[2*i] : raw[i];
}

// ---------------- transpose-convert W[K][M] -> Wt[M][K] bf16 ----------------
__global__ __launch_bounds__(256) void k_transpose(const void* __restrict__ raw,
    bf16* __restrict__ wt, int K, int M, const int* __restrict__ flags, int fi){
  __shared__ float tile[32][33];
  int f = flags[8+fi];
  int kb = blockIdx.y*32, mb = blockIdx.x*32;
  int tx = threadIdx.x & 31, ty = threadIdx.x >> 5;   // 32 x 8
  for (int r = 0; r < 4; r++){
    int k = kb + ty + r*8;
    int m = mb + tx;
    float v = f ? ((const float*)raw)[(size_t)k*M+m] : bf2f(((const bf16*)raw)[(size_t)k*M+m]);
    tile[ty + r*8][tx] = v;
  }
  __syncthreads();
  for (int r = 0; r < 4; r++){
    int m = mb + ty + r*8;
    int k = kb + tx;
    wt[(size_t)m*K + k] = __float2bfloat16(tile[tx][ty + r*8]);
  }
}

// ---------------- CSR build (device-verified R3) ----------------
__global__ void k_init_counts(int* __restrict__ counts){
  int i = blockIdx.x*256 + threadIdx.x;
  if (i < NN) counts[i] = 1;
}

__global__ void k_hist(const int* __restrict__ ei, int* __restrict__ counts){
  int e = blockIdx.x*256 + threadIdx.x;
  if (e < EE){
    int d = ei[EE + e];
    if (d >= 0 && d < NN) atomicAdd(&counts[d], 1);
  }
}

__global__ __launch_bounds__(1024) void k_scan(const int* __restrict__ counts, int* __restrict__ rp){
  __shared__ int buf[1024];
  __shared__ int carry;
  int t = threadIdx.x;
  if (t == 0) carry = 0;
  __syncthreads();
  for (int base = 0; base < NN; base += 1024){
    int i = base + t;
    int v = (i < NN) ? counts[i] : 0;
    buf[t] = v;
    __syncthreads();
    for (int o = 1; o < 1024; o <<= 1){
      int add = (t >= o) ? buf[t - o] : 0;
      __syncthreads();
      buf[t] += add;
      __syncthreads();
    }
    if (i < NN) rp[i] = carry + buf[t] - v;
    __syncthreads();
    if (t == 0) carry += buf[1023];
    __syncthreads();
  }
  if (t == 0) rp[NN] = carry;
}

__global__ void k_selfloop(const int* __restrict__ rp, int* __restrict__ cursor, int* __restrict__ col){
  int i = blockIdx.x*256 + threadIdx.x;
  if (i < NN){ int p = rp[i]; col[p] = i; cursor[i] = p + 1; }
}

__global__ void k_scatter(const int* __restrict__ ei, int* __restrict__ cursor, int* __restrict__ col){
  int e = blockIdx.x*256 + threadIdx.x;
  if (e < EE){
    int s = ei[e], d = ei[EE + e];
    if (d >= 0 && d < NN){
      int pos = atomicAdd(&cursor[d], 1);
      col[pos] = s;
    }
  }
}

__global__ void k_zero2(float* __restrict__ a, float* __restrict__ b, int n){
  int i = blockIdx.x*256 + threadIdx.x;
  if (i < n){ a[i] = 0.f; b[i] = 0.f; }
}

// ---------------- MFMA GEMM (m97 structure) + fused fp32 es/ed epilogue ----------------
// Y[r,m] = sum_k X[r,k]*Wt[m,k]; 128x128 tile, 4 waves (2x2 of 64x64), BK=32.
// es[r,h] += sum_m Y*as[m] (fp32, pre-rounding), likewise ed. h = c0/C block-uniform.
__global__ __launch_bounds__(256) void k_gemm_mfma(
    const bf16* __restrict__ X,    // [>=gridDim.y*128 rows][K], rows >= NN read garbage (dropped)
    const bf16* __restrict__ Wt,   // [M][K]
    bf16* __restrict__ Y,          // [NN][M]
    const float* __restrict__ as_, const float* __restrict__ ad_,
    float* __restrict__ es, float* __restrict__ ed,
    int K, int M, int C, int H)
{
  __shared__ bf16 Xs[128*32];
  __shared__ bf16 Bs[128*32];
  int tid  = threadIdx.x;
  int wave = tid >> 6, lane = tid & 63;
  int quad = lane >> 4, l15 = lane & 15;
  int c0 = blockIdx.x * 128;     // col-fastest for W L2 residency
  int r0 = blockIdx.y * 128;
  int wr = (wave >> 1) * 64;
  int wc = (wave & 1) * 64;

  float4v acc[4][4];
  #pragma unroll
  for (int i=0;i<4;i++)
    #pragma unroll
    for (int j=0;j<4;j++)
      acc[i][j] = (float4v){0.f,0.f,0.f,0.f};

  for (int k0 = 0; k0 < K; k0 += 32){
    #pragma unroll
    for (int i = 0; i < 2; i++){
      int ch = i*256 + tid;            // 512 chunks of 16B per tile
      int row = ch >> 2, kp = ch & 3;
      const bf16* gx = X  + (size_t)(r0 + row)*K + k0 + kp*8;
      const bf16* gb = Wt + (size_t)(c0 + row)*K + k0 + kp*8;
      __builtin_amdgcn_global_load_lds(
        (const __attribute__((address_space(1))) unsigned int*)gx,
        (__attribute__((address_space(3))) unsigned int*)(Xs + ch*8), 16, 0, 0);
      __builtin_amdgcn_global_load_lds(
        (const __attribute__((address_space(1))) unsigned int*)gb,
        (__attribute__((address_space(3))) unsigned int*)(Bs + ch*8), 16, 0, 0);
    }
    __syncthreads();                   // drains vmcnt before barrier (compiler-enforced)

    short8 af[4], bfr[4];
    #pragma unroll
    for (int i = 0; i < 4; i++)
      af[i]  = *(const short8*)(Xs + ((size_t)(wr + i*16 + l15))*32 + quad*8);
    #pragma unroll
    for (int j = 0; j < 4; j++)
      bfr[j] = *(const short8*)(Bs + ((size_t)(wc + j*16 + l15))*32 + quad*8);
    #pragma unroll
    for (int i = 0; i < 4; i++)
      #pragma unroll
      for (int j = 0; j < 4; j++)
        acc[i][j] = __builtin_amdgcn_mfma_f32_16x16x32_bf16(af[i], bfr[j], acc[i][j], 0, 0, 0);
    __syncthreads();
  }

  // epilogue: C/D layout col=lane&15, row=quad*4+reg [m89/m91-verified]
  int h = c0 / C;
  float asv[4], adv[4];
  #pragma unroll
  for (int j = 0; j < 4; j++){
    int colj = c0 + wc + j*16 + l15;
    asv[j] = as_[colj]; adv[j] = ad_[colj];
  }
  #pragma unroll
  for (int i = 0; i < 4; i++){
    int rbase = r0 + wr + i*16 + quad*4;
    #pragma unroll
    for (int rg = 0; rg < 4; rg++){
      int row = rbase + rg;
      bool ok = (row < NN);
      float pe = 0.f, pd = 0.f;
      #pragma unroll
      for (int j = 0; j < 4; j++){
        float v = acc[i][j][rg];
        int colj = c0 + wc + j*16 + l15;
        if (ok) Y[(size_t)row*M + colj] = __float2bfloat16(v);
        pe += v * asv[j];
        pd += v * adv[j];
      }
      #pragma unroll
      for (int o = 1; o < 16; o <<= 1){
        pe += __shfl_xor(pe, o, 64);
        pd += __shfl_xor(pd, o, 64);
      }
      if (ok && l15 == 0){
        atomicAdd(&es[row*H + h], pe);
        atomicAdd(&ed[row*H + h], pd);
      }
    }
  }
}

// ---------------- per-edge alpha ----------------
__global__ void k_alpha(const int* __restrict__ rp, const int* __restrict__ col,
    const float* __restrict__ es, const float* __restrict__ ed,
    float* __restrict__ alpha, int H){
  int idx = blockIdx.x*256 + threadIdx.x;
  if (idx >= NN*H) return;
  int n = idx / H, h = idx - n*H;
  int e0 = rp[n], e1 = rp[n+1];
  float edv = ed[idx];
  float m = -1e30f;
  for (int e = e0; e < e1; e++){
    float v = es[col[e]*H + h] + edv;
    v = v > 0.f ? v : 0.2f*v;
    m = fmaxf(m, v);
  }
  float den = 0.f;
  for (int e = e0; e < e1; e++){
    float v = es[col[e]*H + h] + edv;
    v = v > 0.f ? v : 0.2f*v;
    den += __expf(v - m);
  }
  float rdv = 1.f/(den + 1e-16f);
  for (int e = e0; e < e1; e++){
    float v = es[col[e]*H + h] + edv;
    v = v > 0.f ? v : 0.2f*v;
    alpha[e*H + h] = __expf(v - m) * rdv;
  }
}

// ---------------- aggregate + bias + LN + ELU (layers 1,2); thread owns 4 consecutive ch ----------------
__global__ __launch_bounds__(256) void k_aggln(const int* __restrict__ rp, const int* __restrict__ col,
    const bf16* __restrict__ xw, const float* __restrict__ alpha,
    const float* __restrict__ bias, const float* __restrict__ gam, const float* __restrict__ bet,
    bf16* __restrict__ act){
  int n = blockIdx.x, t = threadIdx.x;
  int h = t >> 6;                        // 4t / 256
  __shared__ float sal[64][4];
  __shared__ int ssrc[64];
  float a0=0.f, a1=0.f, a2=0.f, a3=0.f;
  int e0 = rp[n], e1 = rp[n+1];
  for (int base = e0; base < e1; base += 64){
    int cnt = min(64, e1 - base);
    if (t < cnt){
      int e = base + t;
      ssrc[t] = col[e];
      #pragma unroll
      for (int hh=0;hh<4;hh++) sal[t][hh] = alpha[e*4+hh];
    }
    __syncthreads();
    for (int j = 0; j < cnt; j++){
      int s = ssrc[j];
      float al = sal[j][h];
      ushort4 u = *(const ushort4*)((const unsigned short*)xw + (size_t)s*1024 + 4*t);
      a0 += al * raw2f(u.x);
      a1 += al * raw2f(u.y);
      a2 += al * raw2f(u.z);
      a3 += al * raw2f(u.w);
    }
    __syncthreads();
  }
  a0 += bias[4*t+0]; a1 += bias[4*t+1]; a2 += bias[4*t+2]; a3 += bias[4*t+3];
  float s1 = a0+a1+a2+a3;
  float s2 = a0*a0+a1*a1+a2*a2+a3*a3;
  __shared__ float ls1[256], ls2[256];
  ls1[t] = s1; ls2[t] = s2;
  __syncthreads();
  for (int o = 128; o > 0; o >>= 1){
    if (t < o){ ls1[t] += ls1[t+o]; ls2[t] += ls2[t+o]; }
    __syncthreads();
  }
  float mu  = ls1[0] * (1.f/1024.f);
  float var = ls2[0] * (1.f/1024.f) - mu*mu;
  float rstd = rsqrtf(fmaxf(var, 0.f) + 1e-5f);
  float v0 = (a0-mu)*rstd*gam[4*t+0] + bet[4*t+0];
  float v1 = (a1-mu)*rstd*gam[4*t+1] + bet[4*t+1];
  float v2 = (a2-mu)*rstd*gam[4*t+2] + bet[4*t+2];
  float v3 = (a3-mu)*rstd*gam[4*t+3] + bet[4*t+3];
  v0 = v0 > 0.f ? v0 : (__expf(v0)-1.f);
  v1 = v1 > 0.f ? v1 : (__expf(v1)-1.f);
  v2 = v2 > 0.f ? v2 : (__expf(v2)-1.f);
  v3 = v3 > 0.f ? v3 : (__expf(v3)-1.f);
  ushort4 o4;
  { bf16 hh=__float2bfloat16(v0); o4.x=*(unsigned short*)&hh; }
  { bf16 hh=__float2bfloat16(v1); o4.y=*(unsigned short*)&hh; }
  { bf16 hh=__float2bfloat16(v2); o4.z=*(unsigned short*)&hh; }
  { bf16 hh=__float2bfloat16(v3); o4.w=*(unsigned short*)&hh; }
  *(ushort4*)((unsigned short*)act + (size_t)n*1024 + 4*t) = o4;
}

// ---------------- layer-3 aggregate + bias -> fp32 out; thread owns 2 consecutive ch ----------------
__global__ __launch_bounds__(256) void k_agg3(const int* __restrict__ rp, const int* __restrict__ col,
    const bf16* __restrict__ xw, const float* __restrict__ alpha,
    const float* __restrict__ bias, float* __restrict__ out){
  int n = blockIdx.x, t = threadIdx.x;
  __shared__ float sal[64];
  __shared__ int ssrc[64];
  float a0 = 0.f, a1 = 0.f;
  int e0 = rp[n], e1 = rp[n+1];
  for (int base = e0; base < e1; base += 64){
    int cnt = min(64, e1 - base);
    if (t < cnt){
      int e = base + t;
      ssrc[t] = col[e];
      sal[t] = alpha[e];
    }
    __syncthreads();
    for (int j = 0; j < cnt; j++){
      int s = ssrc[j];
      float al = sal[j];
      ushort2 u = *(const ushort2*)((const unsigned short*)xw + (size_t)s*512 + 2*t);
      a0 += al * raw2f(u.x);
      a1 += al * raw2f(u.y);
    }
    __syncthreads();
  }
  out[(size_t)n*512 + 2*t]     = a0 + bias[2*t];
  out[(size_t)n*512 + 2*t + 1] = a1 + bias[2*t+1];
}

__global__ void k_wssmall(float* __restrict__ out, float code){
  if (threadIdx.x == 0) out[0] = code;
}

// ---------------- launch ----------------
extern "C" void kernel_launch(void* const* d_in, const int* in_sizes, int n_in,
                              void* d_out, int out_size, void* d_ws, size_t ws_size,
                              hipStream_t stream){
  float* out = (float*)d_out;
  char* ws = (char*)d_ws;

  static const int EXP_SZ[18] = {2560000, 320000, 131072, 1024,1024,1024,1024,1024,
                                 1048576, 1024,1024,1024,1024,1024,
                                 524288, 512,512,512};
  if (n_in != 18){ k_wssmall<<<1,64,0,stream>>>(out, 500.0f*301.0f); return; }
  for (int i = 0; i < 18; i++)
    if (in_sizes[i] != EXP_SZ[i]){ k_wssmall<<<1,64,0,stream>>>(out, 500.0f*302.0f); return; }
  if (out_size != NN*512){ k_wssmall<<<1,64,0,stream>>>(out, 500.0f*303.0f); return; }
  const size_t NEED = 93215360;
  if (ws_size < NEED){ k_wssmall<<<1,64,0,stream>>>(out, 500.0f*304.0f); return; }

  // ---- workspace layout ----
  bf16* xw    = (bf16*) (ws);                    // 40,960,000
  bf16* act   = (bf16*) (ws + 40960000);         // -> 81,920,000
  bf16* Xc    = (bf16*) (ws + 81920000);         // 5,120,000 -> 87,040,000
  float* alpha= (float*)(ws + 81920000);         // aliases Xc (Xc dead after layer-1 GEMM)
  bf16* Wt1   = (bf16*) (ws + 87040000);         // -> 87,302,144
  bf16* Wt2   = (bf16*) (ws + 87302144);         // -> 89,399,296
  bf16* Wt3   = (bf16*) (ws + 89399296);         // -> 90,447,872
  float* prm  = (float*)(ws + 90447872);         // -> 90,494,976
  int*  flags = (int*)  (ws + 90494976);         // -> 90,495,232
  int*  eic   = (int*)  (ws + 90495232);         // -> 91,775,232
  float* es   = (float*)(ws + 91775232);         // -> 92,095,232
  int*  cur   = (int*)  (ws + 91775232);         // aliases es (CSR done before es zeroed)
  float* ed   = (float*)(ws + 92095232);         // -> 92,415,232
  int*  rp    = (int*)  (ws + 92415232);         // -> 92,495,360
  int*  col   = (int*)  (ws + 92495360);         // -> 93,215,360

  float *as1=prm+0, *ad1=prm+1024, *b1=prm+2048, *lg1=prm+3072, *lb1=prm+4096;
  float *as2=prm+5120, *ad2=prm+6144, *b2=prm+7168, *lg2=prm+8192, *lb2=prm+9216;
  float *as3=prm+10240, *ad3=prm+10752, *b3=prm+11264;

  const int TB = 256;
  int gbN = (NN + TB - 1)/TB;
  int gbE = (EE + TB - 1)/TB;

  // ---- detect & canonicalize ----
  {
    Ptrs P;
    for (int i=0;i<18;i++){ P.p[i]=d_in[i]; P.n[i]=in_sizes[i]; }
    k_detect<<<18, 64, 0, stream>>>(P, flags);
  }
  k_cvt<<<(NN*128+255)/256, TB, 0, stream>>>(d_in[0], Xc, NN*128, flags, 0);
  k_transpose<<<dim3(1024/32, 128/32),  TB, 0, stream>>>(d_in[2],  Wt1, 128,  1024, flags, 2);
  k_transpose<<<dim3(1024/32, 1024/32), TB, 0, stream>>>(d_in[8],  Wt2, 1024, 1024, flags, 8);
  k_transpose<<<dim3(512/32, 1024/32),  TB, 0, stream>>>(d_in[14], Wt3, 1024, 512,  flags, 14);
  {
    P13 p;
    const int idx[13] = {3,4,5,6,7, 9,10,11,12,13, 15,16,17};
    const int off[13] = {0,1024,2048,3072,4096, 5120,6144,7168,8192,9216, 10240,10752,11264};
    const int nn [13] = {1024,1024,1024,1024,1024, 1024,1024,1024,1024,1024, 512,512,512};
    for (int i=0;i<13;i++){ p.src[i]=d_in[idx[i]]; p.off[i]=off[i]; p.n[i]=nn[i]; p.fi[i]=idx[i]; }
    k_cvt_params<<<13, TB, 0, stream>>>(p, prm, flags);
  }
  k_cvte<<<(2*EE+255)/256, TB, 0, stream>>>((const int*)d_in[1], eic, flags);

  // ---- CSR ----
  k_init_counts<<<gbN, TB, 0, stream>>>(cur);
  k_hist<<<gbE, TB, 0, stream>>>(eic, cur);
  k_scan<<<1, 1024, 0, stream>>>(cur, rp);
  k_selfloop<<<gbN, TB, 0, stream>>>(rp, cur, col);
  k_scatter<<<gbE, TB, 0, stream>>>(eic, cur, col);

  const int RB = (NN + 127)/128;                  // 157 row-bands
  dim3 g12(1024/128, RB);                         // col-fastest
  dim3 g3 (512/128,  RB);

  // ---- layer 1 (K=128) ----
  k_zero2<<<(NN*4+255)/256, TB, 0, stream>>>(es, ed, NN*4);
  k_gemm_mfma<<<g12, TB, 0, stream>>>(Xc, Wt1, xw, as1, ad1, es, ed, 128, 1024, 256, 4);
  k_alpha<<<(NN*4+TB-1)/TB, TB, 0, stream>>>(rp, col, es, ed, alpha, 4);   // overwrites Xc (dead)
  k_aggln<<<NN, TB, 0, stream>>>(rp, col, xw, alpha, b1, lg1, lb1, act);

  // ---- layer 2 (K=1024) ----
  k_zero2<<<(NN*4+255)/256, TB, 0, stream>>>(es, ed, NN*4);
  k_gemm_mfma<<<g12, TB, 0, stream>>>(act, Wt2, xw, as2, ad2, es, ed, 1024, 1024, 256, 4);
  k_alpha<<<(NN*4+TB-1)/TB, TB, 0, stream>>>(rp, col, es, ed, alpha, 4);
  k_aggln<<<NN, TB, 0, stream>>>(rp, col, xw, alpha, b2, lg2, lb2, act);

  // ---- layer 3 (K=1024, M=512) ----
  k_zero2<<<(NN+255)/256, TB, 0, stream>>>(es, ed, NN);
  k_gemm_mfma<<<g3, TB, 0, stream>>>(act, Wt3, xw, as3, ad3, es, ed, 1024, 512, 512, 1);
  k_alpha<<<gbN, TB, 0, stream>>>(rp, col, es, ed, alpha, 1);
  k_agg3<<<NN, TB, 0, stream>>>(rp, col, xw, alpha, b3, out);
}

// Round 10
// 546.288 us; speedup vs baseline: 2.5438x; 1.0731x over previous
//
#include <hip/hip_runtime.h>
#include <hip/hip_bf16.h>

typedef __hip_bfloat16 bf16;
typedef __attribute__((ext_vector_type(8))) short short8;
typedef __attribute__((ext_vector_type(4))) float float4v;

#define NN 20000
#define EE 160000
#define ET (NN + EE)

__device__ __forceinline__ float bf2f(bf16 v){ return __bfloat162float(v); }
__device__ __forceinline__ float raw2f(unsigned short u){ return __uint_as_float(((unsigned)u) << 16); }

// ---------------- per-buffer dtype detection ----------------
struct Ptrs { const void* p[18]; int n[18]; };

__global__ void k_detect(Ptrs P, int* __restrict__ flags){
  int b = blockIdx.x;            // 0..17
  int t = threadIdx.x;           // 64
  if (b == 1){
    const int* e = (const int*)P.p[1];
    int odd = e[2*t + 1];
    unsigned long long m2 = __ballot(odd != 0);
    if (t == 0){ flags[1] = (m2 == 0ULL) ? 1 : 0; }
    return;
  }
  const unsigned* w = (const unsigned*)P.p[b];
  int nwords = P.n[b] / 2;
  unsigned v = w[t % nwords];
  int e8 = (v >> 7) & 0xFF;
  int looks = (e8 >= 100 && e8 <= 140) ? 1 : 0;
  unsigned long long mz = __ballot(v == 0u);
  unsigned long long ml = __ballot(looks);
  if (t == 0){
    int nz = __popcll(mz);
    int nonz = 64 - nz;
    int nl = __popcll(ml);
    flags[8+b] = (nonz > 0 && 2*nl >= nonz) ? 0 : 1;
  }
}

// ---------------- fused preprocessing kernel ----------------
struct P13 { const void* src[13]; int off[13]; int n[13]; int fi[13]; };
struct PrepArgs {
  const void* xraw; bf16* Xc;
  const void* w1raw; bf16* Wt1;
  const void* w2raw; bf16* Wt2;
  const void* w3raw; bf16* Wt3;
  const int* eiraw; int* eic;
  P13 p13; float* prm;
  int* counts;
  const int* flags;
};

__device__ __forceinline__ void do_transpose(float (*tile)[33], const void* raw,
    bf16* wt, int K, int M, int f, int bx, int by, int t){
  int kb = by*32, mb = bx*32;
  int tx = t & 31, ty = t >> 5;   // 32 x 8
  for (int r = 0; r < 4; r++){
    int k = kb + ty + r*8;
    int m = mb + tx;
    float v = f ? ((const float*)raw)[(size_t)k*M+m] : bf2f(((const bf16*)raw)[(size_t)k*M+m]);
    tile[ty + r*8][tx] = v;
  }
  __syncthreads();
  for (int r = 0; r < 4; r++){
    int m = mb + ty + r*8;
    int k = kb + tx;
    wt[(size_t)m*K + k] = __float2bfloat16(tile[tx][ty + r*8]);
  }
}

__global__ __launch_bounds__(256) void k_prep(PrepArgs A){
  __shared__ float tile[32][33];
  int b = blockIdx.x, t = threadIdx.x;
  const int* flags = A.flags;
  if (b < 10000){                                 // cvt X -> bf16
    int i = b*256 + t;
    if (flags[8+0]) A.Xc[i] = __float2bfloat16(((const float*)A.xraw)[i]);
    else            A.Xc[i] = ((const bf16*)A.xraw)[i];
  } else if (b < 10128){                          // transpose W1 [128][1024] -> [1024][128]
    int r = b - 10000;
    do_transpose(tile, A.w1raw, A.Wt1, 128, 1024, flags[8+2], r & 31, r >> 5, t);
  } else if (b < 11152){                          // transpose W2 [1024][1024]
    int r = b - 10128;
    do_transpose(tile, A.w2raw, A.Wt2, 1024, 1024, flags[8+8], r & 31, r >> 5, t);
  } else if (b < 11664){                          // transpose W3 [1024][512] -> [512][1024]
    int r = b - 11152;
    do_transpose(tile, A.w3raw, A.Wt3, 1024, 512, flags[8+14], r & 15, r >> 4, t);
  } else if (b < 12914){                          // cvte
    int i = (b - 11664)*256 + t;
    if (i < 2*EE) A.eic[i] = flags[1] ? A.eiraw[2*i] : A.eiraw[i];
  } else if (b < 12927){                          // params -> fp32
    int pb = b - 12914;
    const void* s = A.p13.src[pb];
    int n = A.p13.n[pb];
    float* d = A.prm + A.p13.off[pb];
    int f = flags[8 + A.p13.fi[pb]];
    for (int i = t; i < n; i += 256)
      d[i] = f ? ((const float*)s)[i] : bf2f(((const bf16*)s)[i]);
  } else {                                        // init_counts
    int i = (b - 12927)*256 + t;
    if (i < NN) A.counts[i] = 1;
  }
}

// ---------------- CSR build ----------------
__global__ void k_hist(const int* __restrict__ ei, int* __restrict__ counts){
  int e = blockIdx.x*256 + threadIdx.x;
  if (e < EE){
    int d = ei[EE + e];
    if (d >= 0 && d < NN) atomicAdd(&counts[d], 1);
  }
}

__global__ __launch_bounds__(1024) void k_scan(const int* __restrict__ counts, int* __restrict__ rp){
  __shared__ int wsum[16];
  __shared__ int sc;
  int t = threadIdx.x, lane = t & 63, wv = t >> 6;
  if (t == 0) sc = 0;
  __syncthreads();
  for (int base = 0; base < NN; base += 1024){
    int i = base + t;
    int v = (i < NN) ? counts[i] : 0;
    int x = v;
    #pragma unroll
    for (int o = 1; o < 64; o <<= 1){
      int y = __shfl_up(x, o, 64);
      if (lane >= o) x += y;
    }
    if (lane == 63) wsum[wv] = x;
    __syncthreads();
    if (wv == 0 && lane < 16){
      int w = wsum[lane];
      #pragma unroll
      for (int o = 1; o < 16; o <<= 1){
        int y = __shfl_up(w, o, 16);
        if ((lane & 15) >= o) w += y;
      }
      wsum[lane] = w;
    }
    __syncthreads();
    int carry = sc;
    int wpre = (wv > 0) ? wsum[wv-1] : 0;
    if (i < NN) rp[i] = carry + wpre + x - v;     // exclusive
    __syncthreads();
    if (t == 1023) sc = carry + wsum[15];
    __syncthreads();
  }
  if (t == 0) rp[NN] = sc;
}

__global__ void k_selfloop(const int* __restrict__ rp, int* __restrict__ cursor, int* __restrict__ col){
  int i = blockIdx.x*256 + threadIdx.x;
  if (i < NN){ int p = rp[i]; col[p] = i; cursor[i] = p + 1; }
}

__global__ void k_scatter(const int* __restrict__ ei, int* __restrict__ cursor, int* __restrict__ col){
  int e = blockIdx.x*256 + threadIdx.x;
  if (e < EE){
    int s = ei[e], d = ei[EE + e];
    if (d >= 0 && d < NN){
      int pos = atomicAdd(&cursor[d], 1);
      col[pos] = s;
    }
  }
}

__global__ void k_zero2(float* __restrict__ a, float* __restrict__ b, int n){
  int i = blockIdx.x*256 + threadIdx.x;
  if (i < n){ a[i] = 0.f; b[i] = 0.f; }
}

// ---------------- MFMA GEMM (m97 structure) + fused fp32 es/ed epilogue ----------------
__global__ __launch_bounds__(256) void k_gemm_mfma(
    const bf16* __restrict__ X, const bf16* __restrict__ Wt, bf16* __restrict__ Y,
    const float* __restrict__ as_, const float* __restrict__ ad_,
    float* __restrict__ es, float* __restrict__ ed,
    int K, int M, int C, int H)
{
  __shared__ bf16 Xs[128*32];
  __shared__ bf16 Bs[128*32];
  int tid  = threadIdx.x;
  int wave = tid >> 6, lane = tid & 63;
  int quad = lane >> 4, l15 = lane & 15;
  int c0 = blockIdx.x * 128;
  int r0 = blockIdx.y * 128;
  int wr = (wave >> 1) * 64;
  int wc = (wave & 1) * 64;

  float4v acc[4][4];
  #pragma unroll
  for (int i=0;i<4;i++)
    #pragma unroll
    for (int j=0;j<4;j++)
      acc[i][j] = (float4v){0.f,0.f,0.f,0.f};

  for (int k0 = 0; k0 < K; k0 += 32){
    #pragma unroll
    for (int i = 0; i < 2; i++){
      int ch = i*256 + tid;
      int row = ch >> 2, kp = ch & 3;
      const bf16* gx = X  + (size_t)(r0 + row)*K + k0 + kp*8;
      const bf16* gb = Wt + (size_t)(c0 + row)*K + k0 + kp*8;
      __builtin_amdgcn_global_load_lds(
        (const __attribute__((address_space(1))) unsigned int*)gx,
        (__attribute__((address_space(3))) unsigned int*)(Xs + ch*8), 16, 0, 0);
      __builtin_amdgcn_global_load_lds(
        (const __attribute__((address_space(1))) unsigned int*)gb,
        (__attribute__((address_space(3))) unsigned int*)(Bs + ch*8), 16, 0, 0);
    }
    __syncthreads();

    short8 af[4], bfr[4];
    #pragma unroll
    for (int i = 0; i < 4; i++)
      af[i]  = *(const short8*)(Xs + ((size_t)(wr + i*16 + l15))*32 + quad*8);
    #pragma unroll
    for (int j = 0; j < 4; j++)
      bfr[j] = *(const short8*)(Bs + ((size_t)(wc + j*16 + l15))*32 + quad*8);
    #pragma unroll
    for (int i = 0; i < 4; i++)
      #pragma unroll
      for (int j = 0; j < 4; j++)
        acc[i][j] = __builtin_amdgcn_mfma_f32_16x16x32_bf16(af[i], bfr[j], acc[i][j], 0, 0, 0);
    __syncthreads();
  }

  int h = c0 / C;
  float asv[4], adv[4];
  #pragma unroll
  for (int j = 0; j < 4; j++){
    int colj = c0 + wc + j*16 + l15;
    asv[j] = as_[colj]; adv[j] = ad_[colj];
  }
  #pragma unroll
  for (int i = 0; i < 4; i++){
    int rbase = r0 + wr + i*16 + quad*4;
    #pragma unroll
    for (int rg = 0; rg < 4; rg++){
      int row = rbase + rg;
      bool ok = (row < NN);
      float pe = 0.f, pd = 0.f;
      #pragma unroll
      for (int j = 0; j < 4; j++){
        float v = acc[i][j][rg];
        int colj = c0 + wc + j*16 + l15;
        if (ok) Y[(size_t)row*M + colj] = __float2bfloat16(v);
        pe += v * asv[j];
        pd += v * adv[j];
      }
      #pragma unroll
      for (int o = 1; o < 16; o <<= 1){
        pe += __shfl_xor(pe, o, 64);
        pd += __shfl_xor(pd, o, 64);
      }
      if (ok && l15 == 0){
        atomicAdd(&es[row*H + h], pe);
        atomicAdd(&ed[row*H + h], pd);
      }
    }
  }
}

// ---------------- fused softmax + aggregate + bias + LN + ELU (layers 1,2; H=4) ----------------
#define DCAP 1024
__global__ __launch_bounds__(256) void k_aggln(const int* __restrict__ rp, const int* __restrict__ col,
    const bf16* __restrict__ xw, const float* __restrict__ es, const float* __restrict__ ed,
    const float* __restrict__ bias, const float* __restrict__ gam, const float* __restrict__ bet,
    bf16* __restrict__ act){
  int n = blockIdx.x, t = threadIdx.x;
  int h = t >> 6;
  __shared__ float llog[DCAP][4];
  __shared__ int ssrc[DCAP];
  __shared__ float smv[4], srd[4];
  __shared__ float ls1[256], ls2[256];
  int e0 = rp[n], e1 = rp[n+1], deg = e1 - e0;
  float4 ed4 = *(const float4*)&ed[n*4];
  float a0=0.f, a1=0.f, a2=0.f, a3=0.f;

  if (deg <= DCAP){
    // one gather pass over es; leaky into LDS
    for (int j = t; j < deg; j += 256){
      int s = col[e0 + j];
      ssrc[j] = s;
      float4 e4 = *(const float4*)&es[s*4];
      float v0 = e4.x + ed4.x; llog[j][0] = v0 > 0.f ? v0 : 0.2f*v0;
      float v1 = e4.y + ed4.y; llog[j][1] = v1 > 0.f ? v1 : 0.2f*v1;
      float v2 = e4.z + ed4.z; llog[j][2] = v2 > 0.f ? v2 : 0.2f*v2;
      float v3 = e4.w + ed4.w; llog[j][3] = v3 > 0.f ? v3 : 0.2f*v3;
    }
    __syncthreads();
    // m/den serial per head — same edge order & ops as the old k_alpha (bit-identical)
    if (t < 4){
      float m = -1e30f;
      for (int j = 0; j < deg; j++) m = fmaxf(m, llog[j][t]);
      float den = 0.f;
      for (int j = 0; j < deg; j++) den += __expf(llog[j][t] - m);
      smv[t] = m; srd[t] = 1.f/(den + 1e-16f);
    }
    __syncthreads();
    // overwrite llog with alpha
    for (int j = t; j < deg; j += 256){
      #pragma unroll
      for (int hh = 0; hh < 4; hh++)
        llog[j][hh] = __expf(llog[j][hh] - smv[hh]) * srd[hh];
    }
    __syncthreads();
    // aggregate (same edge order as before)
    for (int j = 0; j < deg; j++){
      int s = ssrc[j];
      float al = llog[j][h];
      ushort4 u = *(const ushort4*)((const unsigned short*)xw + (size_t)s*1024 + 4*t);
      a0 += al * raw2f(u.x);
      a1 += al * raw2f(u.y);
      a2 += al * raw2f(u.z);
      a3 += al * raw2f(u.w);
    }
  } else {
    // fallback (deg > 1024 — practically never): recompute gathers
    if (t < 4){
      float m = -1e30f;
      for (int e = e0; e < e1; e++){
        float v = es[col[e]*4 + t] + ed[n*4 + t];
        v = v > 0.f ? v : 0.2f*v;
        m = fmaxf(m, v);
      }
      float den = 0.f;
      for (int e = e0; e < e1; e++){
        float v = es[col[e]*4 + t] + ed[n*4 + t];
        v = v > 0.f ? v : 0.2f*v;
        den += __expf(v - m);
      }
      smv[t] = m; srd[t] = 1.f/(den + 1e-16f);
    }
    __syncthreads();
    float edh = ed[n*4 + h];
    for (int e = e0; e < e1; e++){
      int s = col[e];
      float v = es[s*4 + h] + edh;
      v = v > 0.f ? v : 0.2f*v;
      float al = __expf(v - smv[h]) * srd[h];
      ushort4 u = *(const ushort4*)((const unsigned short*)xw + (size_t)s*1024 + 4*t);
      a0 += al * raw2f(u.x);
      a1 += al * raw2f(u.y);
      a2 += al * raw2f(u.z);
      a3 += al * raw2f(u.w);
    }
  }

  a0 += bias[4*t+0]; a1 += bias[4*t+1]; a2 += bias[4*t+2]; a3 += bias[4*t+3];
  float s1 = a0+a1+a2+a3;
  float s2 = a0*a0+a1*a1+a2*a2+a3*a3;
  ls1[t] = s1; ls2[t] = s2;
  __syncthreads();
  for (int o = 128; o > 0; o >>= 1){
    if (t < o){ ls1[t] += ls1[t+o]; ls2[t] += ls2[t+o]; }
    __syncthreads();
  }
  float mu  = ls1[0] * (1.f/1024.f);
  float var = ls2[0] * (1.f/1024.f) - mu*mu;
  float rstd = rsqrtf(fmaxf(var, 0.f) + 1e-5f);
  float v0 = (a0-mu)*rstd*gam[4*t+0] + bet[4*t+0];
  float v1 = (a1-mu)*rstd*gam[4*t+1] + bet[4*t+1];
  float v2 = (a2-mu)*rstd*gam[4*t+2] + bet[4*t+2];
  float v3 = (a3-mu)*rstd*gam[4*t+3] + bet[4*t+3];
  v0 = v0 > 0.f ? v0 : (__expf(v0)-1.f);
  v1 = v1 > 0.f ? v1 : (__expf(v1)-1.f);
  v2 = v2 > 0.f ? v2 : (__expf(v2)-1.f);
  v3 = v3 > 0.f ? v3 : (__expf(v3)-1.f);
  ushort4 o4;
  { bf16 hh2=__float2bfloat16(v0); o4.x=*(unsigned short*)&hh2; }
  { bf16 hh2=__float2bfloat16(v1); o4.y=*(unsigned short*)&hh2; }
  { bf16 hh2=__float2bfloat16(v2); o4.z=*(unsigned short*)&hh2; }
  { bf16 hh2=__float2bfloat16(v3); o4.w=*(unsigned short*)&hh2; }
  *(ushort4*)((unsigned short*)act + (size_t)n*1024 + 4*t) = o4;
}

// ---------------- fused layer-3: softmax + aggregate + bias -> fp32 out (H=1) ----------------
__global__ __launch_bounds__(256) void k_agg3(const int* __restrict__ rp, const int* __restrict__ col,
    const bf16* __restrict__ xw, const float* __restrict__ es, const float* __restrict__ ed,
    const float* __restrict__ bias, float* __restrict__ out){
  int n = blockIdx.x, t = threadIdx.x;
  __shared__ float llog[DCAP];
  __shared__ int ssrc[DCAP];
  __shared__ float smv, srd;
  int e0 = rp[n], e1 = rp[n+1], deg = e1 - e0;
  float edv = ed[n];
  float a0 = 0.f, a1 = 0.f;

  if (deg <= DCAP){
    for (int j = t; j < deg; j += 256){
      int s = col[e0 + j];
      ssrc[j] = s;
      float v = es[s] + edv;
      llog[j] = v > 0.f ? v : 0.2f*v;
    }
    __syncthreads();
    if (t == 0){
      float m = -1e30f;
      for (int j = 0; j < deg; j++) m = fmaxf(m, llog[j]);
      float den = 0.f;
      for (int j = 0; j < deg; j++) den += __expf(llog[j] - m);
      smv = m; srd = 1.f/(den + 1e-16f);
    }
    __syncthreads();
    for (int j = t; j < deg; j += 256)
      llog[j] = __expf(llog[j] - smv) * srd;
    __syncthreads();
    for (int j = 0; j < deg; j++){
      int s = ssrc[j];
      float al = llog[j];
      ushort2 u = *(const ushort2*)((const unsigned short*)xw + (size_t)s*512 + 2*t);
      a0 += al * raw2f(u.x);
      a1 += al * raw2f(u.y);
    }
  } else {
    if (t == 0){
      float m = -1e30f;
      for (int e = e0; e < e1; e++){
        float v = es[col[e]] + edv;
        v = v > 0.f ? v : 0.2f*v;
        m = fmaxf(m, v);
      }
      float den = 0.f;
      for (int e = e0; e < e1; e++){
        float v = es[col[e]] + edv;
        v = v > 0.f ? v : 0.2f*v;
        den += __expf(v - m);
      }
      smv = m; srd = 1.f/(den + 1e-16f);
    }
    __syncthreads();
    for (int e = e0; e < e1; e++){
      int s = col[e];
      float v = es[s] + edv;
      v = v > 0.f ? v : 0.2f*v;
      float al = __expf(v - smv) * srd;
      ushort2 u = *(const ushort2*)((const unsigned short*)xw + (size_t)s*512 + 2*t);
      a0 += al * raw2f(u.x);
      a1 += al * raw2f(u.y);
    }
  }
  out[(size_t)n*512 + 2*t]     = a0 + bias[2*t];
  out[(size_t)n*512 + 2*t + 1] = a1 + bias[2*t+1];
}

__global__ void k_wssmall(float* __restrict__ out, float code){
  if (threadIdx.x == 0) out[0] = code;
}

// ---------------- launch ----------------
extern "C" void kernel_launch(void* const* d_in, const int* in_sizes, int n_in,
                              void* d_out, int out_size, void* d_ws, size_t ws_size,
                              hipStream_t stream){
  float* out = (float*)d_out;
  char* ws = (char*)d_ws;

  static const int EXP_SZ[18] = {2560000, 320000, 131072, 1024,1024,1024,1024,1024,
                                 1048576, 1024,1024,1024,1024,1024,
                                 524288, 512,512,512};
  if (n_in != 18){ k_wssmall<<<1,64,0,stream>>>(out, 500.0f*301.0f); return; }
  for (int i = 0; i < 18; i++)
    if (in_sizes[i] != EXP_SZ[i]){ k_wssmall<<<1,64,0,stream>>>(out, 500.0f*302.0f); return; }
  if (out_size != NN*512){ k_wssmall<<<1,64,0,stream>>>(out, 500.0f*303.0f); return; }
  const size_t NEED = 93215360;
  if (ws_size < NEED){ k_wssmall<<<1,64,0,stream>>>(out, 500.0f*304.0f); return; }

  // ---- workspace layout (same as R9) ----
  bf16* xw    = (bf16*) (ws);                    // 40,960,000
  bf16* act   = (bf16*) (ws + 40960000);         // -> 81,920,000
  bf16* Xc    = (bf16*) (ws + 81920000);         // -> 87,040,000
  bf16* Wt1   = (bf16*) (ws + 87040000);         // -> 87,302,144
  bf16* Wt2   = (bf16*) (ws + 87302144);         // -> 89,399,296
  bf16* Wt3   = (bf16*) (ws + 89399296);         // -> 90,447,872
  float* prm  = (float*)(ws + 90447872);         // -> 90,494,976
  int*  flags = (int*)  (ws + 90494976);         // -> 90,495,232
  int*  eic   = (int*)  (ws + 90495232);         // -> 91,775,232
  float* es   = (float*)(ws + 91775232);         // -> 92,095,232
  int*  cur   = (int*)  (ws + 91775232);         // aliases es (CSR done before es zeroed)
  float* ed   = (float*)(ws + 92095232);         // -> 92,415,232
  int*  rp    = (int*)  (ws + 92415232);         // -> 92,495,360
  int*  col   = (int*)  (ws + 92495360);         // -> 93,215,360

  float *as1=prm+0, *ad1=prm+1024, *b1=prm+2048, *lg1=prm+3072, *lb1=prm+4096;
  float *as2=prm+5120, *ad2=prm+6144, *b2=prm+7168, *lg2=prm+8192, *lb2=prm+9216;
  float *as3=prm+10240, *ad3=prm+10752, *b3=prm+11264;

  const int TB = 256;
  int gbN = (NN + TB - 1)/TB;
  int gbE = (EE + TB - 1)/TB;

  // ---- detect ----
  {
    Ptrs P;
    for (int i=0;i<18;i++){ P.p[i]=d_in[i]; P.n[i]=in_sizes[i]; }
    k_detect<<<18, 64, 0, stream>>>(P, flags);
  }
  // ---- fused prep ----
  {
    PrepArgs A;
    A.xraw = d_in[0]; A.Xc = Xc;
    A.w1raw = d_in[2]; A.Wt1 = Wt1;
    A.w2raw = d_in[8]; A.Wt2 = Wt2;
    A.w3raw = d_in[14]; A.Wt3 = Wt3;
    A.eiraw = (const int*)d_in[1]; A.eic = eic;
    const int idx[13] = {3,4,5,6,7, 9,10,11,12,13, 15,16,17};
    const int off[13] = {0,1024,2048,3072,4096, 5120,6144,7168,8192,9216, 10240,10752,11264};
    const int nn [13] = {1024,1024,1024,1024,1024, 1024,1024,1024,1024,1024, 512,512,512};
    for (int i=0;i<13;i++){ A.p13.src[i]=d_in[idx[i]]; A.p13.off[i]=off[i]; A.p13.n[i]=nn[i]; A.p13.fi[i]=idx[i]; }
    A.prm = prm; A.counts = cur; A.flags = flags;
    k_prep<<<13006, TB, 0, stream>>>(A);
  }

  // ---- CSR ----
  k_hist<<<gbE, TB, 0, stream>>>(eic, cur);
  k_scan<<<1, 1024, 0, stream>>>(cur, rp);
  k_selfloop<<<gbN, TB, 0, stream>>>(rp, cur, col);
  k_scatter<<<gbE, TB, 0, stream>>>(eic, cur, col);

  const int RB = (NN + 127)/128;
  dim3 g12(1024/128, RB);
  dim3 g3 (512/128,  RB);

  // ---- layer 1 (K=128) ----
  k_zero2<<<(NN*4+255)/256, TB, 0, stream>>>(es, ed, NN*4);
  k_gemm_mfma<<<g12, TB, 0, stream>>>(Xc, Wt1, xw, as1, ad1, es, ed, 128, 1024, 256, 4);
  k_aggln<<<NN, TB, 0, stream>>>(rp, col, xw, es, ed, b1, lg1, lb1, act);

  // ---- layer 2 (K=1024) ----
  k_zero2<<<(NN*4+255)/256, TB, 0, stream>>>(es, ed, NN*4);
  k_gemm_mfma<<<g12, TB, 0, stream>>>(act, Wt2, xw, as2, ad2, es, ed, 1024, 1024, 256, 4);
  k_aggln<<<NN, TB, 0, stream>>>(rp, col, xw, es, ed, b2, lg2, lb2, act);

  // ---- layer 3 (K=1024, M=512) ----
  k_zero2<<<(NN+255)/256, TB, 0, stream>>>(es, ed, NN);
  k_gemm_mfma<<<g3, TB, 0, stream>>>(act, Wt3, xw, as3, ad3, es, ed, 1024, 512, 512, 1);
  k_agg3<<<NN, TB, 0, stream>>>(rp, col, xw, es, ed, b3, out);
}

// Round 11
// 542.801 us; speedup vs baseline: 2.5602x; 1.0064x over previous
//
#include <hip/hip_runtime.h>
#include <hip/hip_bf16.h>

typedef __hip_bfloat16 bf16;
typedef __attribute__((ext_vector_type(8))) short short8;
typedef __attribute__((ext_vector_type(4))) float float4v;

#define NN 20000
#define EE 160000
#define ET (NN + EE)

__device__ __forceinline__ float bf2f(bf16 v){ return __bfloat162float(v); }
__device__ __forceinline__ float raw2f(unsigned short u){ return __uint_as_float(((unsigned)u) << 16); }

// ---------------- per-buffer dtype detection ----------------
struct Ptrs { const void* p[18]; int n[18]; };

__global__ void k_detect(Ptrs P, int* __restrict__ flags){
  int b = blockIdx.x;            // 0..17
  int t = threadIdx.x;           // 64
  if (b == 1){
    const int* e = (const int*)P.p[1];
    int odd = e[2*t + 1];
    unsigned long long m2 = __ballot(odd != 0);
    if (t == 0){ flags[1] = (m2 == 0ULL) ? 1 : 0; }
    return;
  }
  const unsigned* w = (const unsigned*)P.p[b];
  int nwords = P.n[b] / 2;
  unsigned v = w[t % nwords];
  int e8 = (v >> 7) & 0xFF;
  int looks = (e8 >= 100 && e8 <= 140) ? 1 : 0;
  unsigned long long mz = __ballot(v == 0u);
  unsigned long long ml = __ballot(looks);
  if (t == 0){
    int nz = __popcll(mz);
    int nonz = 64 - nz;
    int nl = __popcll(ml);
    flags[8+b] = (nonz > 0 && 2*nl >= nonz) ? 0 : 1;
  }
}

// ---------------- fused preprocessing kernel ----------------
struct P13 { const void* src[13]; int off[13]; int n[13]; int fi[13]; };
struct PrepArgs {
  const void* xraw; bf16* Xc;
  const void* w1raw; bf16* Wt1;
  const void* w2raw; bf16* Wt2;
  const void* w3raw; bf16* Wt3;
  const int* eiraw; int* eic;
  P13 p13; float* prm;
  int* counts;
  const int* flags;
};

__device__ __forceinline__ void do_transpose(float (*tile)[33], const void* raw,
    bf16* wt, int K, int M, int f, int bx, int by, int t){
  int kb = by*32, mb = bx*32;
  int tx = t & 31, ty = t >> 5;   // 32 x 8
  for (int r = 0; r < 4; r++){
    int k = kb + ty + r*8;
    int m = mb + tx;
    float v = f ? ((const float*)raw)[(size_t)k*M+m] : bf2f(((const bf16*)raw)[(size_t)k*M+m]);
    tile[ty + r*8][tx] = v;
  }
  __syncthreads();
  for (int r = 0; r < 4; r++){
    int m = mb + ty + r*8;
    int k = kb + tx;
    wt[(size_t)m*K + k] = __float2bfloat16(tile[tx][ty + r*8]);
  }
}

__global__ __launch_bounds__(256) void k_prep(PrepArgs A){
  __shared__ float tile[32][33];
  int b = blockIdx.x, t = threadIdx.x;
  const int* flags = A.flags;
  if (b < 10000){                                 // cvt X -> bf16
    int i = b*256 + t;
    if (flags[8+0]) A.Xc[i] = __float2bfloat16(((const float*)A.xraw)[i]);
    else            A.Xc[i] = ((const bf16*)A.xraw)[i];
  } else if (b < 10128){                          // transpose W1 [128][1024] -> [1024][128]
    int r = b - 10000;
    do_transpose(tile, A.w1raw, A.Wt1, 128, 1024, flags[8+2], r & 31, r >> 5, t);
  } else if (b < 11152){                          // transpose W2 [1024][1024]
    int r = b - 10128;
    do_transpose(tile, A.w2raw, A.Wt2, 1024, 1024, flags[8+8], r & 31, r >> 5, t);
  } else if (b < 11664){                          // transpose W3 [1024][512] -> [512][1024]
    int r = b - 11152;
    do_transpose(tile, A.w3raw, A.Wt3, 1024, 512, flags[8+14], r & 15, r >> 4, t);
  } else if (b < 12914){                          // cvte
    int i = (b - 11664)*256 + t;
    if (i < 2*EE) A.eic[i] = flags[1] ? A.eiraw[2*i] : A.eiraw[i];
  } else if (b < 12927){                          // params -> fp32
    int pb = b - 12914;
    const void* s = A.p13.src[pb];
    int n = A.p13.n[pb];
    float* d = A.prm + A.p13.off[pb];
    int f = flags[8 + A.p13.fi[pb]];
    for (int i = t; i < n; i += 256)
      d[i] = f ? ((const float*)s)[i] : bf2f(((const bf16*)s)[i]);
  } else {                                        // init_counts
    int i = (b - 12927)*256 + t;
    if (i < NN) A.counts[i] = 1;
  }
}

// ---------------- CSR build ----------------
__global__ void k_hist(const int* __restrict__ ei, int* __restrict__ counts){
  int e = blockIdx.x*256 + threadIdx.x;
  if (e < EE){
    int d = ei[EE + e];
    if (d >= 0 && d < NN) atomicAdd(&counts[d], 1);
  }
}

__global__ __launch_bounds__(1024) void k_scan(const int* __restrict__ counts, int* __restrict__ rp){
  __shared__ int wsum[16];
  __shared__ int sc;
  int t = threadIdx.x, lane = t & 63, wv = t >> 6;
  if (t == 0) sc = 0;
  __syncthreads();
  for (int base = 0; base < NN; base += 1024){
    int i = base + t;
    int v = (i < NN) ? counts[i] : 0;
    int x = v;
    #pragma unroll
    for (int o = 1; o < 64; o <<= 1){
      int y = __shfl_up(x, o, 64);
      if (lane >= o) x += y;
    }
    if (lane == 63) wsum[wv] = x;
    __syncthreads();
    if (wv == 0 && lane < 16){
      int w = wsum[lane];
      #pragma unroll
      for (int o = 1; o < 16; o <<= 1){
        int y = __shfl_up(w, o, 16);
        if ((lane & 15) >= o) w += y;
      }
      wsum[lane] = w;
    }
    __syncthreads();
    int carry = sc;
    int wpre = (wv > 0) ? wsum[wv-1] : 0;
    if (i < NN) rp[i] = carry + wpre + x - v;     // exclusive
    __syncthreads();
    if (t == 1023) sc = carry + wsum[15];
    __syncthreads();
  }
  if (t == 0) rp[NN] = sc;
}

__global__ void k_selfloop(const int* __restrict__ rp, int* __restrict__ cursor, int* __restrict__ col){
  int i = blockIdx.x*256 + threadIdx.x;
  if (i < NN){ int p = rp[i]; col[p] = i; cursor[i] = p + 1; }
}

__global__ void k_scatter(const int* __restrict__ ei, int* __restrict__ cursor, int* __restrict__ col){
  int e = blockIdx.x*256 + threadIdx.x;
  if (e < EE){
    int s = ei[e], d = ei[EE + e];
    if (d >= 0 && d < NN){
      int pos = atomicAdd(&cursor[d], 1);
      col[pos] = s;
    }
  }
}

__global__ void k_zero2(float* __restrict__ a, float* __restrict__ b, int n){
  int i = blockIdx.x*256 + threadIdx.x;
  if (i < n){ a[i] = 0.f; b[i] = 0.f; }
}

// ---------------- MFMA GEMM (m97 structure) + fused fp32 es/ed epilogue ----------------
// XCD-aware swizzle: all col-tiles of one row-band share bid%8 -> same XCD L2 caches the X band.
__global__ __launch_bounds__(256) void k_gemm_mfma(
    const bf16* __restrict__ X, const bf16* __restrict__ Wt, bf16* __restrict__ Y,
    const float* __restrict__ as_, const float* __restrict__ ad_,
    float* __restrict__ es, float* __restrict__ ed,
    int K, int M, int C, int H)
{
  __shared__ bf16 Xs[128*32];
  __shared__ bf16 Bs[128*32];
  int ncols = gridDim.x;
  int bid = blockIdx.y * ncols + blockIdx.x;     // dispatch order (x fastest)
  int xcd  = bid & 7;
  int rest = bid >> 3;
  int colb = rest % ncols;
  int rowb = xcd + 8 * (rest / ncols);
  int r0 = rowb * 128;
  if (r0 >= NN) return;                          // padded tail row-bands
  int c0 = colb * 128;

  int tid  = threadIdx.x;
  int wave = tid >> 6, lane = tid & 63;
  int quad = lane >> 4, l15 = lane & 15;
  int wr = (wave >> 1) * 64;
  int wc = (wave & 1) * 64;

  float4v acc[4][4];
  #pragma unroll
  for (int i=0;i<4;i++)
    #pragma unroll
    for (int j=0;j<4;j++)
      acc[i][j] = (float4v){0.f,0.f,0.f,0.f};

  for (int k0 = 0; k0 < K; k0 += 32){
    #pragma unroll
    for (int i = 0; i < 2; i++){
      int ch = i*256 + tid;
      int row = ch >> 2, kp = ch & 3;
      const bf16* gx = X  + (size_t)(r0 + row)*K + k0 + kp*8;
      const bf16* gb = Wt + (size_t)(c0 + row)*K + k0 + kp*8;
      __builtin_amdgcn_global_load_lds(
        (const __attribute__((address_space(1))) unsigned int*)gx,
        (__attribute__((address_space(3))) unsigned int*)(Xs + ch*8), 16, 0, 0);
      __builtin_amdgcn_global_load_lds(
        (const __attribute__((address_space(1))) unsigned int*)gb,
        (__attribute__((address_space(3))) unsigned int*)(Bs + ch*8), 16, 0, 0);
    }
    __syncthreads();

    short8 af[4], bfr[4];
    #pragma unroll
    for (int i = 0; i < 4; i++)
      af[i]  = *(const short8*)(Xs + ((size_t)(wr + i*16 + l15))*32 + quad*8);
    #pragma unroll
    for (int j = 0; j < 4; j++)
      bfr[j] = *(const short8*)(Bs + ((size_t)(wc + j*16 + l15))*32 + quad*8);
    #pragma unroll
    for (int i = 0; i < 4; i++)
      #pragma unroll
      for (int j = 0; j < 4; j++)
        acc[i][j] = __builtin_amdgcn_mfma_f32_16x16x32_bf16(af[i], bfr[j], acc[i][j], 0, 0, 0);
    __syncthreads();
  }

  int h = c0 / C;
  float asv[4], adv[4];
  #pragma unroll
  for (int j = 0; j < 4; j++){
    int colj = c0 + wc + j*16 + l15;
    asv[j] = as_[colj]; adv[j] = ad_[colj];
  }
  #pragma unroll
  for (int i = 0; i < 4; i++){
    int rbase = r0 + wr + i*16 + quad*4;
    #pragma unroll
    for (int rg = 0; rg < 4; rg++){
      int row = rbase + rg;
      bool ok = (row < NN);
      float pe = 0.f, pd = 0.f;
      #pragma unroll
      for (int j = 0; j < 4; j++){
        float v = acc[i][j][rg];
        int colj = c0 + wc + j*16 + l15;
        if (ok) Y[(size_t)row*M + colj] = __float2bfloat16(v);
        pe += v * asv[j];
        pd += v * adv[j];
      }
      #pragma unroll
      for (int o = 1; o < 16; o <<= 1){
        pe += __shfl_xor(pe, o, 64);
        pd += __shfl_xor(pd, o, 64);
      }
      if (ok && l15 == 0){
        atomicAdd(&es[row*H + h], pe);
        atomicAdd(&ed[row*H + h], pd);
      }
    }
  }
}

// ---------------- fused softmax + aggregate + bias + LN + ELU (layers 1,2; H=4) ----------------
#define DCAP 1024
__global__ __launch_bounds__(256) void k_aggln(const int* __restrict__ rp, const int* __restrict__ col,
    const bf16* __restrict__ xw, const float* __restrict__ es, const float* __restrict__ ed,
    const float* __restrict__ bias, const float* __restrict__ gam, const float* __restrict__ bet,
    bf16* __restrict__ act){
  int n = blockIdx.x, t = threadIdx.x;
  int h = t >> 6;
  __shared__ float llog[DCAP][4];
  __shared__ int ssrc[DCAP];
  __shared__ float smv[4], srd[4];
  __shared__ float ls1[256], ls2[256];
  int e0 = rp[n], e1 = rp[n+1], deg = e1 - e0;
  float4 ed4 = *(const float4*)&ed[n*4];
  float a0=0.f, a1=0.f, a2=0.f, a3=0.f;
  const unsigned short* xwu = (const unsigned short*)xw;

  if (deg <= DCAP){
    for (int j = t; j < deg; j += 256){
      int s = col[e0 + j];
      ssrc[j] = s;
      float4 e4 = *(const float4*)&es[s*4];
      float v0 = e4.x + ed4.x; llog[j][0] = v0 > 0.f ? v0 : 0.2f*v0;
      float v1 = e4.y + ed4.y; llog[j][1] = v1 > 0.f ? v1 : 0.2f*v1;
      float v2 = e4.z + ed4.z; llog[j][2] = v2 > 0.f ? v2 : 0.2f*v2;
      float v3 = e4.w + ed4.w; llog[j][3] = v3 > 0.f ? v3 : 0.2f*v3;
    }
    __syncthreads();
    if (t < 4){
      float m = -1e30f;
      for (int j = 0; j < deg; j++) m = fmaxf(m, llog[j][t]);
      float den = 0.f;
      for (int j = 0; j < deg; j++) den += __expf(llog[j][t] - m);
      smv[t] = m; srd[t] = 1.f/(den + 1e-16f);
    }
    __syncthreads();
    for (int j = t; j < deg; j += 256){
      #pragma unroll
      for (int hh = 0; hh < 4; hh++)
        llog[j][hh] = __expf(llog[j][hh] - smv[hh]) * srd[hh];
    }
    __syncthreads();
    // aggregate, unroll-4 (FMA order identical to serial loop)
    int j = 0;
    for (; j + 4 <= deg; j += 4){
      int s0=ssrc[j], s1=ssrc[j+1], s2=ssrc[j+2], s3=ssrc[j+3];
      float al0=llog[j][h], al1=llog[j+1][h], al2=llog[j+2][h], al3=llog[j+3][h];
      ushort4 u0 = *(const ushort4*)(xwu + (size_t)s0*1024 + 4*t);
      ushort4 u1 = *(const ushort4*)(xwu + (size_t)s1*1024 + 4*t);
      ushort4 u2 = *(const ushort4*)(xwu + (size_t)s2*1024 + 4*t);
      ushort4 u3 = *(const ushort4*)(xwu + (size_t)s3*1024 + 4*t);
      a0 += al0*raw2f(u0.x); a1 += al0*raw2f(u0.y); a2 += al0*raw2f(u0.z); a3 += al0*raw2f(u0.w);
      a0 += al1*raw2f(u1.x); a1 += al1*raw2f(u1.y); a2 += al1*raw2f(u1.z); a3 += al1*raw2f(u1.w);
      a0 += al2*raw2f(u2.x); a1 += al2*raw2f(u2.y); a2 += al2*raw2f(u2.z); a3 += al2*raw2f(u2.w);
      a0 += al3*raw2f(u3.x); a1 += al3*raw2f(u3.y); a2 += al3*raw2f(u3.z); a3 += al3*raw2f(u3.w);
    }
    for (; j < deg; j++){
      int s = ssrc[j];
      float al = llog[j][h];
      ushort4 u = *(const ushort4*)(xwu + (size_t)s*1024 + 4*t);
      a0 += al*raw2f(u.x); a1 += al*raw2f(u.y); a2 += al*raw2f(u.z); a3 += al*raw2f(u.w);
    }
  } else {
    if (t < 4){
      float m = -1e30f;
      for (int e = e0; e < e1; e++){
        float v = es[col[e]*4 + t] + ed[n*4 + t];
        v = v > 0.f ? v : 0.2f*v;
        m = fmaxf(m, v);
      }
      float den = 0.f;
      for (int e = e0; e < e1; e++){
        float v = es[col[e]*4 + t] + ed[n*4 + t];
        v = v > 0.f ? v : 0.2f*v;
        den += __expf(v - m);
      }
      smv[t] = m; srd[t] = 1.f/(den + 1e-16f);
    }
    __syncthreads();
    float edh = ed[n*4 + h];
    for (int e = e0; e < e1; e++){
      int s = col[e];
      float v = es[s*4 + h] + edh;
      v = v > 0.f ? v : 0.2f*v;
      float al = __expf(v - smv[h]) * srd[h];
      ushort4 u = *(const ushort4*)(xwu + (size_t)s*1024 + 4*t);
      a0 += al*raw2f(u.x); a1 += al*raw2f(u.y); a2 += al*raw2f(u.z); a3 += al*raw2f(u.w);
    }
  }

  a0 += bias[4*t+0]; a1 += bias[4*t+1]; a2 += bias[4*t+2]; a3 += bias[4*t+3];
  float s1 = a0+a1+a2+a3;
  float s2 = a0*a0+a1*a1+a2*a2+a3*a3;
  ls1[t] = s1; ls2[t] = s2;
  __syncthreads();
  for (int o = 128; o > 0; o >>= 1){
    if (t < o){ ls1[t] += ls1[t+o]; ls2[t] += ls2[t+o]; }
    __syncthreads();
  }
  float mu  = ls1[0] * (1.f/1024.f);
  float var = ls2[0] * (1.f/1024.f) - mu*mu;
  float rstd = rsqrtf(fmaxf(var, 0.f) + 1e-5f);
  float v0 = (a0-mu)*rstd*gam[4*t+0] + bet[4*t+0];
  float v1 = (a1-mu)*rstd*gam[4*t+1] + bet[4*t+1];
  float v2 = (a2-mu)*rstd*gam[4*t+2] + bet[4*t+2];
  float v3 = (a3-mu)*rstd*gam[4*t+3] + bet[4*t+3];
  v0 = v0 > 0.f ? v0 : (__expf(v0)-1.f);
  v1 = v1 > 0.f ? v1 : (__expf(v1)-1.f);
  v2 = v2 > 0.f ? v2 : (__expf(v2)-1.f);
  v3 = v3 > 0.f ? v3 : (__expf(v3)-1.f);
  ushort4 o4;
  { bf16 hh2=__float2bfloat16(v0); o4.x=*(unsigned short*)&hh2; }
  { bf16 hh2=__float2bfloat16(v1); o4.y=*(unsigned short*)&hh2; }
  { bf16 hh2=__float2bfloat16(v2); o4.z=*(unsigned short*)&hh2; }
  { bf16 hh2=__float2bfloat16(v3); o4.w=*(unsigned short*)&hh2; }
  *(ushort4*)((unsigned short*)act + (size_t)n*1024 + 4*t) = o4;
}

// ---------------- fused layer-3: softmax + aggregate + bias -> fp32 out (H=1) ----------------
__global__ __launch_bounds__(256) void k_agg3(const int* __restrict__ rp, const int* __restrict__ col,
    const bf16* __restrict__ xw, const float* __restrict__ es, const float* __restrict__ ed,
    const float* __restrict__ bias, float* __restrict__ out){
  int n = blockIdx.x, t = threadIdx.x;
  __shared__ float llog[DCAP];
  __shared__ int ssrc[DCAP];
  __shared__ float smv, srd;
  int e0 = rp[n], e1 = rp[n+1], deg = e1 - e0;
  float edv = ed[n];
  float a0 = 0.f, a1 = 0.f;
  const unsigned short* xwu = (const unsigned short*)xw;

  if (deg <= DCAP){
    for (int j = t; j < deg; j += 256){
      int s = col[e0 + j];
      ssrc[j] = s;
      float v = es[s] + edv;
      llog[j] = v > 0.f ? v : 0.2f*v;
    }
    __syncthreads();
    if (t == 0){
      float m = -1e30f;
      for (int j = 0; j < deg; j++) m = fmaxf(m, llog[j]);
      float den = 0.f;
      for (int j = 0; j < deg; j++) den += __expf(llog[j] - m);
      smv = m; srd = 1.f/(den + 1e-16f);
    }
    __syncthreads();
    for (int j = t; j < deg; j += 256)
      llog[j] = __expf(llog[j] - smv) * srd;
    __syncthreads();
    int j = 0;
    for (; j + 4 <= deg; j += 4){
      int s0=ssrc[j], s1=ssrc[j+1], s2=ssrc[j+2], s3=ssrc[j+3];
      float al0=llog[j], al1=llog[j+1], al2=llog[j+2], al3=llog[j+3];
      ushort2 u0 = *(const ushort2*)(xwu + (size_t)s0*512 + 2*t);
      ushort2 u1 = *(const ushort2*)(xwu + (size_t)s1*512 + 2*t);
      ushort2 u2 = *(const ushort2*)(xwu + (size_t)s2*512 + 2*t);
      ushort2 u3 = *(const ushort2*)(xwu + (size_t)s3*512 + 2*t);
      a0 += al0*raw2f(u0.x); a1 += al0*raw2f(u0.y);
      a0 += al1*raw2f(u1.x); a1 += al1*raw2f(u1.y);
      a0 += al2*raw2f(u2.x); a1 += al2*raw2f(u2.y);
      a0 += al3*raw2f(u3.x); a1 += al3*raw2f(u3.y);
    }
    for (; j < deg; j++){
      int s = ssrc[j];
      float al = llog[j];
      ushort2 u = *(const ushort2*)(xwu + (size_t)s*512 + 2*t);
      a0 += al*raw2f(u.x); a1 += al*raw2f(u.y);
    }
  } else {
    if (t == 0){
      float m = -1e30f;
      for (int e = e0; e < e1; e++){
        float v = es[col[e]] + edv;
        v = v > 0.f ? v : 0.2f*v;
        m = fmaxf(m, v);
      }
      float den = 0.f;
      for (int e = e0; e < e1; e++){
        float v = es[col[e]] + edv;
        v = v > 0.f ? v : 0.2f*v;
        den += __expf(v - m);
      }
      smv = m; srd = 1.f/(den + 1e-16f);
    }
    __syncthreads();
    for (int e = e0; e < e1; e++){
      int s = col[e];
      float v = es[s] + edv;
      v = v > 0.f ? v : 0.2f*v;
      float al = __expf(v - smv) * srd;
      ushort2 u = *(const ushort2*)(xwu + (size_t)s*512 + 2*t);
      a0 += al*raw2f(u.x); a1 += al*raw2f(u.y);
    }
  }
  out[(size_t)n*512 + 2*t]     = a0 + bias[2*t];
  out[(size_t)n*512 + 2*t + 1] = a1 + bias[2*t+1];
}

__global__ void k_wssmall(float* __restrict__ out, float code){
  if (threadIdx.x == 0) out[0] = code;
}

// ---------------- launch ----------------
extern "C" void kernel_launch(void* const* d_in, const int* in_sizes, int n_in,
                              void* d_out, int out_size, void* d_ws, size_t ws_size,
                              hipStream_t stream){
  float* out = (float*)d_out;
  char* ws = (char*)d_ws;

  static const int EXP_SZ[18] = {2560000, 320000, 131072, 1024,1024,1024,1024,1024,
                                 1048576, 1024,1024,1024,1024,1024,
                                 524288, 512,512,512};
  if (n_in != 18){ k_wssmall<<<1,64,0,stream>>>(out, 500.0f*301.0f); return; }
  for (int i = 0; i < 18; i++)
    if (in_sizes[i] != EXP_SZ[i]){ k_wssmall<<<1,64,0,stream>>>(out, 500.0f*302.0f); return; }
  if (out_size != NN*512){ k_wssmall<<<1,64,0,stream>>>(out, 500.0f*303.0f); return; }
  const size_t NEED = 93215360;
  if (ws_size < NEED){ k_wssmall<<<1,64,0,stream>>>(out, 500.0f*304.0f); return; }

  // ---- workspace layout ----
  bf16* xw    = (bf16*) (ws);                    // 40,960,000
  bf16* act   = (bf16*) (ws + 40960000);         // -> 81,920,000
  bf16* Xc    = (bf16*) (ws + 81920000);         // -> 87,040,000
  bf16* Wt1   = (bf16*) (ws + 87040000);         // -> 87,302,144
  bf16* Wt2   = (bf16*) (ws + 87302144);         // -> 89,399,296
  bf16* Wt3   = (bf16*) (ws + 89399296);         // -> 90,447,872
  float* prm  = (float*)(ws + 90447872);         // -> 90,494,976
  int*  flags = (int*)  (ws + 90494976);         // -> 90,495,232
  int*  eic   = (int*)  (ws + 90495232);         // -> 91,775,232
  float* es   = (float*)(ws + 91775232);         // -> 92,095,232
  int*  cur   = (int*)  (ws + 91775232);         // aliases es (CSR done before es zeroed)
  float* ed   = (float*)(ws + 92095232);         // -> 92,415,232
  int*  rp    = (int*)  (ws + 92415232);         // -> 92,495,360
  int*  col   = (int*)  (ws + 92495360);         // -> 93,215,360

  float *as1=prm+0, *ad1=prm+1024, *b1=prm+2048, *lg1=prm+3072, *lb1=prm+4096;
  float *as2=prm+5120, *ad2=prm+6144, *b2=prm+7168, *lg2=prm+8192, *lb2=prm+9216;
  float *as3=prm+10240, *ad3=prm+10752, *b3=prm+11264;

  const int TB = 256;
  int gbN = (NN + TB - 1)/TB;
  int gbE = (EE + TB - 1)/TB;

  // ---- detect ----
  {
    Ptrs P;
    for (int i=0;i<18;i++){ P.p[i]=d_in[i]; P.n[i]=in_sizes[i]; }
    k_detect<<<18, 64, 0, stream>>>(P, flags);
  }
  // ---- fused prep ----
  {
    PrepArgs A;
    A.xraw = d_in[0]; A.Xc = Xc;
    A.w1raw = d_in[2]; A.Wt1 = Wt1;
    A.w2raw = d_in[8]; A.Wt2 = Wt2;
    A.w3raw = d_in[14]; A.Wt3 = Wt3;
    A.eiraw = (const int*)d_in[1]; A.eic = eic;
    const int idx[13] = {3,4,5,6,7, 9,10,11,12,13, 15,16,17};
    const int off[13] = {0,1024,2048,3072,4096, 5120,6144,7168,8192,9216, 10240,10752,11264};
    const int nn [13] = {1024,1024,1024,1024,1024, 1024,1024,1024,1024,1024, 512,512,512};
    for (int i=0;i<13;i++){ A.p13.src[i]=d_in[idx[i]]; A.p13.off[i]=off[i]; A.p13.n[i]=nn[i]; A.p13.fi[i]=idx[i]; }
    A.prm = prm; A.counts = cur; A.flags = flags;
    k_prep<<<13006, TB, 0, stream>>>(A);
  }

  // ---- CSR ----
  k_hist<<<gbE, TB, 0, stream>>>(eic, cur);
  k_scan<<<1, 1024, 0, stream>>>(cur, rp);
  k_selfloop<<<gbN, TB, 0, stream>>>(rp, cur, col);
  k_scatter<<<gbE, TB, 0, stream>>>(eic, cur, col);

  const int RB = (NN + 127)/128;                  // 157
  const int R8 = ((RB + 7)/8)*8;                  // 160 (padded, guard in kernel)
  dim3 g12(1024/128, R8);
  dim3 g3 (512/128,  R8);

  // ---- layer 1 (K=128) ----
  k_zero2<<<(NN*4+255)/256, TB, 0, stream>>>(es, ed, NN*4);
  k_gemm_mfma<<<g12, TB, 0, stream>>>(Xc, Wt1, xw, as1, ad1, es, ed, 128, 1024, 256, 4);
  k_aggln<<<NN, TB, 0, stream>>>(rp, col, xw, es, ed, b1, lg1, lb1, act);

  // ---- layer 2 (K=1024) ----
  k_zero2<<<(NN*4+255)/256, TB, 0, stream>>>(es, ed, NN*4);
  k_gemm_mfma<<<g12, TB, 0, stream>>>(act, Wt2, xw, as2, ad2, es, ed, 1024, 1024, 256, 4);
  k_aggln<<<NN, TB, 0, stream>>>(rp, col, xw, es, ed, b2, lg2, lb2, act);

  // ---- layer 3 (K=1024, M=512) ----
  k_zero2<<<(NN+255)/256, TB, 0, stream>>>(es, ed, NN);
  k_gemm_mfma<<<g3, TB, 0, stream>>>(act, Wt3, xw, as3, ad3, es, ed, 1024, 512, 512, 1);
  k_agg3<<<NN, TB, 0, stream>>>(rp, col, xw, es, ed, b3, out);
}

// Round 13
// 501.120 us; speedup vs baseline: 2.7731x; 1.0832x over previous
//
#include <hip/hip_runtime.h>
#include <hip/hip_bf16.h>

typedef __hip_bfloat16 bf16;
typedef __attribute__((ext_vector_type(8))) short short8;
typedef __attribute__((ext_vector_type(4))) float float4v;

#define NN 20000
#define EE 160000
#define ET (NN + EE)

__device__ __forceinline__ float bf2f(bf16 v){ return __bfloat162float(v); }
__device__ __forceinline__ float raw2f(unsigned short u){ return __uint_as_float(((unsigned)u) << 16); }
__device__ __forceinline__ unsigned short f2raw(float f){
  bf16 h = __float2bfloat16(f);
  return *(unsigned short*)&h;
}

// ---------------- per-buffer dtype detection ----------------
struct Ptrs { const void* p[18]; int n[18]; };

__global__ void k_detect(Ptrs P, int* __restrict__ flags){
  int b = blockIdx.x;            // 0..17
  int t = threadIdx.x;           // 64
  if (b == 1){
    const int* e = (const int*)P.p[1];
    int odd = e[2*t + 1];
    unsigned long long m2 = __ballot(odd != 0);
    if (t == 0){ flags[1] = (m2 == 0ULL) ? 1 : 0; }
    return;
  }
  const unsigned* w = (const unsigned*)P.p[b];
  int nwords = P.n[b] / 2;
  unsigned v = w[t % nwords];
  int e8 = (v >> 7) & 0xFF;
  int looks = (e8 >= 100 && e8 <= 140) ? 1 : 0;
  unsigned long long mz = __ballot(v == 0u);
  unsigned long long ml = __ballot(looks);
  if (t == 0){
    int nz = __popcll(mz);
    int nonz = 64 - nz;
    int nl = __popcll(ml);
    flags[8+b] = (nonz > 0 && 2*nl >= nonz) ? 0 : 1;
  }
}

// ---------------- fused preprocessing kernel ----------------
struct P13 { const void* src[13]; int off[13]; int n[13]; int fi[13]; };
struct PrepArgs {
  const void* xraw; bf16* Xc;
  const void* w1raw; bf16* Wt1;
  const void* w2raw; bf16* Wt2;
  const void* w3raw; bf16* Wt3;
  const int* eiraw; int* eic;
  P13 p13; float* prm;
  int* counts;
  const int* flags;
};

__device__ __forceinline__ void do_transpose(float (*tile)[33], const void* raw,
    bf16* wt, int K, int M, int f, int bx, int by, int t){
  int kb = by*32, mb = bx*32;
  int tx = t & 31, ty = t >> 5;   // 32 x 8
  for (int r = 0; r < 4; r++){
    int k = kb + ty + r*8;
    int m = mb + tx;
    float v = f ? ((const float*)raw)[(size_t)k*M+m] : bf2f(((const bf16*)raw)[(size_t)k*M+m]);
    tile[ty + r*8][tx] = v;
  }
  __syncthreads();
  for (int r = 0; r < 4; r++){
    int m = mb + ty + r*8;
    int k = kb + tx;
    wt[(size_t)m*K + k] = __float2bfloat16(tile[tx][ty + r*8]);
  }
}

__global__ __launch_bounds__(256) void k_prep(PrepArgs A){
  __shared__ float tile[32][33];
  int b = blockIdx.x, t = threadIdx.x;
  const int* flags = A.flags;
  if (b < 10000){                                 // cvt X -> bf16
    int i = b*256 + t;
    if (flags[8+0]) A.Xc[i] = __float2bfloat16(((const float*)A.xraw)[i]);
    else            A.Xc[i] = ((const bf16*)A.xraw)[i];
  } else if (b < 10128){                          // transpose W1 [128][1024] -> [1024][128]
    int r = b - 10000;
    do_transpose(tile, A.w1raw, A.Wt1, 128, 1024, flags[8+2], r & 31, r >> 5, t);
  } else if (b < 11152){                          // transpose W2 [1024][1024]
    int r = b - 10128;
    do_transpose(tile, A.w2raw, A.Wt2, 1024, 1024, flags[8+8], r & 31, r >> 5, t);
  } else if (b < 11664){                          // transpose W3 [1024][512] -> [512][1024]
    int r = b - 11152;
    do_transpose(tile, A.w3raw, A.Wt3, 1024, 512, flags[8+14], r & 15, r >> 4, t);
  } else if (b < 12914){                          // cvte
    int i = (b - 11664)*256 + t;
    if (i < 2*EE) A.eic[i] = flags[1] ? A.eiraw[2*i] : A.eiraw[i];
  } else if (b < 12927){                          // params -> fp32
    int pb = b - 12914;
    const void* s = A.p13.src[pb];
    int n = A.p13.n[pb];
    float* d = A.prm + A.p13.off[pb];
    int f = flags[8 + A.p13.fi[pb]];
    for (int i = t; i < n; i += 256)
      d[i] = f ? ((const float*)s)[i] : bf2f(((const bf16*)s)[i]);
  } else {                                        // init_counts
    int i = (b - 12927)*256 + t;
    if (i < NN) A.counts[i] = 1;
  }
}

// ---------------- CSR build (R11-proven path) ----------------
__global__ void k_hist(const int* __restrict__ ei, int* __restrict__ counts){
  int e = blockIdx.x*256 + threadIdx.x;
  if (e < EE){
    int d = ei[EE + e];
    if (d >= 0 && d < NN) atomicAdd(&counts[d], 1);
  }
}

__global__ __launch_bounds__(1024) void k_scan(const int* __restrict__ counts, int* __restrict__ rp){
  __shared__ int wsum[16];
  __shared__ int sc;
  int t = threadIdx.x, lane = t & 63, wv = t >> 6;
  if (t == 0) sc = 0;
  __syncthreads();
  for (int base = 0; base < NN; base += 1024){
    int i = base + t;
    int v = (i < NN) ? counts[i] : 0;
    int x = v;
    #pragma unroll
    for (int o = 1; o < 64; o <<= 1){
      int y = __shfl_up(x, o, 64);
      if (lane >= o) x += y;
    }
    if (lane == 63) wsum[wv] = x;
    __syncthreads();
    if (wv == 0 && lane < 16){
      int w = wsum[lane];
      #pragma unroll
      for (int o = 1; o < 16; o <<= 1){
        int y = __shfl_up(w, o, 16);
        if ((lane & 15) >= o) w += y;
      }
      wsum[lane] = w;
    }
    __syncthreads();
    int carry = sc;
    int wpre = (wv > 0) ? wsum[wv-1] : 0;
    if (i < NN) rp[i] = carry + wpre + x - v;     // exclusive
    __syncthreads();
    if (t == 1023) sc = carry + wsum[15];
    __syncthreads();
  }
  if (t == 0) rp[NN] = sc;
}

__global__ void k_selfloop(const int* __restrict__ rp, int* __restrict__ cursor, int* __restrict__ col){
  int i = blockIdx.x*256 + threadIdx.x;
  if (i < NN){ int p = rp[i]; col[p] = i; cursor[i] = p + 1; }
}

__global__ void k_scatter(const int* __restrict__ ei, int* __restrict__ cursor, int* __restrict__ col){
  int e = blockIdx.x*256 + threadIdx.x;
  if (e < EE){
    int s = ei[e], d = ei[EE + e];
    if (d >= 0 && d < NN){
      int pos = atomicAdd(&cursor[d], 1);
      col[pos] = s;
    }
  }
}

__global__ void k_zero2(float* __restrict__ a, float* __restrict__ b, int n){
  int i = blockIdx.x*256 + threadIdx.x;
  if (i < n){ a[i] = 0.f; b[i] = 0.f; }
}

// ---------------- MFMA GEMM (m97 structure) + fused fp32 es/ed epilogue ----------------
__global__ __launch_bounds__(256) void k_gemm_mfma(
    const bf16* __restrict__ X, const bf16* __restrict__ Wt, bf16* __restrict__ Y,
    const float* __restrict__ as_, const float* __restrict__ ad_,
    float* __restrict__ es, float* __restrict__ ed,
    int K, int M, int C, int H)
{
  __shared__ bf16 Xs[128*32];
  __shared__ bf16 Bs[128*32];
  int ncols = gridDim.x;
  int bid = blockIdx.y * ncols + blockIdx.x;
  int xcd  = bid & 7;
  int rest = bid >> 3;
  int colb = rest % ncols;
  int rowb = xcd + 8 * (rest / ncols);
  int r0 = rowb * 128;
  if (r0 >= NN) return;
  int c0 = colb * 128;

  int tid  = threadIdx.x;
  int wave = tid >> 6, lane = tid & 63;
  int quad = lane >> 4, l15 = lane & 15;
  int wr = (wave >> 1) * 64;
  int wc = (wave & 1) * 64;

  float4v acc[4][4];
  #pragma unroll
  for (int i=0;i<4;i++)
    #pragma unroll
    for (int j=0;j<4;j++)
      acc[i][j] = (float4v){0.f,0.f,0.f,0.f};

  for (int k0 = 0; k0 < K; k0 += 32){
    #pragma unroll
    for (int i = 0; i < 2; i++){
      int ch = i*256 + tid;
      int row = ch >> 2, kp = ch & 3;
      const bf16* gx = X  + (size_t)(r0 + row)*K + k0 + kp*8;
      const bf16* gb = Wt + (size_t)(c0 + row)*K + k0 + kp*8;
      __builtin_amdgcn_global_load_lds(
        (const __attribute__((address_space(1))) unsigned int*)gx,
        (__attribute__((address_space(3))) unsigned int*)(Xs + ch*8), 16, 0, 0);
      __builtin_amdgcn_global_load_lds(
        (const __attribute__((address_space(1))) unsigned int*)gb,
        (__attribute__((address_space(3))) unsigned int*)(Bs + ch*8), 16, 0, 0);
    }
    __syncthreads();

    short8 af[4], bfr[4];
    #pragma unroll
    for (int i = 0; i < 4; i++)
      af[i]  = *(const short8*)(Xs + ((size_t)(wr + i*16 + l15))*32 + quad*8);
    #pragma unroll
    for (int j = 0; j < 4; j++)
      bfr[j] = *(const short8*)(Bs + ((size_t)(wc + j*16 + l15))*32 + quad*8);
    #pragma unroll
    for (int i = 0; i < 4; i++)
      #pragma unroll
      for (int j = 0; j < 4; j++)
        acc[i][j] = __builtin_amdgcn_mfma_f32_16x16x32_bf16(af[i], bfr[j], acc[i][j], 0, 0, 0);
    __syncthreads();
  }

  int h = c0 / C;
  float asv[4], adv[4];
  #pragma unroll
  for (int j = 0; j < 4; j++){
    int colj = c0 + wc + j*16 + l15;
    asv[j] = as_[colj]; adv[j] = ad_[colj];
  }
  #pragma unroll
  for (int i = 0; i < 4; i++){
    int rbase = r0 + wr + i*16 + quad*4;
    #pragma unroll
    for (int rg = 0; rg < 4; rg++){
      int row = rbase + rg;
      bool ok = (row < NN);
      float pe = 0.f, pd = 0.f;
      #pragma unroll
      for (int j = 0; j < 4; j++){
        float v = acc[i][j][rg];
        int colj = c0 + wc + j*16 + l15;
        if (ok) Y[(size_t)row*M + colj] = __float2bfloat16(v);
        pe += v * asv[j];
        pd += v * adv[j];
      }
      #pragma unroll
      for (int o = 1; o < 16; o <<= 1){
        pe += __shfl_xor(pe, o, 64);
        pd += __shfl_xor(pd, o, 64);
      }
      if (ok && l15 == 0){
        atomicAdd(&es[row*H + h], pe);
        atomicAdd(&ed[row*H + h], pd);
      }
    }
  }
}

// ---------------- wave-per-node softmax+aggregate+bias+LN+ELU (layers 1,2; H=4) ----------------
// 4 nodes/block (one per wave), zero __syncthreads. Lane owns 16 consecutive channels.
__global__ __launch_bounds__(256) void k_aggln(const int* __restrict__ rp, const int* __restrict__ col,
    const bf16* __restrict__ xw, const float* __restrict__ es, const float* __restrict__ ed,
    const float* __restrict__ bias, const float* __restrict__ gam, const float* __restrict__ bet,
    bf16* __restrict__ act){
  int wv = threadIdx.x >> 6, lane = threadIdx.x & 63;
  int n = blockIdx.x*4 + wv;              // NN % 4 == 0
  int h = lane >> 4;                      // this lane's head
  int cb = lane * 16;                     // first channel
  int e0 = rp[n], e1 = rp[n+1], deg = e1 - e0;
  float4 ed4 = *(const float4*)&ed[n*4];
  const unsigned short* xwu = (const unsigned short*)xw;

  float acc[16];
  #pragma unroll
  for (int c=0;c<16;c++) acc[c]=0.f;

  if (deg <= 64){
    int src = 0;
    float l0=-1e30f, l1=-1e30f, l2=-1e30f, l3=-1e30f;
    if (lane < deg){
      src = col[e0 + lane];
      float4 e4 = *(const float4*)&es[src*4];
      float v;
      v = e4.x + ed4.x; l0 = v > 0.f ? v : 0.2f*v;
      v = e4.y + ed4.y; l1 = v > 0.f ? v : 0.2f*v;
      v = e4.z + ed4.z; l2 = v > 0.f ? v : 0.2f*v;
      v = e4.w + ed4.w; l3 = v > 0.f ? v : 0.2f*v;
    }
    float m0=l0, m1=l1, m2=l2, m3=l3;
    #pragma unroll
    for (int o=1;o<64;o<<=1){
      m0 = fmaxf(m0, __shfl_xor(m0,o,64));
      m1 = fmaxf(m1, __shfl_xor(m1,o,64));
      m2 = fmaxf(m2, __shfl_xor(m2,o,64));
      m3 = fmaxf(m3, __shfl_xor(m3,o,64));
    }
    float p0 = (lane<deg) ? __expf(l0-m0) : 0.f;
    float p1 = (lane<deg) ? __expf(l1-m1) : 0.f;
    float p2 = (lane<deg) ? __expf(l2-m2) : 0.f;
    float p3 = (lane<deg) ? __expf(l3-m3) : 0.f;
    float d0=p0, d1=p1, d2=p2, d3=p3;
    #pragma unroll
    for (int o=1;o<64;o<<=1){
      d0 += __shfl_xor(d0,o,64);
      d1 += __shfl_xor(d1,o,64);
      d2 += __shfl_xor(d2,o,64);
      d3 += __shfl_xor(d3,o,64);
    }
    float al0 = p0 * (1.f/(d0+1e-16f));
    float al1 = p1 * (1.f/(d1+1e-16f));
    float al2 = p2 * (1.f/(d2+1e-16f));
    float al3 = p3 * (1.f/(d3+1e-16f));

    for (int j=0;j<deg;j++){
      int s = __shfl(src, j, 64);
      float a0j = __shfl(al0, j, 64);
      float a1j = __shfl(al1, j, 64);
      float a2j = __shfl(al2, j, 64);
      float a3j = __shfl(al3, j, 64);
      float aj = (h==0) ? a0j : ((h==1) ? a1j : ((h==2) ? a2j : a3j));
      const unsigned short* row = xwu + (size_t)s*1024 + cb;
      ushort4 u0 = *(const ushort4*)(row);
      ushort4 u1 = *(const ushort4*)(row+4);
      ushort4 u2 = *(const ushort4*)(row+8);
      ushort4 u3 = *(const ushort4*)(row+12);
      acc[0] += aj*raw2f(u0.x); acc[1] += aj*raw2f(u0.y); acc[2] += aj*raw2f(u0.z); acc[3] += aj*raw2f(u0.w);
      acc[4] += aj*raw2f(u1.x); acc[5] += aj*raw2f(u1.y); acc[6] += aj*raw2f(u1.z); acc[7] += aj*raw2f(u1.w);
      acc[8] += aj*raw2f(u2.x); acc[9] += aj*raw2f(u2.y); acc[10]+= aj*raw2f(u2.z); acc[11]+= aj*raw2f(u2.w);
      acc[12]+= aj*raw2f(u3.x); acc[13]+= aj*raw2f(u3.y); acc[14]+= aj*raw2f(u3.z); acc[15]+= aj*raw2f(u3.w);
    }
  } else {
    float edh = (h==0) ? ed4.x : ((h==1) ? ed4.y : ((h==2) ? ed4.z : ed4.w));
    float m = -1e30f;
    for (int e=e0;e<e1;e++){
      float v = es[col[e]*4 + h] + edh;
      v = v > 0.f ? v : 0.2f*v;
      m = fmaxf(m, v);
    }
    float den = 0.f;
    for (int e=e0;e<e1;e++){
      float v = es[col[e]*4 + h] + edh;
      v = v > 0.f ? v : 0.2f*v;
      den += __expf(v - m);
    }
    float rd = 1.f/(den + 1e-16f);
    for (int e=e0;e<e1;e++){
      int s = col[e];
      float v = es[s*4 + h] + edh;
      v = v > 0.f ? v : 0.2f*v;
      float aj = __expf(v - m) * rd;
      const unsigned short* row = xwu + (size_t)s*1024 + cb;
      ushort4 u0 = *(const ushort4*)(row);
      ushort4 u1 = *(const ushort4*)(row+4);
      ushort4 u2 = *(const ushort4*)(row+8);
      ushort4 u3 = *(const ushort4*)(row+12);
      acc[0] += aj*raw2f(u0.x); acc[1] += aj*raw2f(u0.y); acc[2] += aj*raw2f(u0.z); acc[3] += aj*raw2f(u0.w);
      acc[4] += aj*raw2f(u1.x); acc[5] += aj*raw2f(u1.y); acc[6] += aj*raw2f(u1.z); acc[7] += aj*raw2f(u1.w);
      acc[8] += aj*raw2f(u2.x); acc[9] += aj*raw2f(u2.y); acc[10]+= aj*raw2f(u2.z); acc[11]+= aj*raw2f(u2.w);
      acc[12]+= aj*raw2f(u3.x); acc[13]+= aj*raw2f(u3.y); acc[14]+= aj*raw2f(u3.z); acc[15]+= aj*raw2f(u3.w);
    }
  }

  #pragma unroll
  for (int c=0;c<16;c++) acc[c] += bias[cb+c];
  float s1 = 0.f, s2 = 0.f;
  #pragma unroll
  for (int c=0;c<16;c++){ s1 += acc[c]; s2 += acc[c]*acc[c]; }
  #pragma unroll
  for (int o=1;o<64;o<<=1){
    s1 += __shfl_xor(s1,o,64);
    s2 += __shfl_xor(s2,o,64);
  }
  float mu  = s1 * (1.f/1024.f);
  float var = s2 * (1.f/1024.f) - mu*mu;
  float rstd = rsqrtf(fmaxf(var, 0.f) + 1e-5f);

  ushort4 o4[4];
  #pragma unroll
  for (int q=0;q<4;q++){
    float v0 = (acc[q*4+0]-mu)*rstd*gam[cb+q*4+0] + bet[cb+q*4+0];
    float v1 = (acc[q*4+1]-mu)*rstd*gam[cb+q*4+1] + bet[cb+q*4+1];
    float v2 = (acc[q*4+2]-mu)*rstd*gam[cb+q*4+2] + bet[cb+q*4+2];
    float v3 = (acc[q*4+3]-mu)*rstd*gam[cb+q*4+3] + bet[cb+q*4+3];
    v0 = v0 > 0.f ? v0 : (__expf(v0)-1.f);
    v1 = v1 > 0.f ? v1 : (__expf(v1)-1.f);
    v2 = v2 > 0.f ? v2 : (__expf(v2)-1.f);
    v3 = v3 > 0.f ? v3 : (__expf(v3)-1.f);
    o4[q].x = f2raw(v0); o4[q].y = f2raw(v1); o4[q].z = f2raw(v2); o4[q].w = f2raw(v3);
  }
  unsigned short* dst = (unsigned short*)act + (size_t)n*1024 + cb;
  *(ushort4*)(dst)    = o4[0];
  *(ushort4*)(dst+4)  = o4[1];
  *(ushort4*)(dst+8)  = o4[2];
  *(ushort4*)(dst+12) = o4[3];
}

// ---------------- wave-per-node layer-3: softmax + aggregate + bias -> fp32 out (H=1) ----------------
__global__ __launch_bounds__(256) void k_agg3(const int* __restrict__ rp, const int* __restrict__ col,
    const bf16* __restrict__ xw, const float* __restrict__ es, const float* __restrict__ ed,
    const float* __restrict__ bias, float* __restrict__ out){
  int wv = threadIdx.x >> 6, lane = threadIdx.x & 63;
  int n = blockIdx.x*4 + wv;
  int cb = lane * 8;
  int e0 = rp[n], e1 = rp[n+1], deg = e1 - e0;
  float edv = ed[n];
  const unsigned short* xwu = (const unsigned short*)xw;

  float acc[8];
  #pragma unroll
  for (int c=0;c<8;c++) acc[c]=0.f;

  if (deg <= 64){
    int src = 0;
    float l = -1e30f;
    if (lane < deg){
      src = col[e0 + lane];
      float v = es[src] + edv;
      l = v > 0.f ? v : 0.2f*v;
    }
    float m = l;
    #pragma unroll
    for (int o=1;o<64;o<<=1) m = fmaxf(m, __shfl_xor(m,o,64));
    float p = (lane<deg) ? __expf(l-m) : 0.f;
    float d = p;
    #pragma unroll
    for (int o=1;o<64;o<<=1) d += __shfl_xor(d,o,64);
    float al = p * (1.f/(d+1e-16f));

    for (int j=0;j<deg;j++){
      int s = __shfl(src, j, 64);
      float aj = __shfl(al, j, 64);
      const unsigned short* row = xwu + (size_t)s*512 + cb;
      ushort4 u0 = *(const ushort4*)(row);
      ushort4 u1 = *(const ushort4*)(row+4);
      acc[0] += aj*raw2f(u0.x); acc[1] += aj*raw2f(u0.y); acc[2] += aj*raw2f(u0.z); acc[3] += aj*raw2f(u0.w);
      acc[4] += aj*raw2f(u1.x); acc[5] += aj*raw2f(u1.y); acc[6] += aj*raw2f(u1.z); acc[7] += aj*raw2f(u1.w);
    }
  } else {
    float m = -1e30f;
    for (int e=e0;e<e1;e++){
      float v = es[col[e]] + edv;
      v = v > 0.f ? v : 0.2f*v;
      m = fmaxf(m, v);
    }
    float den = 0.f;
    for (int e=e0;e<e1;e++){
      float v = es[col[e]] + edv;
      v = v > 0.f ? v : 0.2f*v;
      den += __expf(v - m);
    }
    float rd = 1.f/(den + 1e-16f);
    for (int e=e0;e<e1;e++){
      int s = col[e];
      float v = es[s] + edv;
      v = v > 0.f ? v : 0.2f*v;
      float aj = __expf(v - m) * rd;
      const unsigned short* row = xwu + (size_t)s*512 + cb;
      ushort4 u0 = *(const ushort4*)(row);
      ushort4 u1 = *(const ushort4*)(row+4);
      acc[0] += aj*raw2f(u0.x); acc[1] += aj*raw2f(u0.y); acc[2] += aj*raw2f(u0.z); acc[3] += aj*raw2f(u0.w);
      acc[4] += aj*raw2f(u1.x); acc[5] += aj*raw2f(u1.y); acc[6] += aj*raw2f(u1.z); acc[7] += aj*raw2f(u1.w);
    }
  }
  float* dst = out + (size_t)n*512 + cb;
  #pragma unroll
  for (int c=0;c<8;c++) dst[c] = acc[c] + bias[cb+c];
}

__global__ void k_wssmall(float* __restrict__ out, float code){
  if (threadIdx.x == 0) out[0] = code;
}

// ---------------- launch ----------------
extern "C" void kernel_launch(void* const* d_in, const int* in_sizes, int n_in,
                              void* d_out, int out_size, void* d_ws, size_t ws_size,
                              hipStream_t stream){
  float* out = (float*)d_out;
  char* ws = (char*)d_ws;

  static const int EXP_SZ[18] = {2560000, 320000, 131072, 1024,1024,1024,1024,1024,
                                 1048576, 1024,1024,1024,1024,1024,
                                 524288, 512,512,512};
  if (n_in != 18){ k_wssmall<<<1,64,0,stream>>>(out, 500.0f*301.0f); return; }
  for (int i = 0; i < 18; i++)
    if (in_sizes[i] != EXP_SZ[i]){ k_wssmall<<<1,64,0,stream>>>(out, 500.0f*302.0f); return; }
  if (out_size != NN*512){ k_wssmall<<<1,64,0,stream>>>(out, 500.0f*303.0f); return; }
  const size_t NEED = 93215360;
  if (ws_size < NEED){ k_wssmall<<<1,64,0,stream>>>(out, 500.0f*304.0f); return; }

  // ---- workspace layout ----
  bf16* xw    = (bf16*) (ws);                    // 40,960,000
  bf16* act   = (bf16*) (ws + 40960000);         // -> 81,920,000
  bf16* Xc    = (bf16*) (ws + 81920000);         // -> 87,040,000
  bf16* Wt1   = (bf16*) (ws + 87040000);         // -> 87,302,144
  bf16* Wt2   = (bf16*) (ws + 87302144);         // -> 89,399,296
  bf16* Wt3   = (bf16*) (ws + 89399296);         // -> 90,447,872
  float* prm  = (float*)(ws + 90447872);         // -> 90,494,976
  int*  flags = (int*)  (ws + 90494976);         // -> 90,495,232
  int*  eic   = (int*)  (ws + 90495232);         // -> 91,775,232
  float* es   = (float*)(ws + 91775232);         // -> 92,095,232
  int*  cur   = (int*)  (ws + 91775232);         // aliases es (CSR done before es zeroed)
  float* ed   = (float*)(ws + 92095232);         // -> 92,415,232
  int*  rp    = (int*)  (ws + 92415232);         // -> 92,495,360
  int*  col   = (int*)  (ws + 92495360);         // -> 93,215,360

  float *as1=prm+0, *ad1=prm+1024, *b1=prm+2048, *lg1=prm+3072, *lb1=prm+4096;
  float *as2=prm+5120, *ad2=prm+6144, *b2=prm+7168, *lg2=prm+8192, *lb2=prm+9216;
  float *as3=prm+10240, *ad3=prm+10752, *b3=prm+11264;

  const int TB = 256;
  int gbN = (NN + TB - 1)/TB;
  int gbE = (EE + TB - 1)/TB;

  // ---- detect ----
  {
    Ptrs P;
    for (int i=0;i<18;i++){ P.p[i]=d_in[i]; P.n[i]=in_sizes[i]; }
    k_detect<<<18, 64, 0, stream>>>(P, flags);
  }
  // ---- fused prep ----
  {
    PrepArgs A;
    A.xraw = d_in[0]; A.Xc = Xc;
    A.w1raw = d_in[2]; A.Wt1 = Wt1;
    A.w2raw = d_in[8]; A.Wt2 = Wt2;
    A.w3raw = d_in[14]; A.Wt3 = Wt3;
    A.eiraw = (const int*)d_in[1]; A.eic = eic;
    const int idx[13] = {3,4,5,6,7, 9,10,11,12,13, 15,16,17};
    const int off[13] = {0,1024,2048,3072,4096, 5120,6144,7168,8192,9216, 10240,10752,11264};
    const int nn [13] = {1024,1024,1024,1024,1024, 1024,1024,1024,1024,1024, 512,512,512};
    for (int i=0;i<13;i++){ A.p13.src[i]=d_in[idx[i]]; A.p13.off[i]=off[i]; A.p13.n[i]=nn[i]; A.p13.fi[i]=idx[i]; }
    A.prm = prm; A.counts = cur; A.flags = flags;
    k_prep<<<13006, TB, 0, stream>>>(A);
  }

  // ---- CSR ----
  k_hist<<<gbE, TB, 0, stream>>>(eic, cur);
  k_scan<<<1, 1024, 0, stream>>>(cur, rp);
  k_selfloop<<<gbN, TB, 0, stream>>>(rp, cur, col);
  k_scatter<<<gbE, TB, 0, stream>>>(eic, cur, col);

  const int RB = (NN + 127)/128;                  // 157
  const int R8 = ((RB + 7)/8)*8;                  // 160 (padded, guard in kernel)
  dim3 g12(1024/128, R8);
  dim3 g3 (512/128,  R8);

  // ---- layer 1 (K=128) ----
  k_zero2<<<(NN*4+255)/256, TB, 0, stream>>>(es, ed, NN*4);
  k_gemm_mfma<<<g12, TB, 0, stream>>>(Xc, Wt1, xw, as1, ad1, es, ed, 128, 1024, 256, 4);
  k_aggln<<<NN/4, TB, 0, stream>>>(rp, col, xw, es, ed, b1, lg1, lb1, act);

  // ---- layer 2 (K=1024) ----
  k_zero2<<<(NN*4+255)/256, TB, 0, stream>>>(es, ed, NN*4);
  k_gemm_mfma<<<g12, TB, 0, stream>>>(act, Wt2, xw, as2, ad2, es, ed, 1024, 1024, 256, 4);
  k_aggln<<<NN/4, TB, 0, stream>>>(rp, col, xw, es, ed, b2, lg2, lb2, act);

  // ---- layer 3 (K=1024, M=512) ----
  k_zero2<<<(NN+255)/256, TB, 0, stream>>>(es, ed, NN);
  k_gemm_mfma<<<g3, TB, 0, stream>>>(act, Wt3, xw, as3, ad3, es, ed, 1024, 512, 512, 1);
  k_agg3<<<NN/4, TB, 0, stream>>>(rp, col, xw, es, ed, b3, out);
}

// Round 14
// 473.528 us; speedup vs baseline: 2.9347x; 1.0583x over previous
//
#include <hip/hip_runtime.h>
#include <hip/hip_bf16.h>

typedef __hip_bfloat16 bf16;
typedef __attribute__((ext_vector_type(8))) short short8;
typedef __attribute__((ext_vector_type(4))) float float4v;

#define NN 20000
#define EE 160000
#define ET (NN + EE)

__device__ __forceinline__ float bf2f(bf16 v){ return __bfloat162float(v); }
__device__ __forceinline__ float raw2f(unsigned short u){ return __uint_as_float(((unsigned)u) << 16); }
__device__ __forceinline__ unsigned short f2raw(float f){
  bf16 h = __float2bfloat16(f);
  return *(unsigned short*)&h;
}

// ---------------- per-buffer dtype detection ----------------
struct Ptrs { const void* p[18]; int n[18]; };

__global__ void k_detect(Ptrs P, int* __restrict__ flags){
  int b = blockIdx.x;            // 0..17
  int t = threadIdx.x;           // 64
  if (b == 1){
    const int* e = (const int*)P.p[1];
    int odd = e[2*t + 1];
    unsigned long long m2 = __ballot(odd != 0);
    if (t == 0){ flags[1] = (m2 == 0ULL) ? 1 : 0; }
    return;
  }
  const unsigned* w = (const unsigned*)P.p[b];
  int nwords = P.n[b] / 2;
  unsigned v = w[t % nwords];
  int e8 = (v >> 7) & 0xFF;
  int looks = (e8 >= 100 && e8 <= 140) ? 1 : 0;
  unsigned long long mz = __ballot(v == 0u);
  unsigned long long ml = __ballot(looks);
  if (t == 0){
    int nz = __popcll(mz);
    int nonz = 64 - nz;
    int nl = __popcll(ml);
    flags[8+b] = (nonz > 0 && 2*nl >= nonz) ? 0 : 1;
  }
}

// ---------------- fused preprocessing kernel ----------------
struct P13 { const void* src[13]; int off[13]; int n[13]; int fi[13]; };
struct PrepArgs {
  const void* xraw; bf16* Xc;
  const void* w1raw; bf16* Wt1;
  const void* w2raw; bf16* Wt2;
  const void* w3raw; bf16* Wt3;
  const int* eiraw; int* eic;
  P13 p13; float* prm;
  int* counts;
  float* esA; float* edA;
  const int* flags;
};

__device__ __forceinline__ void do_transpose(float (*tile)[33], const void* raw,
    bf16* wt, int K, int M, int f, int bx, int by, int t){
  int kb = by*32, mb = bx*32;
  int tx = t & 31, ty = t >> 5;   // 32 x 8
  for (int r = 0; r < 4; r++){
    int k = kb + ty + r*8;
    int m = mb + tx;
    float v = f ? ((const float*)raw)[(size_t)k*M+m] : bf2f(((const bf16*)raw)[(size_t)k*M+m]);
    tile[ty + r*8][tx] = v;
  }
  __syncthreads();
  for (int r = 0; r < 4; r++){
    int m = mb + ty + r*8;
    int k = kb + tx;
    wt[(size_t)m*K + k] = __float2bfloat16(tile[tx][ty + r*8]);
  }
}

__global__ __launch_bounds__(256) void k_prep(PrepArgs A){
  __shared__ float tile[32][33];
  int b = blockIdx.x, t = threadIdx.x;
  const int* flags = A.flags;
  if (b < 10000){                                 // cvt X -> bf16
    int i = b*256 + t;
    if (flags[8+0]) A.Xc[i] = __float2bfloat16(((const float*)A.xraw)[i]);
    else            A.Xc[i] = ((const bf16*)A.xraw)[i];
  } else if (b < 10128){                          // transpose W1 [128][1024] -> [1024][128]
    int r = b - 10000;
    do_transpose(tile, A.w1raw, A.Wt1, 128, 1024, flags[8+2], r & 31, r >> 5, t);
  } else if (b < 11152){                          // transpose W2 [1024][1024]
    int r = b - 10128;
    do_transpose(tile, A.w2raw, A.Wt2, 1024, 1024, flags[8+8], r & 31, r >> 5, t);
  } else if (b < 11664){                          // transpose W3 [1024][512] -> [512][1024]
    int r = b - 11152;
    do_transpose(tile, A.w3raw, A.Wt3, 1024, 512, flags[8+14], r & 15, r >> 4, t);
  } else if (b < 12914){                          // cvte
    int i = (b - 11664)*256 + t;
    if (i < 2*EE) A.eic[i] = flags[1] ? A.eiraw[2*i] : A.eiraw[i];
  } else if (b < 12927){                          // params -> fp32
    int pb = b - 12914;
    const void* s = A.p13.src[pb];
    int n = A.p13.n[pb];
    float* d = A.prm + A.p13.off[pb];
    int f = flags[8 + A.p13.fi[pb]];
    for (int i = t; i < n; i += 256)
      d[i] = f ? ((const float*)s)[i] : bf2f(((const bf16*)s)[i]);
  } else if (b < 13006){                          // init_counts (cur aliases xw region)
    int i = (b - 12927)*256 + t;
    if (i < NN) A.counts[i] = 1;
  } else {                                        // zero esA/edA (NN*4 floats each)
    int i = (b - 13006)*256 + t;
    if (i < NN*4){ A.esA[i] = 0.f; A.edA[i] = 0.f; }
  }
}

// ---------------- CSR build ----------------
__global__ void k_hist(const int* __restrict__ ei, int* __restrict__ counts){
  int e = blockIdx.x*256 + threadIdx.x;
  if (e < EE){
    int d = ei[EE + e];
    if (d >= 0 && d < NN) atomicAdd(&counts[d], 1);
  }
}

__global__ __launch_bounds__(1024) void k_scan(const int* __restrict__ counts, int* __restrict__ rp){
  __shared__ int wsum[16];
  __shared__ int sc;
  int t = threadIdx.x, lane = t & 63, wv = t >> 6;
  if (t == 0) sc = 0;
  __syncthreads();
  for (int base = 0; base < NN; base += 1024){
    int i = base + t;
    int v = (i < NN) ? counts[i] : 0;
    int x = v;
    #pragma unroll
    for (int o = 1; o < 64; o <<= 1){
      int y = __shfl_up(x, o, 64);
      if (lane >= o) x += y;
    }
    if (lane == 63) wsum[wv] = x;
    __syncthreads();
    if (wv == 0 && lane < 16){
      int w = wsum[lane];
      #pragma unroll
      for (int o = 1; o < 16; o <<= 1){
        int y = __shfl_up(w, o, 16);
        if ((lane & 15) >= o) w += y;
      }
      wsum[lane] = w;
    }
    __syncthreads();
    int carry = sc;
    int wpre = (wv > 0) ? wsum[wv-1] : 0;
    if (i < NN) rp[i] = carry + wpre + x - v;     // exclusive
    __syncthreads();
    if (t == 1023) sc = carry + wsum[15];
    __syncthreads();
  }
  if (t == 0) rp[NN] = sc;
}

__global__ void k_selfloop(const int* __restrict__ rp, int* __restrict__ cursor, int* __restrict__ col){
  int i = blockIdx.x*256 + threadIdx.x;
  if (i < NN){ int p = rp[i]; col[p] = i; cursor[i] = p + 1; }
}

__global__ void k_scatter(const int* __restrict__ ei, int* __restrict__ cursor, int* __restrict__ col){
  int e = blockIdx.x*256 + threadIdx.x;
  if (e < EE){
    int s = ei[e], d = ei[EE + e];
    if (d >= 0 && d < NN){
      int pos = atomicAdd(&cursor[d], 1);
      col[pos] = s;
    }
  }
}

// ---------------- MFMA GEMM: BK=64, XOR-swizzled LDS, fused fp32 es/ed epilogue ----------------
__global__ __launch_bounds__(256) void k_gemm_mfma(
    const bf16* __restrict__ X, const bf16* __restrict__ Wt, bf16* __restrict__ Y,
    const float* __restrict__ as_, const float* __restrict__ ad_,
    float* __restrict__ es, float* __restrict__ ed,
    int K, int M, int C, int H)
{
  __shared__ bf16 Xs[128*64];   // 16 KB
  __shared__ bf16 Bs[128*64];   // 16 KB
  int ncols = gridDim.x;
  int bid = blockIdx.y * ncols + blockIdx.x;
  int xcd  = bid & 7;
  int rest = bid >> 3;
  int colb = rest % ncols;
  int rowb = xcd + 8 * (rest / ncols);
  int r0 = rowb * 128;
  if (r0 >= NN) return;
  int c0 = colb * 128;

  int tid  = threadIdx.x;
  int wave = tid >> 6, lane = tid & 63;
  int quad = lane >> 4, l15 = lane & 15;
  int wr = (wave >> 1) * 64;
  int wc = (wave & 1) * 64;
  int sw = l15 & 7;                       // row&7 for all fragment rows this lane touches

  float4v acc[4][4];
  #pragma unroll
  for (int i=0;i<4;i++)
    #pragma unroll
    for (int j=0;j<4;j++)
      acc[i][j] = (float4v){0.f,0.f,0.f,0.f};

  for (int k0 = 0; k0 < K; k0 += 64){
    #pragma unroll
    for (int i = 0; i < 4; i++){
      int ch = i*256 + tid;               // 0..1023, 16B chunks
      int row = ch >> 3, kl = ch & 7;
      int kg = kl ^ (row & 7);            // swizzled source chunk
      const bf16* gx = X  + (size_t)(r0 + row)*K + k0 + kg*8;
      const bf16* gb = Wt + (size_t)(c0 + row)*K + k0 + kg*8;
      __builtin_amdgcn_global_load_lds(
        (const __attribute__((address_space(1))) unsigned int*)gx,
        (__attribute__((address_space(3))) unsigned int*)(Xs + ch*8), 16, 0, 0);
      __builtin_amdgcn_global_load_lds(
        (const __attribute__((address_space(1))) unsigned int*)gb,
        (__attribute__((address_space(3))) unsigned int*)(Bs + ch*8), 16, 0, 0);
    }
    __syncthreads();

    #pragma unroll
    for (int kk = 0; kk < 2; kk++){       // two 32-wide K slices, in order (bit-identical accum)
      int kp = quad + kk*4;
      short8 af[4], bfr[4];
      #pragma unroll
      for (int i = 0; i < 4; i++){
        int r = wr + i*16 + l15;
        af[i] = *(const short8*)(Xs + ((size_t)r*8 + (kp ^ sw))*8);
      }
      #pragma unroll
      for (int j = 0; j < 4; j++){
        int r = wc + j*16 + l15;
        bfr[j] = *(const short8*)(Bs + ((size_t)r*8 + (kp ^ sw))*8);
      }
      #pragma unroll
      for (int i = 0; i < 4; i++)
        #pragma unroll
        for (int j = 0; j < 4; j++)
          acc[i][j] = __builtin_amdgcn_mfma_f32_16x16x32_bf16(af[i], bfr[j], acc[i][j], 0, 0, 0);
    }
    __syncthreads();
  }

  int h = c0 / C;
  float asv[4], adv[4];
  #pragma unroll
  for (int j = 0; j < 4; j++){
    int colj = c0 + wc + j*16 + l15;
    asv[j] = as_[colj]; adv[j] = ad_[colj];
  }
  #pragma unroll
  for (int i = 0; i < 4; i++){
    int rbase = r0 + wr + i*16 + quad*4;
    #pragma unroll
    for (int rg = 0; rg < 4; rg++){
      int row = rbase + rg;
      bool ok = (row < NN);
      float pe = 0.f, pd = 0.f;
      #pragma unroll
      for (int j = 0; j < 4; j++){
        float v = acc[i][j][rg];
        int colj = c0 + wc + j*16 + l15;
        if (ok) Y[(size_t)row*M + colj] = __float2bfloat16(v);
        pe += v * asv[j];
        pd += v * adv[j];
      }
      #pragma unroll
      for (int o = 1; o < 16; o <<= 1){
        pe += __shfl_xor(pe, o, 64);
        pd += __shfl_xor(pd, o, 64);
      }
      if (ok && l15 == 0){
        atomicAdd(&es[row*H + h], pe);
        atomicAdd(&ed[row*H + h], pd);
      }
    }
  }
}

// ---------------- wave-per-node softmax+aggregate+bias+LN+ELU (layers 1,2; H=4) ----------------
// Epilogue zeroes next layer's es/ed slot for this node (zn floats each; exclusive ownership).
__global__ __launch_bounds__(256) void k_aggln(const int* __restrict__ rp, const int* __restrict__ col,
    const bf16* __restrict__ xw, const float* __restrict__ es, const float* __restrict__ ed,
    const float* __restrict__ bias, const float* __restrict__ gam, const float* __restrict__ bet,
    bf16* __restrict__ act, float* __restrict__ esz, float* __restrict__ edz, int zn){
  int wv = threadIdx.x >> 6, lane = threadIdx.x & 63;
  int n = blockIdx.x*4 + wv;              // NN % 4 == 0
  int h = lane >> 4;
  int cb = lane * 16;
  int e0 = rp[n], e1 = rp[n+1], deg = e1 - e0;
  float4 ed4 = *(const float4*)&ed[n*4];
  const unsigned short* xwu = (const unsigned short*)xw;

  float acc[16];
  #pragma unroll
  for (int c=0;c<16;c++) acc[c]=0.f;

  if (deg <= 64){
    int src = 0;
    float l0=-1e30f, l1=-1e30f, l2=-1e30f, l3=-1e30f;
    if (lane < deg){
      src = col[e0 + lane];
      float4 e4 = *(const float4*)&es[src*4];
      float v;
      v = e4.x + ed4.x; l0 = v > 0.f ? v : 0.2f*v;
      v = e4.y + ed4.y; l1 = v > 0.f ? v : 0.2f*v;
      v = e4.z + ed4.z; l2 = v > 0.f ? v : 0.2f*v;
      v = e4.w + ed4.w; l3 = v > 0.f ? v : 0.2f*v;
    }
    float m0=l0, m1=l1, m2=l2, m3=l3;
    #pragma unroll
    for (int o=1;o<64;o<<=1){
      m0 = fmaxf(m0, __shfl_xor(m0,o,64));
      m1 = fmaxf(m1, __shfl_xor(m1,o,64));
      m2 = fmaxf(m2, __shfl_xor(m2,o,64));
      m3 = fmaxf(m3, __shfl_xor(m3,o,64));
    }
    float p0 = (lane<deg) ? __expf(l0-m0) : 0.f;
    float p1 = (lane<deg) ? __expf(l1-m1) : 0.f;
    float p2 = (lane<deg) ? __expf(l2-m2) : 0.f;
    float p3 = (lane<deg) ? __expf(l3-m3) : 0.f;
    float d0=p0, d1=p1, d2=p2, d3=p3;
    #pragma unroll
    for (int o=1;o<64;o<<=1){
      d0 += __shfl_xor(d0,o,64);
      d1 += __shfl_xor(d1,o,64);
      d2 += __shfl_xor(d2,o,64);
      d3 += __shfl_xor(d3,o,64);
    }
    float al0 = p0 * (1.f/(d0+1e-16f));
    float al1 = p1 * (1.f/(d1+1e-16f));
    float al2 = p2 * (1.f/(d2+1e-16f));
    float al3 = p3 * (1.f/(d3+1e-16f));

    for (int j=0;j<deg;j++){
      int s = __shfl(src, j, 64);
      float a0j = __shfl(al0, j, 64);
      float a1j = __shfl(al1, j, 64);
      float a2j = __shfl(al2, j, 64);
      float a3j = __shfl(al3, j, 64);
      float aj = (h==0) ? a0j : ((h==1) ? a1j : ((h==2) ? a2j : a3j));
      const unsigned short* row = xwu + (size_t)s*1024 + cb;
      ushort4 u0 = *(const ushort4*)(row);
      ushort4 u1 = *(const ushort4*)(row+4);
      ushort4 u2 = *(const ushort4*)(row+8);
      ushort4 u3 = *(const ushort4*)(row+12);
      acc[0] += aj*raw2f(u0.x); acc[1] += aj*raw2f(u0.y); acc[2] += aj*raw2f(u0.z); acc[3] += aj*raw2f(u0.w);
      acc[4] += aj*raw2f(u1.x); acc[5] += aj*raw2f(u1.y); acc[6] += aj*raw2f(u1.z); acc[7] += aj*raw2f(u1.w);
      acc[8] += aj*raw2f(u2.x); acc[9] += aj*raw2f(u2.y); acc[10]+= aj*raw2f(u2.z); acc[11]+= aj*raw2f(u2.w);
      acc[12]+= aj*raw2f(u3.x); acc[13]+= aj*raw2f(u3.y); acc[14]+= aj*raw2f(u3.z); acc[15]+= aj*raw2f(u3.w);
    }
  } else {
    float edh = (h==0) ? ed4.x : ((h==1) ? ed4.y : ((h==2) ? ed4.z : ed4.w));
    float m = -1e30f;
    for (int e=e0;e<e1;e++){
      float v = es[col[e]*4 + h] + edh;
      v = v > 0.f ? v : 0.2f*v;
      m = fmaxf(m, v);
    }
    float den = 0.f;
    for (int e=e0;e<e1;e++){
      float v = es[col[e]*4 + h] + edh;
      v = v > 0.f ? v : 0.2f*v;
      den += __expf(v - m);
    }
    float rd = 1.f/(den + 1e-16f);
    for (int e=e0;e<e1;e++){
      int s = col[e];
      float v = es[s*4 + h] + edh;
      v = v > 0.f ? v : 0.2f*v;
      float aj = __expf(v - m) * rd;
      const unsigned short* row = xwu + (size_t)s*1024 + cb;
      ushort4 u0 = *(const ushort4*)(row);
      ushort4 u1 = *(const ushort4*)(row+4);
      ushort4 u2 = *(const ushort4*)(row+8);
      ushort4 u3 = *(const ushort4*)(row+12);
      acc[0] += aj*raw2f(u0.x); acc[1] += aj*raw2f(u0.y); acc[2] += aj*raw2f(u0.z); acc[3] += aj*raw2f(u0.w);
      acc[4] += aj*raw2f(u1.x); acc[5] += aj*raw2f(u1.y); acc[6] += aj*raw2f(u1.z); acc[7] += aj*raw2f(u1.w);
      acc[8] += aj*raw2f(u2.x); acc[9] += aj*raw2f(u2.y); acc[10]+= aj*raw2f(u2.z); acc[11]+= aj*raw2f(u2.w);
      acc[12]+= aj*raw2f(u3.x); acc[13]+= aj*raw2f(u3.y); acc[14]+= aj*raw2f(u3.z); acc[15]+= aj*raw2f(u3.w);
    }
  }

  #pragma unroll
  for (int c=0;c<16;c++) acc[c] += bias[cb+c];
  float s1 = 0.f, s2 = 0.f;
  #pragma unroll
  for (int c=0;c<16;c++){ s1 += acc[c]; s2 += acc[c]*acc[c]; }
  #pragma unroll
  for (int o=1;o<64;o<<=1){
    s1 += __shfl_xor(s1,o,64);
    s2 += __shfl_xor(s2,o,64);
  }
  float mu  = s1 * (1.f/1024.f);
  float var = s2 * (1.f/1024.f) - mu*mu;
  float rstd = rsqrtf(fmaxf(var, 0.f) + 1e-5f);

  ushort4 o4[4];
  #pragma unroll
  for (int q=0;q<4;q++){
    float v0 = (acc[q*4+0]-mu)*rstd*gam[cb+q*4+0] + bet[cb+q*4+0];
    float v1 = (acc[q*4+1]-mu)*rstd*gam[cb+q*4+1] + bet[cb+q*4+1];
    float v2 = (acc[q*4+2]-mu)*rstd*gam[cb+q*4+2] + bet[cb+q*4+2];
    float v3 = (acc[q*4+3]-mu)*rstd*gam[cb+q*4+3] + bet[cb+q*4+3];
    v0 = v0 > 0.f ? v0 : (__expf(v0)-1.f);
    v1 = v1 > 0.f ? v1 : (__expf(v1)-1.f);
    v2 = v2 > 0.f ? v2 : (__expf(v2)-1.f);
    v3 = v3 > 0.f ? v3 : (__expf(v3)-1.f);
    o4[q].x = f2raw(v0); o4[q].y = f2raw(v1); o4[q].z = f2raw(v2); o4[q].w = f2raw(v3);
  }
  unsigned short* dst = (unsigned short*)act + (size_t)n*1024 + cb;
  *(ushort4*)(dst)    = o4[0];
  *(ushort4*)(dst+4)  = o4[1];
  *(ushort4*)(dst+8)  = o4[2];
  *(ushort4*)(dst+12) = o4[3];

  // zero next layer's logit slots for this node (exclusive ownership; read next dispatch)
  if (lane < zn){ esz[n*zn + lane] = 0.f; edz[n*zn + lane] = 0.f; }
}

// ---------------- wave-per-node layer-3: softmax + aggregate + bias -> fp32 out (H=1) ----------------
__global__ __launch_bounds__(256) void k_agg3(const int* __restrict__ rp, const int* __restrict__ col,
    const bf16* __restrict__ xw, const float* __restrict__ es, const float* __restrict__ ed,
    const float* __restrict__ bias, float* __restrict__ out){
  int wv = threadIdx.x >> 6, lane = threadIdx.x & 63;
  int n = blockIdx.x*4 + wv;
  int cb = lane * 8;
  int e0 = rp[n], e1 = rp[n+1], deg = e1 - e0;
  float edv = ed[n];
  const unsigned short* xwu = (const unsigned short*)xw;

  float acc[8];
  #pragma unroll
  for (int c=0;c<8;c++) acc[c]=0.f;

  if (deg <= 64){
    int src = 0;
    float l = -1e30f;
    if (lane < deg){
      src = col[e0 + lane];
      float v = es[src] + edv;
      l = v > 0.f ? v : 0.2f*v;
    }
    float m = l;
    #pragma unroll
    for (int o=1;o<64;o<<=1) m = fmaxf(m, __shfl_xor(m,o,64));
    float p = (lane<deg) ? __expf(l-m) : 0.f;
    float d = p;
    #pragma unroll
    for (int o=1;o<64;o<<=1) d += __shfl_xor(d,o,64);
    float al = p * (1.f/(d+1e-16f));

    for (int j=0;j<deg;j++){
      int s = __shfl(src, j, 64);
      float aj = __shfl(al, j, 64);
      const unsigned short* row = xwu + (size_t)s*512 + cb;
      ushort4 u0 = *(const ushort4*)(row);
      ushort4 u1 = *(const ushort4*)(row+4);
      acc[0] += aj*raw2f(u0.x); acc[1] += aj*raw2f(u0.y); acc[2] += aj*raw2f(u0.z); acc[3] += aj*raw2f(u0.w);
      acc[4] += aj*raw2f(u1.x); acc[5] += aj*raw2f(u1.y); acc[6] += aj*raw2f(u1.z); acc[7] += aj*raw2f(u1.w);
    }
  } else {
    float m = -1e30f;
    for (int e=e0;e<e1;e++){
      float v = es[col[e]] + edv;
      v = v > 0.f ? v : 0.2f*v;
      m = fmaxf(m, v);
    }
    float den = 0.f;
    for (int e=e0;e<e1;e++){
      float v = es[col[e]] + edv;
      v = v > 0.f ? v : 0.2f*v;
      den += __expf(v - m);
    }
    float rd = 1.f/(den + 1e-16f);
    for (int e=e0;e<e1;e++){
      int s = col[e];
      float v = es[s] + edv;
      v = v > 0.f ? v : 0.2f*v;
      float aj = __expf(v - m) * rd;
      const unsigned short* row = xwu + (size_t)s*512 + cb;
      ushort4 u0 = *(const ushort4*)(row);
      ushort4 u1 = *(const ushort4*)(row+4);
      acc[0] += aj*raw2f(u0.x); acc[1] += aj*raw2f(u0.y); acc[2] += aj*raw2f(u0.z); acc[3] += aj*raw2f(u0.w);
      acc[4] += aj*raw2f(u1.x); acc[5] += aj*raw2f(u1.y); acc[6] += aj*raw2f(u1.z); acc[7] += aj*raw2f(u1.w);
    }
  }
  float* dst = out + (size_t)n*512 + cb;
  #pragma unroll
  for (int c=0;c<8;c++) dst[c] = acc[c] + bias[cb+c];
}

__global__ void k_wssmall(float* __restrict__ out, float code){
  if (threadIdx.x == 0) out[0] = code;
}

// ---------------- launch ----------------
extern "C" void kernel_launch(void* const* d_in, const int* in_sizes, int n_in,
                              void* d_out, int out_size, void* d_ws, size_t ws_size,
                              hipStream_t stream){
  float* out = (float*)d_out;
  char* ws = (char*)d_ws;

  static const int EXP_SZ[18] = {2560000, 320000, 131072, 1024,1024,1024,1024,1024,
                                 1048576, 1024,1024,1024,1024,1024,
                                 524288, 512,512,512};
  if (n_in != 18){ k_wssmall<<<1,64,0,stream>>>(out, 500.0f*301.0f); return; }
  for (int i = 0; i < 18; i++)
    if (in_sizes[i] != EXP_SZ[i]){ k_wssmall<<<1,64,0,stream>>>(out, 500.0f*302.0f); return; }
  if (out_size != NN*512){ k_wssmall<<<1,64,0,stream>>>(out, 500.0f*303.0f); return; }
  const size_t NEED = 93215360;
  if (ws_size < NEED){ k_wssmall<<<1,64,0,stream>>>(out, 500.0f*304.0f); return; }

  // ---- workspace layout ----
  bf16* xw    = (bf16*) (ws);                    // 40,960,000 (first 80KB doubles as CSR 'cur' pre-gemm1)
  int*  cur   = (int*)  (ws);                    // aliases xw: live prep->scatter; xw live gemm1 onward
  bf16* act   = (bf16*) (ws + 40960000);         // -> 81,920,000
  bf16* Xc    = (bf16*) (ws + 81920000);         // -> 87,040,000 (dead after gemm1)
  float* esC  = (float*)(ws + 81920000);         // aliases Xc: 80,000 B (layer-3 logits, H=1)
  float* edC  = (float*)(ws + 82000000);         // aliases Xc: 80,000 B
  bf16* Wt1   = (bf16*) (ws + 87040000);         // -> 87,302,144
  bf16* Wt2   = (bf16*) (ws + 87302144);         // -> 89,399,296
  bf16* Wt3   = (bf16*) (ws + 89399296);         // -> 90,447,872
  float* prm  = (float*)(ws + 90447872);         // -> 90,494,976
  int*  flags = (int*)  (ws + 90494976);         // -> 90,495,232
  int*  eic   = (int*)  (ws + 90495232);         // -> 91,775,232 (dead after scatter)
  float* esB  = (float*)(ws + 90495232);         // aliases eic: 320,000 B (layer-2 logits)
  float* edB  = (float*)(ws + 90815232);         // aliases eic: 320,000 B
  float* esA  = (float*)(ws + 91775232);         // -> 92,095,232 (layer-1 logits)
  float* edA  = (float*)(ws + 92095232);         // -> 92,415,232
  int*  rp    = (int*)  (ws + 92415232);         // -> 92,495,360
  int*  col   = (int*)  (ws + 92495360);         // -> 93,215,360

  float *as1=prm+0, *ad1=prm+1024, *b1=prm+2048, *lg1=prm+3072, *lb1=prm+4096;
  float *as2=prm+5120, *ad2=prm+6144, *b2=prm+7168, *lg2=prm+8192, *lb2=prm+9216;
  float *as3=prm+10240, *ad3=prm+10752, *b3=prm+11264;

  const int TB = 256;
  int gbN = (NN + TB - 1)/TB;
  int gbE = (EE + TB - 1)/TB;

  // ---- detect ----
  {
    Ptrs P;
    for (int i=0;i<18;i++){ P.p[i]=d_in[i]; P.n[i]=in_sizes[i]; }
    k_detect<<<18, 64, 0, stream>>>(P, flags);
  }
  // ---- fused prep (incl. init_counts + zero esA/edA) ----
  {
    PrepArgs A;
    A.xraw = d_in[0]; A.Xc = Xc;
    A.w1raw = d_in[2]; A.Wt1 = Wt1;
    A.w2raw = d_in[8]; A.Wt2 = Wt2;
    A.w3raw = d_in[14]; A.Wt3 = Wt3;
    A.eiraw = (const int*)d_in[1]; A.eic = eic;
    const int idx[13] = {3,4,5,6,7, 9,10,11,12,13, 15,16,17};
    const int off[13] = {0,1024,2048,3072,4096, 5120,6144,7168,8192,9216, 10240,10752,11264};
    const int nn [13] = {1024,1024,1024,1024,1024, 1024,1024,1024,1024,1024, 512,512,512};
    for (int i=0;i<13;i++){ A.p13.src[i]=d_in[idx[i]]; A.p13.off[i]=off[i]; A.p13.n[i]=nn[i]; A.p13.fi[i]=idx[i]; }
    A.prm = prm; A.counts = cur; A.esA = esA; A.edA = edA; A.flags = flags;
    k_prep<<<13006 + 313, TB, 0, stream>>>(A);
  }

  // ---- CSR ----
  k_hist<<<gbE, TB, 0, stream>>>(eic, cur);
  k_scan<<<1, 1024, 0, stream>>>(cur, rp);
  k_selfloop<<<gbN, TB, 0, stream>>>(rp, cur, col);
  k_scatter<<<gbE, TB, 0, stream>>>(eic, cur, col);

  const int RB = (NN + 127)/128;                  // 157
  const int R8 = ((RB + 7)/8)*8;                  // 160 (padded, guard in kernel)
  dim3 g12(1024/128, R8);
  dim3 g3 (512/128,  R8);

  // ---- layer 1 (K=128) ----
  k_gemm_mfma<<<g12, TB, 0, stream>>>(Xc, Wt1, xw, as1, ad1, esA, edA, 128, 1024, 256, 4);
  k_aggln<<<NN/4, TB, 0, stream>>>(rp, col, xw, esA, edA, b1, lg1, lb1, act, esB, edB, 4);

  // ---- layer 2 (K=1024) ----
  k_gemm_mfma<<<g12, TB, 0, stream>>>(act, Wt2, xw, as2, ad2, esB, edB, 1024, 1024, 256, 4);
  k_aggln<<<NN/4, TB, 0, stream>>>(rp, col, xw, esB, edB, b2, lg2, lb2, act, esC, edC, 1);

  // ---- layer 3 (K=1024, M=512) ----
  k_gemm_mfma<<<g3, TB, 0, stream>>>(act, Wt3, xw, as3, ad3, esC, edC, 1024, 512, 512, 1);
  k_agg3<<<NN/4, TB, 0, stream>>>(rp, col, xw, esC, edC, b3, out);
}

// Round 15
// 473.505 us; speedup vs baseline: 2.9348x; 1.0000x over previous
//
#include <hip/hip_runtime.h>
#include <hip/hip_bf16.h>

typedef __hip_bfloat16 bf16;
typedef __attribute__((ext_vector_type(8))) short short8;
typedef __attribute__((ext_vector_type(4))) float float4v;

#define NN 20000
#define EE 160000
#define ET (NN + EE)

__device__ __forceinline__ float bf2f(bf16 v){ return __bfloat162float(v); }
__device__ __forceinline__ float raw2f(unsigned short u){ return __uint_as_float(((unsigned)u) << 16); }
__device__ __forceinline__ unsigned short f2raw(float f){
  bf16 h = __float2bfloat16(f);
  return *(unsigned short*)&h;
}

// ---------------- inline dtype detection (per-wave ballot; all waves agree) ----------------
__device__ __forceinline__ int detect_f32(const void* raw, int nwords, int lane){
  unsigned v = ((const unsigned*)raw)[lane % nwords];
  int e8 = (v >> 7) & 0xFF;
  int looks = (e8 >= 100 && e8 <= 140) ? 1 : 0;
  unsigned long long mz = __ballot(v == 0u);
  unsigned long long ml = __ballot(looks);
  int nz = __popcll(mz);
  int nonz = 64 - nz;
  int nl = __popcll(ml);
  return (nonz > 0 && 2*nl >= nonz) ? 0 : 1;
}

__device__ __forceinline__ int detect_i64(const int* eiraw, int lane){
  int odd = eiraw[2*lane + 1];
  unsigned long long m2 = __ballot(odd != 0);
  return (m2 == 0ULL) ? 1 : 0;
}

// ---------------- fused preprocessing kernel ----------------
struct P13 { const void* src[13]; int off[13]; int n[13]; };
struct PrepArgs {
  const void* xraw; bf16* Xc;
  const void* w1raw; bf16* Wt1;
  const void* w2raw; bf16* Wt2;
  const void* w3raw; bf16* Wt3;
  const int* eiraw; int* eic;
  P13 p13; float* prm;
  int* counts;
  float* esA; float* edA;
};

__device__ __forceinline__ void do_transpose(float (*tile)[33], const void* raw,
    bf16* wt, int K, int M, int f, int bx, int by, int t){
  int kb = by*32, mb = bx*32;
  int tx = t & 31, ty = t >> 5;   // 32 x 8
  for (int r = 0; r < 4; r++){
    int k = kb + ty + r*8;
    int m = mb + tx;
    float v = f ? ((const float*)raw)[(size_t)k*M+m] : bf2f(((const bf16*)raw)[(size_t)k*M+m]);
    tile[ty + r*8][tx] = v;
  }
  __syncthreads();
  for (int r = 0; r < 4; r++){
    int m = mb + ty + r*8;
    int k = kb + tx;
    wt[(size_t)m*K + k] = __float2bfloat16(tile[tx][ty + r*8]);
  }
}

__global__ __launch_bounds__(256) void k_prep(PrepArgs A){
  __shared__ float tile[32][33];
  int b = blockIdx.x, t = threadIdx.x;
  int lane = t & 63;
  if (b < 10000){                                 // cvt X -> bf16
    int f = detect_f32(A.xraw, NN*128/2, lane);
    int i = b*256 + t;
    if (f) A.Xc[i] = __float2bfloat16(((const float*)A.xraw)[i]);
    else   A.Xc[i] = ((const bf16*)A.xraw)[i];
  } else if (b < 10128){                          // transpose W1 [128][1024] -> [1024][128]
    int f = detect_f32(A.w1raw, 128*1024/2, lane);
    int r = b - 10000;
    do_transpose(tile, A.w1raw, A.Wt1, 128, 1024, f, r & 31, r >> 5, t);
  } else if (b < 11152){                          // transpose W2 [1024][1024]
    int f = detect_f32(A.w2raw, 1024*1024/2, lane);
    int r = b - 10128;
    do_transpose(tile, A.w2raw, A.Wt2, 1024, 1024, f, r & 31, r >> 5, t);
  } else if (b < 11664){                          // transpose W3 [1024][512] -> [512][1024]
    int f = detect_f32(A.w3raw, 1024*512/2, lane);
    int r = b - 11152;
    do_transpose(tile, A.w3raw, A.Wt3, 1024, 512, f, r & 15, r >> 4, t);
  } else if (b < 12914){                          // cvte
    int f64 = detect_i64(A.eiraw, lane);
    int i = (b - 11664)*256 + t;
    if (i < 2*EE) A.eic[i] = f64 ? A.eiraw[2*i] : A.eiraw[i];
  } else if (b < 12927){                          // params -> fp32
    int pb = b - 12914;
    const void* s = A.p13.src[pb];
    int n = A.p13.n[pb];
    int f = detect_f32(s, n/2, lane);
    float* d = A.prm + A.p13.off[pb];
    for (int i = t; i < n; i += 256)
      d[i] = f ? ((const float*)s)[i] : bf2f(((const bf16*)s)[i]);
  } else if (b < 13006){                          // init_counts
    int i = (b - 12927)*256 + t;
    if (i < NN) A.counts[i] = 1;
  } else {                                        // zero esA/edA (NN*4 floats each)
    int i = (b - 13006)*256 + t;
    if (i < NN*4){ A.esA[i] = 0.f; A.edA[i] = 0.f; }
  }
}

// ---------------- CSR build ----------------
__global__ void k_hist(const int* __restrict__ ei, int* __restrict__ counts){
  int e = blockIdx.x*256 + threadIdx.x;
  if (e < EE){
    int d = ei[EE + e];
    if (d >= 0 && d < NN) atomicAdd(&counts[d], 1);
  }
}

// scan + self-loop insertion fused; counts/rp/cursor/col are DISTINCT buffers (no aliasing)
__global__ __launch_bounds__(1024) void k_scan(const int* __restrict__ counts, int* __restrict__ rp,
    int* __restrict__ cursor, int* __restrict__ col){
  __shared__ int wsum[16];
  __shared__ int sc;
  int t = threadIdx.x, lane = t & 63, wv = t >> 6;
  if (t == 0) sc = 0;
  __syncthreads();
  for (int base = 0; base < NN; base += 1024){
    int i = base + t;
    int v = (i < NN) ? counts[i] : 0;
    int x = v;
    #pragma unroll
    for (int o = 1; o < 64; o <<= 1){
      int y = __shfl_up(x, o, 64);
      if (lane >= o) x += y;
    }
    if (lane == 63) wsum[wv] = x;
    __syncthreads();
    if (wv == 0 && lane < 16){
      int w = wsum[lane];
      #pragma unroll
      for (int o = 1; o < 16; o <<= 1){
        int y = __shfl_up(w, o, 16);
        if ((lane & 15) >= o) w += y;
      }
      wsum[lane] = w;
    }
    __syncthreads();
    int carry = sc;
    int wpre = (wv > 0) ? wsum[wv-1] : 0;
    if (i < NN){
      int p = carry + wpre + x - v;   // exclusive
      rp[i] = p;
      col[p] = i;                     // self loop at segment head
      cursor[i] = p + 1;
    }
    __syncthreads();
    if (t == 1023) sc = carry + wsum[15];
    __syncthreads();
  }
  if (t == 0) rp[NN] = sc;
}

__global__ void k_scatter(const int* __restrict__ ei, int* __restrict__ cursor, int* __restrict__ col){
  int e = blockIdx.x*256 + threadIdx.x;
  if (e < EE){
    int s = ei[e], d = ei[EE + e];
    if (d >= 0 && d < NN){
      int pos = atomicAdd(&cursor[d], 1);
      col[pos] = s;
    }
  }
}

// ---------------- MFMA GEMM: BK=64, XOR-swizzled LDS, fused fp32 es/ed epilogue ----------------
__global__ __launch_bounds__(256) void k_gemm_mfma(
    const bf16* __restrict__ X, const bf16* __restrict__ Wt, bf16* __restrict__ Y,
    const float* __restrict__ as_, const float* __restrict__ ad_,
    float* __restrict__ es, float* __restrict__ ed,
    int K, int M, int C, int H)
{
  __shared__ bf16 Xs[128*64];   // 16 KB
  __shared__ bf16 Bs[128*64];   // 16 KB
  int ncols = gridDim.x;
  int bid = blockIdx.y * ncols + blockIdx.x;
  int xcd  = bid & 7;
  int rest = bid >> 3;
  int colb = rest % ncols;
  int rowb = xcd + 8 * (rest / ncols);
  int r0 = rowb * 128;
  if (r0 >= NN) return;
  int c0 = colb * 128;

  int tid  = threadIdx.x;
  int wave = tid >> 6, lane = tid & 63;
  int quad = lane >> 4, l15 = lane & 15;
  int wr = (wave >> 1) * 64;
  int wc = (wave & 1) * 64;
  int sw = l15 & 7;

  float4v acc[4][4];
  #pragma unroll
  for (int i=0;i<4;i++)
    #pragma unroll
    for (int j=0;j<4;j++)
      acc[i][j] = (float4v){0.f,0.f,0.f,0.f};

  for (int k0 = 0; k0 < K; k0 += 64){
    #pragma unroll
    for (int i = 0; i < 4; i++){
      int ch = i*256 + tid;               // 0..1023, 16B chunks
      int row = ch >> 3, kl = ch & 7;
      int kg = kl ^ (row & 7);            // swizzled source chunk
      const bf16* gx = X  + (size_t)(r0 + row)*K + k0 + kg*8;
      const bf16* gb = Wt + (size_t)(c0 + row)*K + k0 + kg*8;
      __builtin_amdgcn_global_load_lds(
        (const __attribute__((address_space(1))) unsigned int*)gx,
        (__attribute__((address_space(3))) unsigned int*)(Xs + ch*8), 16, 0, 0);
      __builtin_amdgcn_global_load_lds(
        (const __attribute__((address_space(1))) unsigned int*)gb,
        (__attribute__((address_space(3))) unsigned int*)(Bs + ch*8), 16, 0, 0);
    }
    __syncthreads();

    #pragma unroll
    for (int kk = 0; kk < 2; kk++){       // two 32-wide K slices, in order (bit-identical accum)
      int kp = quad + kk*4;
      short8 af[4], bfr[4];
      #pragma unroll
      for (int i = 0; i < 4; i++){
        int r = wr + i*16 + l15;
        af[i] = *(const short8*)(Xs + ((size_t)r*8 + (kp ^ sw))*8);
      }
      #pragma unroll
      for (int j = 0; j < 4; j++){
        int r = wc + j*16 + l15;
        bfr[j] = *(const short8*)(Bs + ((size_t)r*8 + (kp ^ sw))*8);
      }
      #pragma unroll
      for (int i = 0; i < 4; i++)
        #pragma unroll
        for (int j = 0; j < 4; j++)
          acc[i][j] = __builtin_amdgcn_mfma_f32_16x16x32_bf16(af[i], bfr[j], acc[i][j], 0, 0, 0);
    }
    __syncthreads();
  }

  int h = c0 / C;
  float asv[4], adv[4];
  #pragma unroll
  for (int j = 0; j < 4; j++){
    int colj = c0 + wc + j*16 + l15;
    asv[j] = as_[colj]; adv[j] = ad_[colj];
  }
  #pragma unroll
  for (int i = 0; i < 4; i++){
    int rbase = r0 + wr + i*16 + quad*4;
    #pragma unroll
    for (int rg = 0; rg < 4; rg++){
      int row = rbase + rg;
      bool ok = (row < NN);
      float pe = 0.f, pd = 0.f;
      #pragma unroll
      for (int j = 0; j < 4; j++){
        float v = acc[i][j][rg];
        int colj = c0 + wc + j*16 + l15;
        if (ok) Y[(size_t)row*M + colj] = __float2bfloat16(v);
        pe += v * asv[j];
        pd += v * adv[j];
      }
      #pragma unroll
      for (int o = 1; o < 16; o <<= 1){
        pe += __shfl_xor(pe, o, 64);
        pd += __shfl_xor(pd, o, 64);
      }
      if (ok && l15 == 0){
        atomicAdd(&es[row*H + h], pe);
        atomicAdd(&ed[row*H + h], pd);
      }
    }
  }
}

// ---------------- wave-per-node softmax+aggregate+bias+LN+ELU (layers 1,2; H=4) ----------------
__global__ __launch_bounds__(256) void k_aggln(const int* __restrict__ rp, const int* __restrict__ col,
    const bf16* __restrict__ xw, const float* __restrict__ es, const float* __restrict__ ed,
    const float* __restrict__ bias, const float* __restrict__ gam, const float* __restrict__ bet,
    bf16* __restrict__ act, float* __restrict__ esz, float* __restrict__ edz, int zn){
  int wv = threadIdx.x >> 6, lane = threadIdx.x & 63;
  int n = blockIdx.x*4 + wv;              // NN % 4 == 0
  int h = lane >> 4;
  int cb = lane * 16;
  int e0 = rp[n], e1 = rp[n+1], deg = e1 - e0;
  float4 ed4 = *(const float4*)&ed[n*4];
  const unsigned short* xwu = (const unsigned short*)xw;

  float acc[16];
  #pragma unroll
  for (int c=0;c<16;c++) acc[c]=0.f;

  if (deg <= 64){
    int src = 0;
    float l0=-1e30f, l1=-1e30f, l2=-1e30f, l3=-1e30f;
    if (lane < deg){
      src = col[e0 + lane];
      float4 e4 = *(const float4*)&es[src*4];
      float v;
      v = e4.x + ed4.x; l0 = v > 0.f ? v : 0.2f*v;
      v = e4.y + ed4.y; l1 = v > 0.f ? v : 0.2f*v;
      v = e4.z + ed4.z; l2 = v > 0.f ? v : 0.2f*v;
      v = e4.w + ed4.w; l3 = v > 0.f ? v : 0.2f*v;
    }
    float m0=l0, m1=l1, m2=l2, m3=l3;
    #pragma unroll
    for (int o=1;o<64;o<<=1){
      m0 = fmaxf(m0, __shfl_xor(m0,o,64));
      m1 = fmaxf(m1, __shfl_xor(m1,o,64));
      m2 = fmaxf(m2, __shfl_xor(m2,o,64));
      m3 = fmaxf(m3, __shfl_xor(m3,o,64));
    }
    float p0 = (lane<deg) ? __expf(l0-m0) : 0.f;
    float p1 = (lane<deg) ? __expf(l1-m1) : 0.f;
    float p2 = (lane<deg) ? __expf(l2-m2) : 0.f;
    float p3 = (lane<deg) ? __expf(l3-m3) : 0.f;
    float d0=p0, d1=p1, d2=p2, d3=p3;
    #pragma unroll
    for (int o=1;o<64;o<<=1){
      d0 += __shfl_xor(d0,o,64);
      d1 += __shfl_xor(d1,o,64);
      d2 += __shfl_xor(d2,o,64);
      d3 += __shfl_xor(d3,o,64);
    }
    float al0 = p0 * (1.f/(d0+1e-16f));
    float al1 = p1 * (1.f/(d1+1e-16f));
    float al2 = p2 * (1.f/(d2+1e-16f));
    float al3 = p3 * (1.f/(d3+1e-16f));

    // unroll-2 gather loop; per-channel FMA order (j then j+1) identical to serial
    int j = 0;
    for (; j + 2 <= deg; j += 2){
      int sA = __shfl(src, j, 64);
      int sB = __shfl(src, j+1, 64);
      float a0A = __shfl(al0, j, 64), a1A = __shfl(al1, j, 64);
      float a2A = __shfl(al2, j, 64), a3A = __shfl(al3, j, 64);
      float a0B = __shfl(al0, j+1, 64), a1B = __shfl(al1, j+1, 64);
      float a2B = __shfl(al2, j+1, 64), a3B = __shfl(al3, j+1, 64);
      float aA = (h==0) ? a0A : ((h==1) ? a1A : ((h==2) ? a2A : a3A));
      float aB = (h==0) ? a0B : ((h==1) ? a1B : ((h==2) ? a2B : a3B));
      const unsigned short* rA = xwu + (size_t)sA*1024 + cb;
      const unsigned short* rB = xwu + (size_t)sB*1024 + cb;
      ushort4 uA0 = *(const ushort4*)(rA);
      ushort4 uA1 = *(const ushort4*)(rA+4);
      ushort4 uA2 = *(const ushort4*)(rA+8);
      ushort4 uA3 = *(const ushort4*)(rA+12);
      ushort4 uB0 = *(const ushort4*)(rB);
      ushort4 uB1 = *(const ushort4*)(rB+4);
      ushort4 uB2 = *(const ushort4*)(rB+8);
      ushort4 uB3 = *(const ushort4*)(rB+12);
      acc[0] += aA*raw2f(uA0.x); acc[1] += aA*raw2f(uA0.y); acc[2] += aA*raw2f(uA0.z); acc[3] += aA*raw2f(uA0.w);
      acc[4] += aA*raw2f(uA1.x); acc[5] += aA*raw2f(uA1.y); acc[6] += aA*raw2f(uA1.z); acc[7] += aA*raw2f(uA1.w);
      acc[8] += aA*raw2f(uA2.x); acc[9] += aA*raw2f(uA2.y); acc[10]+= aA*raw2f(uA2.z); acc[11]+= aA*raw2f(uA2.w);
      acc[12]+= aA*raw2f(uA3.x); acc[13]+= aA*raw2f(uA3.y); acc[14]+= aA*raw2f(uA3.z); acc[15]+= aA*raw2f(uA3.w);
      acc[0] += aB*raw2f(uB0.x); acc[1] += aB*raw2f(uB0.y); acc[2] += aB*raw2f(uB0.z); acc[3] += aB*raw2f(uB0.w);
      acc[4] += aB*raw2f(uB1.x); acc[5] += aB*raw2f(uB1.y); acc[6] += aB*raw2f(uB1.z); acc[7] += aB*raw2f(uB1.w);
      acc[8] += aB*raw2f(uB2.x); acc[9] += aB*raw2f(uB2.y); acc[10]+= aB*raw2f(uB2.z); acc[11]+= aB*raw2f(uB2.w);
      acc[12]+= aB*raw2f(uB3.x); acc[13]+= aB*raw2f(uB3.y); acc[14]+= aB*raw2f(uB3.z); acc[15]+= aB*raw2f(uB3.w);
    }
    for (; j < deg; j++){
      int s = __shfl(src, j, 64);
      float a0j = __shfl(al0, j, 64);
      float a1j = __shfl(al1, j, 64);
      float a2j = __shfl(al2, j, 64);
      float a3j = __shfl(al3, j, 64);
      float aj = (h==0) ? a0j : ((h==1) ? a1j : ((h==2) ? a2j : a3j));
      const unsigned short* row = xwu + (size_t)s*1024 + cb;
      ushort4 u0 = *(const ushort4*)(row);
      ushort4 u1 = *(const ushort4*)(row+4);
      ushort4 u2 = *(const ushort4*)(row+8);
      ushort4 u3 = *(const ushort4*)(row+12);
      acc[0] += aj*raw2f(u0.x); acc[1] += aj*raw2f(u0.y); acc[2] += aj*raw2f(u0.z); acc[3] += aj*raw2f(u0.w);
      acc[4] += aj*raw2f(u1.x); acc[5] += aj*raw2f(u1.y); acc[6] += aj*raw2f(u1.z); acc[7] += aj*raw2f(u1.w);
      acc[8] += aj*raw2f(u2.x); acc[9] += aj*raw2f(u2.y); acc[10]+= aj*raw2f(u2.z); acc[11]+= aj*raw2f(u2.w);
      acc[12]+= aj*raw2f(u3.x); acc[13]+= aj*raw2f(u3.y); acc[14]+= aj*raw2f(u3.z); acc[15]+= aj*raw2f(u3.w);
    }
  } else {
    float edh = (h==0) ? ed4.x : ((h==1) ? ed4.y : ((h==2) ? ed4.z : ed4.w));
    float m = -1e30f;
    for (int e=e0;e<e1;e++){
      float v = es[col[e]*4 + h] + edh;
      v = v > 0.f ? v : 0.2f*v;
      m = fmaxf(m, v);
    }
    float den = 0.f;
    for (int e=e0;e<e1;e++){
      float v = es[col[e]*4 + h] + edh;
      v = v > 0.f ? v : 0.2f*v;
      den += __expf(v - m);
    }
    float rd = 1.f/(den + 1e-16f);
    for (int e=e0;e<e1;e++){
      int s = col[e];
      float v = es[s*4 + h] + edh;
      v = v > 0.f ? v : 0.2f*v;
      float aj = __expf(v - m) * rd;
      const unsigned short* row = xwu + (size_t)s*1024 + cb;
      ushort4 u0 = *(const ushort4*)(row);
      ushort4 u1 = *(const ushort4*)(row+4);
      ushort4 u2 = *(const ushort4*)(row+8);
      ushort4 u3 = *(const ushort4*)(row+12);
      acc[0] += aj*raw2f(u0.x); acc[1] += aj*raw2f(u0.y); acc[2] += aj*raw2f(u0.z); acc[3] += aj*raw2f(u0.w);
      acc[4] += aj*raw2f(u1.x); acc[5] += aj*raw2f(u1.y); acc[6] += aj*raw2f(u1.z); acc[7] += aj*raw2f(u1.w);
      acc[8] += aj*raw2f(u2.x); acc[9] += aj*raw2f(u2.y); acc[10]+= aj*raw2f(u2.z); acc[11]+= aj*raw2f(u2.w);
      acc[12]+= aj*raw2f(u3.x); acc[13]+= aj*raw2f(u3.y); acc[14]+= aj*raw2f(u3.z); acc[15]+= aj*raw2f(u3.w);
    }
  }

  #pragma unroll
  for (int c=0;c<16;c++) acc[c] += bias[cb+c];
  float s1 = 0.f, s2 = 0.f;
  #pragma unroll
  for (int c=0;c<16;c++){ s1 += acc[c]; s2 += acc[c]*acc[c]; }
  #pragma unroll
  for (int o=1;o<64;o<<=1){
    s1 += __shfl_xor(s1,o,64);
    s2 += __shfl_xor(s2,o,64);
  }
  float mu  = s1 * (1.f/1024.f);
  float var = s2 * (1.f/1024.f) - mu*mu;
  float rstd = rsqrtf(fmaxf(var, 0.f) + 1e-5f);

  ushort4 o4[4];
  #pragma unroll
  for (int q=0;q<4;q++){
    float v0 = (acc[q*4+0]-mu)*rstd*gam[cb+q*4+0] + bet[cb+q*4+0];
    float v1 = (acc[q*4+1]-mu)*rstd*gam[cb+q*4+1] + bet[cb+q*4+1];
    float v2 = (acc[q*4+2]-mu)*rstd*gam[cb+q*4+2] + bet[cb+q*4+2];
    float v3 = (acc[q*4+3]-mu)*rstd*gam[cb+q*4+3] + bet[cb+q*4+3];
    v0 = v0 > 0.f ? v0 : (__expf(v0)-1.f);
    v1 = v1 > 0.f ? v1 : (__expf(v1)-1.f);
    v2 = v2 > 0.f ? v2 : (__expf(v2)-1.f);
    v3 = v3 > 0.f ? v3 : (__expf(v3)-1.f);
    o4[q].x = f2raw(v0); o4[q].y = f2raw(v1); o4[q].z = f2raw(v2); o4[q].w = f2raw(v3);
  }
  unsigned short* dst = (unsigned short*)act + (size_t)n*1024 + cb;
  *(ushort4*)(dst)    = o4[0];
  *(ushort4*)(dst+4)  = o4[1];
  *(ushort4*)(dst+8)  = o4[2];
  *(ushort4*)(dst+12) = o4[3];

  // zero next layer's logit slots for this node (exclusive ownership; read next dispatch)
  if (lane < zn){ esz[n*zn + lane] = 0.f; edz[n*zn + lane] = 0.f; }
}

// ---------------- wave-per-node layer-3: softmax + aggregate + bias -> fp32 out (H=1) ----------------
__global__ __launch_bounds__(256) void k_agg3(const int* __restrict__ rp, const int* __restrict__ col,
    const bf16* __restrict__ xw, const float* __restrict__ es, const float* __restrict__ ed,
    const float* __restrict__ bias, float* __restrict__ out){
  int wv = threadIdx.x >> 6, lane = threadIdx.x & 63;
  int n = blockIdx.x*4 + wv;
  int cb = lane * 8;
  int e0 = rp[n], e1 = rp[n+1], deg = e1 - e0;
  float edv = ed[n];
  const unsigned short* xwu = (const unsigned short*)xw;

  float acc[8];
  #pragma unroll
  for (int c=0;c<8;c++) acc[c]=0.f;

  if (deg <= 64){
    int src = 0;
    float l = -1e30f;
    if (lane < deg){
      src = col[e0 + lane];
      float v = es[src] + edv;
      l = v > 0.f ? v : 0.2f*v;
    }
    float m = l;
    #pragma unroll
    for (int o=1;o<64;o<<=1) m = fmaxf(m, __shfl_xor(m,o,64));
    float p = (lane<deg) ? __expf(l-m) : 0.f;
    float d = p;
    #pragma unroll
    for (int o=1;o<64;o<<=1) d += __shfl_xor(d,o,64);
    float al = p * (1.f/(d+1e-16f));

    int j = 0;
    for (; j + 2 <= deg; j += 2){
      int sA = __shfl(src, j, 64);
      int sB = __shfl(src, j+1, 64);
      float aA = __shfl(al, j, 64);
      float aB = __shfl(al, j+1, 64);
      const unsigned short* rA = xwu + (size_t)sA*512 + cb;
      const unsigned short* rB = xwu + (size_t)sB*512 + cb;
      ushort4 uA0 = *(const ushort4*)(rA);
      ushort4 uA1 = *(const ushort4*)(rA+4);
      ushort4 uB0 = *(const ushort4*)(rB);
      ushort4 uB1 = *(const ushort4*)(rB+4);
      acc[0] += aA*raw2f(uA0.x); acc[1] += aA*raw2f(uA0.y); acc[2] += aA*raw2f(uA0.z); acc[3] += aA*raw2f(uA0.w);
      acc[4] += aA*raw2f(uA1.x); acc[5] += aA*raw2f(uA1.y); acc[6] += aA*raw2f(uA1.z); acc[7] += aA*raw2f(uA1.w);
      acc[0] += aB*raw2f(uB0.x); acc[1] += aB*raw2f(uB0.y); acc[2] += aB*raw2f(uB0.z); acc[3] += aB*raw2f(uB0.w);
      acc[4] += aB*raw2f(uB1.x); acc[5] += aB*raw2f(uB1.y); acc[6] += aB*raw2f(uB1.z); acc[7] += aB*raw2f(uB1.w);
    }
    for (; j < deg; j++){
      int s = __shfl(src, j, 64);
      float aj = __shfl(al, j, 64);
      const unsigned short* row = xwu + (size_t)s*512 + cb;
      ushort4 u0 = *(const ushort4*)(row);
      ushort4 u1 = *(const ushort4*)(row+4);
      acc[0] += aj*raw2f(u0.x); acc[1] += aj*raw2f(u0.y); acc[2] += aj*raw2f(u0.z); acc[3] += aj*raw2f(u0.w);
      acc[4] += aj*raw2f(u1.x); acc[5] += aj*raw2f(u1.y); acc[6] += aj*raw2f(u1.z); acc[7] += aj*raw2f(u1.w);
    }
  } else {
    float m = -1e30f;
    for (int e=e0;e<e1;e++){
      float v = es[col[e]] + edv;
      v = v > 0.f ? v : 0.2f*v;
      m = fmaxf(m, v);
    }
    float den = 0.f;
    for (int e=e0;e<e1;e++){
      float v = es[col[e]] + edv;
      v = v > 0.f ? v : 0.2f*v;
      den += __expf(v - m);
    }
    float rd = 1.f/(den + 1e-16f);
    for (int e=e0;e<e1;e++){
      int s = col[e];
      float v = es[s] + edv;
      v = v > 0.f ? v : 0.2f*v;
      float aj = __expf(v - m) * rd;
      const unsigned short* row = xwu + (size_t)s*512 + cb;
      ushort4 u0 = *(const ushort4*)(row);
      ushort4 u1 = *(const ushort4*)(row+4);
      acc[0] += aj*raw2f(u0.x); acc[1] += aj*raw2f(u0.y); acc[2] += aj*raw2f(u0.z); acc[3] += aj*raw2f(u0.w);
      acc[4] += aj*raw2f(u1.x); acc[5] += aj*raw2f(u1.y); acc[6] += aj*raw2f(u1.z); acc[7] += aj*raw2f(u1.w);
    }
  }
  float* dst = out + (size_t)n*512 + cb;
  #pragma unroll
  for (int c=0;c<8;c++) dst[c] = acc[c] + bias[cb+c];
}

__global__ void k_wssmall(float* __restrict__ out, float code){
  if (threadIdx.x == 0) out[0] = code;
}

// ---------------- launch ----------------
extern "C" void kernel_launch(void* const* d_in, const int* in_sizes, int n_in,
                              void* d_out, int out_size, void* d_ws, size_t ws_size,
                              hipStream_t stream){
  float* out = (float*)d_out;
  char* ws = (char*)d_ws;

  static const int EXP_SZ[18] = {2560000, 320000, 131072, 1024,1024,1024,1024,1024,
                                 1048576, 1024,1024,1024,1024,1024,
                                 524288, 512,512,512};
  if (n_in != 18){ k_wssmall<<<1,64,0,stream>>>(out, 500.0f*301.0f); return; }
  for (int i = 0; i < 18; i++)
    if (in_sizes[i] != EXP_SZ[i]){ k_wssmall<<<1,64,0,stream>>>(out, 500.0f*302.0f); return; }
  if (out_size != NN*512){ k_wssmall<<<1,64,0,stream>>>(out, 500.0f*303.0f); return; }
  const size_t NEED = 93215360;
  if (ws_size < NEED){ k_wssmall<<<1,64,0,stream>>>(out, 500.0f*304.0f); return; }

  // ---- workspace layout ----
  bf16* xw    = (bf16*) (ws);                    // 40,960,000 (first 80KB doubles as CSR 'counts' pre-gemm1)
  int*  cnt   = (int*)  (ws);                    // aliases xw: counts, live prep->scan
  bf16* act   = (bf16*) (ws + 40960000);         // -> 81,920,000 (first 80KB doubles as CSR 'cursor')
  int*  cursor= (int*)  (ws + 40960000);         // aliases act: live scan->scatter; act live aggln1 onward
  bf16* Xc    = (bf16*) (ws + 81920000);         // -> 87,040,000 (dead after gemm1)
  float* esC  = (float*)(ws + 81920000);         // aliases Xc: 80,000 B (layer-3 logits, H=1)
  float* edC  = (float*)(ws + 82000000);         // aliases Xc: 80,000 B
  bf16* Wt1   = (bf16*) (ws + 87040000);         // -> 87,302,144
  bf16* Wt2   = (bf16*) (ws + 87302144);         // -> 89,399,296
  bf16* Wt3   = (bf16*) (ws + 89399296);         // -> 90,447,872
  float* prm  = (float*)(ws + 90447872);         // -> 90,494,976
  int*  eic   = (int*)  (ws + 90495232);         // -> 91,775,232 (dead after scatter)
  float* esB  = (float*)(ws + 90495232);         // aliases eic: 320,000 B (layer-2 logits)
  float* edB  = (float*)(ws + 90815232);         // aliases eic: 320,000 B
  float* esA  = (float*)(ws + 91775232);         // -> 92,095,232 (layer-1 logits)
  float* edA  = (float*)(ws + 92095232);         // -> 92,415,232
  int*  rp    = (int*)  (ws + 92415232);         // -> 92,495,360
  int*  col   = (int*)  (ws + 92495360);         // -> 93,215,360

  float *as1=prm+0, *ad1=prm+1024, *b1=prm+2048, *lg1=prm+3072, *lb1=prm+4096;
  float *as2=prm+5120, *ad2=prm+6144, *b2=prm+7168, *lg2=prm+8192, *lb2=prm+9216;
  float *as3=prm+10240, *ad3=prm+10752, *b3=prm+11264;

  const int TB = 256;
  int gbE = (EE + TB - 1)/TB;

  // ---- fused prep (inline dtype detect; incl. init_counts + zero esA/edA) ----
  {
    PrepArgs A;
    A.xraw = d_in[0]; A.Xc = Xc;
    A.w1raw = d_in[2]; A.Wt1 = Wt1;
    A.w2raw = d_in[8]; A.Wt2 = Wt2;
    A.w3raw = d_in[14]; A.Wt3 = Wt3;
    A.eiraw = (const int*)d_in[1]; A.eic = eic;
    const int idx[13] = {3,4,5,6,7, 9,10,11,12,13, 15,16,17};
    const int off[13] = {0,1024,2048,3072,4096, 5120,6144,7168,8192,9216, 10240,10752,11264};
    const int nn [13] = {1024,1024,1024,1024,1024, 1024,1024,1024,1024,1024, 512,512,512};
    for (int i=0;i<13;i++){ A.p13.src[i]=d_in[idx[i]]; A.p13.off[i]=off[i]; A.p13.n[i]=nn[i]; }
    A.prm = prm; A.counts = cnt; A.esA = esA; A.edA = edA;
    k_prep<<<13006 + 313, TB, 0, stream>>>(A);
  }

  // ---- CSR ----
  k_hist<<<gbE, TB, 0, stream>>>(eic, cnt);
  k_scan<<<1, 1024, 0, stream>>>(cnt, rp, cursor, col);
  k_scatter<<<gbE, TB, 0, stream>>>(eic, cursor, col);

  const int RB = (NN + 127)/128;                  // 157
  const int R8 = ((RB + 7)/8)*8;                  // 160 (padded, guard in kernel)
  dim3 g12(1024/128, R8);
  dim3 g3 (512/128,  R8);

  // ---- layer 1 (K=128) ----
  k_gemm_mfma<<<g12, TB, 0, stream>>>(Xc, Wt1, xw, as1, ad1, esA, edA, 128, 1024, 256, 4);
  k_aggln<<<NN/4, TB, 0, stream>>>(rp, col, xw, esA, edA, b1, lg1, lb1, act, esB, edB, 4);

  // ---- layer 2 (K=1024) ----
  k_gemm_mfma<<<g12, TB, 0, stream>>>(act, Wt2, xw, as2, ad2, esB, edB, 1024, 1024, 256, 4);
  k_aggln<<<NN/4, TB, 0, stream>>>(rp, col, xw, esB, edB, b2, lg2, lb2, act, esC, edC, 1);

  // ---- layer 3 (K=1024, M=512) ----
  k_gemm_mfma<<<g3, TB, 0, stream>>>(act, Wt3, xw, as3, ad3, esC, edC, 1024, 512, 512, 1);
  k_agg3<<<NN/4, TB, 0, stream>>>(rp, col, xw, esC, edC, b3, out);
}

// Round 16
// 442.330 us; speedup vs baseline: 3.1417x; 1.0705x over previous
//
#include <hip/hip_runtime.h>
#include <hip/hip_bf16.h>

typedef __hip_bfloat16 bf16;
typedef __attribute__((ext_vector_type(8))) short short8;
typedef __attribute__((ext_vector_type(4))) float float4v;

#define NN 20000
#define EE 160000
#define ET (NN + EE)

__device__ __forceinline__ float bf2f(bf16 v){ return __bfloat162float(v); }
__device__ __forceinline__ float raw2f(unsigned short u){ return __uint_as_float(((unsigned)u) << 16); }
__device__ __forceinline__ unsigned short f2raw(float f){
  bf16 h = __float2bfloat16(f);
  return *(unsigned short*)&h;
}

// ---------------- inline dtype detection (per-wave ballot; all waves agree) ----------------
__device__ __forceinline__ int detect_f32(const void* raw, int nwords, int lane){
  unsigned v = ((const unsigned*)raw)[lane % nwords];
  int e8 = (v >> 7) & 0xFF;
  int looks = (e8 >= 100 && e8 <= 140) ? 1 : 0;
  unsigned long long mz = __ballot(v == 0u);
  unsigned long long ml = __ballot(looks);
  int nz = __popcll(mz);
  int nonz = 64 - nz;
  int nl = __popcll(ml);
  return (nonz > 0 && 2*nl >= nonz) ? 0 : 1;
}

__device__ __forceinline__ int detect_i64(const int* eiraw, int lane){
  int odd = eiraw[2*lane + 1];
  unsigned long long m2 = __ballot(odd != 0);
  return (m2 == 0ULL) ? 1 : 0;
}

// ---------------- fused preprocessing kernel ----------------
struct P13 { const void* src[13]; int off[13]; int n[13]; };
struct PrepArgs {
  const void* xraw; bf16* Xc;
  const void* w1raw; bf16* Wt1;
  const void* w2raw; bf16* Wt2;
  const void* w3raw; bf16* Wt3;
  const int* eiraw; int* eic;
  P13 p13; float* prm;
  int* counts;
  float* esA; float* edA;
};

__device__ __forceinline__ void do_transpose(float (*tile)[33], const void* raw,
    bf16* wt, int K, int M, int f, int bx, int by, int t){
  int kb = by*32, mb = bx*32;
  int tx = t & 31, ty = t >> 5;   // 32 x 8
  for (int r = 0; r < 4; r++){
    int k = kb + ty + r*8;
    int m = mb + tx;
    float v = f ? ((const float*)raw)[(size_t)k*M+m] : bf2f(((const bf16*)raw)[(size_t)k*M+m]);
    tile[ty + r*8][tx] = v;
  }
  __syncthreads();
  for (int r = 0; r < 4; r++){
    int m = mb + ty + r*8;
    int k = kb + tx;
    wt[(size_t)m*K + k] = __float2bfloat16(tile[tx][ty + r*8]);
  }
}

__global__ __launch_bounds__(256) void k_prep(PrepArgs A){
  __shared__ float tile[32][33];
  int b = blockIdx.x, t = threadIdx.x;
  int lane = t & 63;
  if (b < 10000){                                 // cvt X -> bf16
    int f = detect_f32(A.xraw, NN*128/2, lane);
    int i = b*256 + t;
    if (f) A.Xc[i] = __float2bfloat16(((const float*)A.xraw)[i]);
    else   A.Xc[i] = ((const bf16*)A.xraw)[i];
  } else if (b < 10128){                          // transpose W1 [128][1024] -> [1024][128]
    int f = detect_f32(A.w1raw, 128*1024/2, lane);
    int r = b - 10000;
    do_transpose(tile, A.w1raw, A.Wt1, 128, 1024, f, r & 31, r >> 5, t);
  } else if (b < 11152){                          // transpose W2 [1024][1024]
    int f = detect_f32(A.w2raw, 1024*1024/2, lane);
    int r = b - 10128;
    do_transpose(tile, A.w2raw, A.Wt2, 1024, 1024, f, r & 31, r >> 5, t);
  } else if (b < 11664){                          // transpose W3 [1024][512] -> [512][1024]
    int f = detect_f32(A.w3raw, 1024*512/2, lane);
    int r = b - 11152;
    do_transpose(tile, A.w3raw, A.Wt3, 1024, 512, f, r & 15, r >> 4, t);
  } else if (b < 12914){                          // cvte
    int f64 = detect_i64(A.eiraw, lane);
    int i = (b - 11664)*256 + t;
    if (i < 2*EE) A.eic[i] = f64 ? A.eiraw[2*i] : A.eiraw[i];
  } else if (b < 12927){                          // params -> fp32
    int pb = b - 12914;
    const void* s = A.p13.src[pb];
    int n = A.p13.n[pb];
    int f = detect_f32(s, n/2, lane);
    float* d = A.prm + A.p13.off[pb];
    for (int i = t; i < n; i += 256)
      d[i] = f ? ((const float*)s)[i] : bf2f(((const bf16*)s)[i]);
  } else if (b < 13006){                          // init_counts
    int i = (b - 12927)*256 + t;
    if (i < NN) A.counts[i] = 1;
  } else {                                        // zero esA/edA (NN*4 floats each)
    int i = (b - 13006)*256 + t;
    if (i < NN*4){ A.esA[i] = 0.f; A.edA[i] = 0.f; }
  }
}

// ---------------- CSR build ----------------
__global__ void k_hist(const int* __restrict__ ei, int* __restrict__ counts){
  int e = blockIdx.x*256 + threadIdx.x;
  if (e < EE){
    int d = ei[EE + e];
    if (d >= 0 && d < NN) atomicAdd(&counts[d], 1);
  }
}

// scan + self-loop insertion fused; counts/rp/cursor/col are DISTINCT buffers (no aliasing)
__global__ __launch_bounds__(1024) void k_scan(const int* __restrict__ counts, int* __restrict__ rp,
    int* __restrict__ cursor, int* __restrict__ col){
  __shared__ int wsum[16];
  __shared__ int sc;
  int t = threadIdx.x, lane = t & 63, wv = t >> 6;
  if (t == 0) sc = 0;
  __syncthreads();
  for (int base = 0; base < NN; base += 1024){
    int i = base + t;
    int v = (i < NN) ? counts[i] : 0;
    int x = v;
    #pragma unroll
    for (int o = 1; o < 64; o <<= 1){
      int y = __shfl_up(x, o, 64);
      if (lane >= o) x += y;
    }
    if (lane == 63) wsum[wv] = x;
    __syncthreads();
    if (wv == 0 && lane < 16){
      int w = wsum[lane];
      #pragma unroll
      for (int o = 1; o < 16; o <<= 1){
        int y = __shfl_up(w, o, 16);
        if ((lane & 15) >= o) w += y;
      }
      wsum[lane] = w;
    }
    __syncthreads();
    int carry = sc;
    int wpre = (wv > 0) ? wsum[wv-1] : 0;
    if (i < NN){
      int p = carry + wpre + x - v;   // exclusive
      rp[i] = p;
      col[p] = i;                     // self loop at segment head
      cursor[i] = p + 1;
    }
    __syncthreads();
    if (t == 1023) sc = carry + wsum[15];
    __syncthreads();
  }
  if (t == 0) rp[NN] = sc;
}

__global__ void k_scatter(const int* __restrict__ ei, int* __restrict__ cursor, int* __restrict__ col){
  int e = blockIdx.x*256 + threadIdx.x;
  if (e < EE){
    int s = ei[e], d = ei[EE + e];
    if (d >= 0 && d < NN){
      int pos = atomicAdd(&cursor[d], 1);
      col[pos] = s;
    }
  }
}

// ---------------- MFMA GEMM: 64x128 tile, BK=64, XOR-swizzled LDS, fused fp32 es/ed ----------------
// Smaller tile -> 2x blocks (≈10/CU) so barrier drains overlap across more independent waves.
// Per-element K-accumulation order identical to the 128x128 version (bit-identical output).
__global__ __launch_bounds__(256) void k_gemm_mfma(
    const bf16* __restrict__ X, const bf16* __restrict__ Wt, bf16* __restrict__ Y,
    const float* __restrict__ as_, const float* __restrict__ ad_,
    float* __restrict__ es, float* __restrict__ ed,
    int K, int M, int C, int H)
{
  __shared__ bf16 Xs[64*64];    // 8 KB
  __shared__ bf16 Bs[128*64];   // 16 KB
  int ncols = gridDim.x;
  int bid = blockIdx.y * ncols + blockIdx.x;
  int xcd  = bid & 7;
  int rest = bid >> 3;
  int colb = rest % ncols;
  int rowb = xcd + 8 * (rest / ncols);
  int r0 = rowb * 64;
  if (r0 >= NN) return;
  int c0 = colb * 128;

  int tid  = threadIdx.x;
  int wave = tid >> 6, lane = tid & 63;
  int quad = lane >> 4, l15 = lane & 15;
  int wr = (wave >> 1) * 32;     // 2 row-groups of 32
  int wc = (wave & 1) * 64;      // 2 col-groups of 64
  int sw = l15 & 7;

  float4v acc[2][4];
  #pragma unroll
  for (int i=0;i<2;i++)
    #pragma unroll
    for (int j=0;j<4;j++)
      acc[i][j] = (float4v){0.f,0.f,0.f,0.f};

  for (int k0 = 0; k0 < K; k0 += 64){
    #pragma unroll
    for (int i = 0; i < 2; i++){            // Xs: 512 chunks of 16B
      int ch = i*256 + tid;
      int row = ch >> 3, kl = ch & 7;
      int kg = kl ^ (row & 7);
      const bf16* gx = X + (size_t)(r0 + row)*K + k0 + kg*8;
      __builtin_amdgcn_global_load_lds(
        (const __attribute__((address_space(1))) unsigned int*)gx,
        (__attribute__((address_space(3))) unsigned int*)(Xs + ch*8), 16, 0, 0);
    }
    #pragma unroll
    for (int i = 0; i < 4; i++){            // Bs: 1024 chunks of 16B
      int ch = i*256 + tid;
      int row = ch >> 3, kl = ch & 7;
      int kg = kl ^ (row & 7);
      const bf16* gb = Wt + (size_t)(c0 + row)*K + k0 + kg*8;
      __builtin_amdgcn_global_load_lds(
        (const __attribute__((address_space(1))) unsigned int*)gb,
        (__attribute__((address_space(3))) unsigned int*)(Bs + ch*8), 16, 0, 0);
    }
    __syncthreads();

    #pragma unroll
    for (int kk = 0; kk < 2; kk++){         // two 32-wide K slices, in order (bit-identical accum)
      int kp = quad + kk*4;
      short8 af[2], bfr[4];
      #pragma unroll
      for (int i = 0; i < 2; i++){
        int r = wr + i*16 + l15;
        af[i] = *(const short8*)(Xs + ((size_t)r*8 + (kp ^ sw))*8);
      }
      #pragma unroll
      for (int j = 0; j < 4; j++){
        int r = wc + j*16 + l15;
        bfr[j] = *(const short8*)(Bs + ((size_t)r*8 + (kp ^ sw))*8);
      }
      #pragma unroll
      for (int i = 0; i < 2; i++)
        #pragma unroll
        for (int j = 0; j < 4; j++)
          acc[i][j] = __builtin_amdgcn_mfma_f32_16x16x32_bf16(af[i], bfr[j], acc[i][j], 0, 0, 0);
    }
    __syncthreads();
  }

  int h = c0 / C;
  float asv[4], adv[4];
  #pragma unroll
  for (int j = 0; j < 4; j++){
    int colj = c0 + wc + j*16 + l15;
    asv[j] = as_[colj]; adv[j] = ad_[colj];
  }
  #pragma unroll
  for (int i = 0; i < 2; i++){
    int rbase = r0 + wr + i*16 + quad*4;
    #pragma unroll
    for (int rg = 0; rg < 4; rg++){
      int row = rbase + rg;
      bool ok = (row < NN);
      float pe = 0.f, pd = 0.f;
      #pragma unroll
      for (int j = 0; j < 4; j++){
        float v = acc[i][j][rg];
        int colj = c0 + wc + j*16 + l15;
        if (ok) Y[(size_t)row*M + colj] = __float2bfloat16(v);
        pe += v * asv[j];
        pd += v * adv[j];
      }
      #pragma unroll
      for (int o = 1; o < 16; o <<= 1){
        pe += __shfl_xor(pe, o, 64);
        pd += __shfl_xor(pd, o, 64);
      }
      if (ok && l15 == 0){
        atomicAdd(&es[row*H + h], pe);
        atomicAdd(&ed[row*H + h], pd);
      }
    }
  }
}

// ---------------- wave-per-node softmax+aggregate+bias+LN+ELU (layers 1,2; H=4) ----------------
__global__ __launch_bounds__(256) void k_aggln(const int* __restrict__ rp, const int* __restrict__ col,
    const bf16* __restrict__ xw, const float* __restrict__ es, const float* __restrict__ ed,
    const float* __restrict__ bias, const float* __restrict__ gam, const float* __restrict__ bet,
    bf16* __restrict__ act, float* __restrict__ esz, float* __restrict__ edz, int zn){
  int wv = threadIdx.x >> 6, lane = threadIdx.x & 63;
  int n = blockIdx.x*4 + wv;              // NN % 4 == 0
  int h = lane >> 4;
  int cb = lane * 16;
  int e0 = rp[n], e1 = rp[n+1], deg = e1 - e0;
  float4 ed4 = *(const float4*)&ed[n*4];
  const unsigned short* xwu = (const unsigned short*)xw;

  float acc[16];
  #pragma unroll
  for (int c=0;c<16;c++) acc[c]=0.f;

  if (deg <= 64){
    int src = 0;
    float l0=-1e30f, l1=-1e30f, l2=-1e30f, l3=-1e30f;
    if (lane < deg){
      src = col[e0 + lane];
      float4 e4 = *(const float4*)&es[src*4];
      float v;
      v = e4.x + ed4.x; l0 = v > 0.f ? v : 0.2f*v;
      v = e4.y + ed4.y; l1 = v > 0.f ? v : 0.2f*v;
      v = e4.z + ed4.z; l2 = v > 0.f ? v : 0.2f*v;
      v = e4.w + ed4.w; l3 = v > 0.f ? v : 0.2f*v;
    }
    float m0=l0, m1=l1, m2=l2, m3=l3;
    #pragma unroll
    for (int o=1;o<64;o<<=1){
      m0 = fmaxf(m0, __shfl_xor(m0,o,64));
      m1 = fmaxf(m1, __shfl_xor(m1,o,64));
      m2 = fmaxf(m2, __shfl_xor(m2,o,64));
      m3 = fmaxf(m3, __shfl_xor(m3,o,64));
    }
    float p0 = (lane<deg) ? __expf(l0-m0) : 0.f;
    float p1 = (lane<deg) ? __expf(l1-m1) : 0.f;
    float p2 = (lane<deg) ? __expf(l2-m2) : 0.f;
    float p3 = (lane<deg) ? __expf(l3-m3) : 0.f;
    float d0=p0, d1=p1, d2=p2, d3=p3;
    #pragma unroll
    for (int o=1;o<64;o<<=1){
      d0 += __shfl_xor(d0,o,64);
      d1 += __shfl_xor(d1,o,64);
      d2 += __shfl_xor(d2,o,64);
      d3 += __shfl_xor(d3,o,64);
    }
    float al0 = p0 * (1.f/(d0+1e-16f));
    float al1 = p1 * (1.f/(d1+1e-16f));
    float al2 = p2 * (1.f/(d2+1e-16f));
    float al3 = p3 * (1.f/(d3+1e-16f));

    int j = 0;
    for (; j + 2 <= deg; j += 2){
      int sA = __shfl(src, j, 64);
      int sB = __shfl(src, j+1, 64);
      float a0A = __shfl(al0, j, 64), a1A = __shfl(al1, j, 64);
      float a2A = __shfl(al2, j, 64), a3A = __shfl(al3, j, 64);
      float a0B = __shfl(al0, j+1, 64), a1B = __shfl(al1, j+1, 64);
      float a2B = __shfl(al2, j+1, 64), a3B = __shfl(al3, j+1, 64);
      float aA = (h==0) ? a0A : ((h==1) ? a1A : ((h==2) ? a2A : a3A));
      float aB = (h==0) ? a0B : ((h==1) ? a1B : ((h==2) ? a2B : a3B));
      const unsigned short* rA = xwu + (size_t)sA*1024 + cb;
      const unsigned short* rB = xwu + (size_t)sB*1024 + cb;
      ushort4 uA0 = *(const ushort4*)(rA);
      ushort4 uA1 = *(const ushort4*)(rA+4);
      ushort4 uA2 = *(const ushort4*)(rA+8);
      ushort4 uA3 = *(const ushort4*)(rA+12);
      ushort4 uB0 = *(const ushort4*)(rB);
      ushort4 uB1 = *(const ushort4*)(rB+4);
      ushort4 uB2 = *(const ushort4*)(rB+8);
      ushort4 uB3 = *(const ushort4*)(rB+12);
      acc[0] += aA*raw2f(uA0.x); acc[1] += aA*raw2f(uA0.y); acc[2] += aA*raw2f(uA0.z); acc[3] += aA*raw2f(uA0.w);
      acc[4] += aA*raw2f(uA1.x); acc[5] += aA*raw2f(uA1.y); acc[6] += aA*raw2f(uA1.z); acc[7] += aA*raw2f(uA1.w);
      acc[8] += aA*raw2f(uA2.x); acc[9] += aA*raw2f(uA2.y); acc[10]+= aA*raw2f(uA2.z); acc[11]+= aA*raw2f(uA2.w);
      acc[12]+= aA*raw2f(uA3.x); acc[13]+= aA*raw2f(uA3.y); acc[14]+= aA*raw2f(uA3.z); acc[15]+= aA*raw2f(uA3.w);
      acc[0] += aB*raw2f(uB0.x); acc[1] += aB*raw2f(uB0.y); acc[2] += aB*raw2f(uB0.z); acc[3] += aB*raw2f(uB0.w);
      acc[4] += aB*raw2f(uB1.x); acc[5] += aB*raw2f(uB1.y); acc[6] += aB*raw2f(uB1.z); acc[7] += aB*raw2f(uB1.w);
      acc[8] += aB*raw2f(uB2.x); acc[9] += aB*raw2f(uB2.y); acc[10]+= aB*raw2f(uB2.z); acc[11]+= aB*raw2f(uB2.w);
      acc[12]+= aB*raw2f(uB3.x); acc[13]+= aB*raw2f(uB3.y); acc[14]+= aB*raw2f(uB3.z); acc[15]+= aB*raw2f(uB3.w);
    }
    for (; j < deg; j++){
      int s = __shfl(src, j, 64);
      float a0j = __shfl(al0, j, 64);
      float a1j = __shfl(al1, j, 64);
      float a2j = __shfl(al2, j, 64);
      float a3j = __shfl(al3, j, 64);
      float aj = (h==0) ? a0j : ((h==1) ? a1j : ((h==2) ? a2j : a3j));
      const unsigned short* row = xwu + (size_t)s*1024 + cb;
      ushort4 u0 = *(const ushort4*)(row);
      ushort4 u1 = *(const ushort4*)(row+4);
      ushort4 u2 = *(const ushort4*)(row+8);
      ushort4 u3 = *(const ushort4*)(row+12);
      acc[0] += aj*raw2f(u0.x); acc[1] += aj*raw2f(u0.y); acc[2] += aj*raw2f(u0.z); acc[3] += aj*raw2f(u0.w);
      acc[4] += aj*raw2f(u1.x); acc[5] += aj*raw2f(u1.y); acc[6] += aj*raw2f(u1.z); acc[7] += aj*raw2f(u1.w);
      acc[8] += aj*raw2f(u2.x); acc[9] += aj*raw2f(u2.y); acc[10]+= aj*raw2f(u2.z); acc[11]+= aj*raw2f(u2.w);
      acc[12]+= aj*raw2f(u3.x); acc[13]+= aj*raw2f(u3.y); acc[14]+= aj*raw2f(u3.z); acc[15]+= aj*raw2f(u3.w);
    }
  } else {
    float edh = (h==0) ? ed4.x : ((h==1) ? ed4.y : ((h==2) ? ed4.z : ed4.w));
    float m = -1e30f;
    for (int e=e0;e<e1;e++){
      float v = es[col[e]*4 + h] + edh;
      v = v > 0.f ? v : 0.2f*v;
      m = fmaxf(m, v);
    }
    float den = 0.f;
    for (int e=e0;e<e1;e++){
      float v = es[col[e]*4 + h] + edh;
      v = v > 0.f ? v : 0.2f*v;
      den += __expf(v - m);
    }
    float rd = 1.f/(den + 1e-16f);
    for (int e=e0;e<e1;e++){
      int s = col[e];
      float v = es[s*4 + h] + edh;
      v = v > 0.f ? v : 0.2f*v;
      float aj = __expf(v - m) * rd;
      const unsigned short* row = xwu + (size_t)s*1024 + cb;
      ushort4 u0 = *(const ushort4*)(row);
      ushort4 u1 = *(const ushort4*)(row+4);
      ushort4 u2 = *(const ushort4*)(row+8);
      ushort4 u3 = *(const ushort4*)(row+12);
      acc[0] += aj*raw2f(u0.x); acc[1] += aj*raw2f(u0.y); acc[2] += aj*raw2f(u0.z); acc[3] += aj*raw2f(u0.w);
      acc[4] += aj*raw2f(u1.x); acc[5] += aj*raw2f(u1.y); acc[6] += aj*raw2f(u1.z); acc[7] += aj*raw2f(u1.w);
      acc[8] += aj*raw2f(u2.x); acc[9] += aj*raw2f(u2.y); acc[10]+= aj*raw2f(u2.z); acc[11]+= aj*raw2f(u2.w);
      acc[12]+= aj*raw2f(u3.x); acc[13]+= aj*raw2f(u3.y); acc[14]+= aj*raw2f(u3.z); acc[15]+= aj*raw2f(u3.w);
    }
  }

  #pragma unroll
  for (int c=0;c<16;c++) acc[c] += bias[cb+c];
  float s1 = 0.f, s2 = 0.f;
  #pragma unroll
  for (int c=0;c<16;c++){ s1 += acc[c]; s2 += acc[c]*acc[c]; }
  #pragma unroll
  for (int o=1;o<64;o<<=1){
    s1 += __shfl_xor(s1,o,64);
    s2 += __shfl_xor(s2,o,64);
  }
  float mu  = s1 * (1.f/1024.f);
  float var = s2 * (1.f/1024.f) - mu*mu;
  float rstd = rsqrtf(fmaxf(var, 0.f) + 1e-5f);

  ushort4 o4[4];
  #pragma unroll
  for (int q=0;q<4;q++){
    float v0 = (acc[q*4+0]-mu)*rstd*gam[cb+q*4+0] + bet[cb+q*4+0];
    float v1 = (acc[q*4+1]-mu)*rstd*gam[cb+q*4+1] + bet[cb+q*4+1];
    float v2 = (acc[q*4+2]-mu)*rstd*gam[cb+q*4+2] + bet[cb+q*4+2];
    float v3 = (acc[q*4+3]-mu)*rstd*gam[cb+q*4+3] + bet[cb+q*4+3];
    v0 = v0 > 0.f ? v0 : (__expf(v0)-1.f);
    v1 = v1 > 0.f ? v1 : (__expf(v1)-1.f);
    v2 = v2 > 0.f ? v2 : (__expf(v2)-1.f);
    v3 = v3 > 0.f ? v3 : (__expf(v3)-1.f);
    o4[q].x = f2raw(v0); o4[q].y = f2raw(v1); o4[q].z = f2raw(v2); o4[q].w = f2raw(v3);
  }
  unsigned short* dst = (unsigned short*)act + (size_t)n*1024 + cb;
  *(ushort4*)(dst)    = o4[0];
  *(ushort4*)(dst+4)  = o4[1];
  *(ushort4*)(dst+8)  = o4[2];
  *(ushort4*)(dst+12) = o4[3];

  // zero next layer's logit slots for this node (exclusive ownership; read next dispatch)
  if (lane < zn){ esz[n*zn + lane] = 0.f; edz[n*zn + lane] = 0.f; }
}

// ---------------- wave-per-node layer-3: softmax + aggregate + bias -> fp32 out (H=1) ----------------
__global__ __launch_bounds__(256) void k_agg3(const int* __restrict__ rp, const int* __restrict__ col,
    const bf16* __restrict__ xw, const float* __restrict__ es, const float* __restrict__ ed,
    const float* __restrict__ bias, float* __restrict__ out){
  int wv = threadIdx.x >> 6, lane = threadIdx.x & 63;
  int n = blockIdx.x*4 + wv;
  int cb = lane * 8;
  int e0 = rp[n], e1 = rp[n+1], deg = e1 - e0;
  float edv = ed[n];
  const unsigned short* xwu = (const unsigned short*)xw;

  float acc[8];
  #pragma unroll
  for (int c=0;c<8;c++) acc[c]=0.f;

  if (deg <= 64){
    int src = 0;
    float l = -1e30f;
    if (lane < deg){
      src = col[e0 + lane];
      float v = es[src] + edv;
      l = v > 0.f ? v : 0.2f*v;
    }
    float m = l;
    #pragma unroll
    for (int o=1;o<64;o<<=1) m = fmaxf(m, __shfl_xor(m,o,64));
    float p = (lane<deg) ? __expf(l-m) : 0.f;
    float d = p;
    #pragma unroll
    for (int o=1;o<64;o<<=1) d += __shfl_xor(d,o,64);
    float al = p * (1.f/(d+1e-16f));

    int j = 0;
    for (; j + 2 <= deg; j += 2){
      int sA = __shfl(src, j, 64);
      int sB = __shfl(src, j+1, 64);
      float aA = __shfl(al, j, 64);
      float aB = __shfl(al, j+1, 64);
      const unsigned short* rA = xwu + (size_t)sA*512 + cb;
      const unsigned short* rB = xwu + (size_t)sB*512 + cb;
      ushort4 uA0 = *(const ushort4*)(rA);
      ushort4 uA1 = *(const ushort4*)(rA+4);
      ushort4 uB0 = *(const ushort4*)(rB);
      ushort4 uB1 = *(const ushort4*)(rB+4);
      acc[0] += aA*raw2f(uA0.x); acc[1] += aA*raw2f(uA0.y); acc[2] += aA*raw2f(uA0.z); acc[3] += aA*raw2f(uA0.w);
      acc[4] += aA*raw2f(uA1.x); acc[5] += aA*raw2f(uA1.y); acc[6] += aA*raw2f(uA1.z); acc[7] += aA*raw2f(uA1.w);
      acc[0] += aB*raw2f(uB0.x); acc[1] += aB*raw2f(uB0.y); acc[2] += aB*raw2f(uB0.z); acc[3] += aB*raw2f(uB0.w);
      acc[4] += aB*raw2f(uB1.x); acc[5] += aB*raw2f(uB1.y); acc[6] += aB*raw2f(uB1.z); acc[7] += aB*raw2f(uB1.w);
    }
    for (; j < deg; j++){
      int s = __shfl(src, j, 64);
      float aj = __shfl(al, j, 64);
      const unsigned short* row = xwu + (size_t)s*512 + cb;
      ushort4 u0 = *(const ushort4*)(row);
      ushort4 u1 = *(const ushort4*)(row+4);
      acc[0] += aj*raw2f(u0.x); acc[1] += aj*raw2f(u0.y); acc[2] += aj*raw2f(u0.z); acc[3] += aj*raw2f(u0.w);
      acc[4] += aj*raw2f(u1.x); acc[5] += aj*raw2f(u1.y); acc[6] += aj*raw2f(u1.z); acc[7] += aj*raw2f(u1.w);
    }
  } else {
    float m = -1e30f;
    for (int e=e0;e<e1;e++){
      float v = es[col[e]] + edv;
      v = v > 0.f ? v : 0.2f*v;
      m = fmaxf(m, v);
    }
    float den = 0.f;
    for (int e=e0;e<e1;e++){
      float v = es[col[e]] + edv;
      v = v > 0.f ? v : 0.2f*v;
      den += __expf(v - m);
    }
    float rd = 1.f/(den + 1e-16f);
    for (int e=e0;e<e1;e++){
      int s = col[e];
      float v = es[s] + edv;
      v = v > 0.f ? v : 0.2f*v;
      float aj = __expf(v - m) * rd;
      const unsigned short* row = xwu + (size_t)s*512 + cb;
      ushort4 u0 = *(const ushort4*)(row);
      ushort4 u1 = *(const ushort4*)(row+4);
      acc[0] += aj*raw2f(u0.x); acc[1] += aj*raw2f(u0.y); acc[2] += aj*raw2f(u0.z); acc[3] += aj*raw2f(u0.w);
      acc[4] += aj*raw2f(u1.x); acc[5] += aj*raw2f(u1.y); acc[6] += aj*raw2f(u1.z); acc[7] += aj*raw2f(u1.w);
    }
  }
  float* dst = out + (size_t)n*512 + cb;
  #pragma unroll
  for (int c=0;c<8;c++) dst[c] = acc[c] + bias[cb+c];
}

__global__ void k_wssmall(float* __restrict__ out, float code){
  if (threadIdx.x == 0) out[0] = code;
}

// ---------------- launch ----------------
extern "C" void kernel_launch(void* const* d_in, const int* in_sizes, int n_in,
                              void* d_out, int out_size, void* d_ws, size_t ws_size,
                              hipStream_t stream){
  float* out = (float*)d_out;
  char* ws = (char*)d_ws;

  static const int EXP_SZ[18] = {2560000, 320000, 131072, 1024,1024,1024,1024,1024,
                                 1048576, 1024,1024,1024,1024,1024,
                                 524288, 512,512,512};
  if (n_in != 18){ k_wssmall<<<1,64,0,stream>>>(out, 500.0f*301.0f); return; }
  for (int i = 0; i < 18; i++)
    if (in_sizes[i] != EXP_SZ[i]){ k_wssmall<<<1,64,0,stream>>>(out, 500.0f*302.0f); return; }
  if (out_size != NN*512){ k_wssmall<<<1,64,0,stream>>>(out, 500.0f*303.0f); return; }
  const size_t NEED = 93215360;
  if (ws_size < NEED){ k_wssmall<<<1,64,0,stream>>>(out, 500.0f*304.0f); return; }

  // ---- workspace layout ----
  bf16* xw    = (bf16*) (ws);                    // 40,960,000 (first 80KB doubles as CSR 'counts')
  int*  cnt   = (int*)  (ws);                    // aliases xw: counts, live prep->scan
  bf16* act   = (bf16*) (ws + 40960000);         // -> 81,920,000 (first 80KB doubles as CSR 'cursor')
  int*  cursor= (int*)  (ws + 40960000);         // aliases act: live scan->scatter
  bf16* Xc    = (bf16*) (ws + 81920000);         // -> 87,040,000 (dead after gemm1)
  float* esC  = (float*)(ws + 81920000);         // aliases Xc: 80,000 B (layer-3 logits, H=1)
  float* edC  = (float*)(ws + 82000000);         // aliases Xc: 80,000 B
  bf16* Wt1   = (bf16*) (ws + 87040000);         // -> 87,302,144
  bf16* Wt2   = (bf16*) (ws + 87302144);         // -> 89,399,296
  bf16* Wt3   = (bf16*) (ws + 89399296);         // -> 90,447,872
  float* prm  = (float*)(ws + 90447872);         // -> 90,494,976
  int*  eic   = (int*)  (ws + 90495232);         // -> 91,775,232 (dead after scatter)
  float* esB  = (float*)(ws + 90495232);         // aliases eic: 320,000 B (layer-2 logits)
  float* edB  = (float*)(ws + 90815232);         // aliases eic: 320,000 B
  float* esA  = (float*)(ws + 91775232);         // -> 92,095,232 (layer-1 logits)
  float* edA  = (float*)(ws + 92095232);         // -> 92,415,232
  int*  rp    = (int*)  (ws + 92415232);         // -> 92,495,360
  int*  col   = (int*)  (ws + 92495360);         // -> 93,215,360

  float *as1=prm+0, *ad1=prm+1024, *b1=prm+2048, *lg1=prm+3072, *lb1=prm+4096;
  float *as2=prm+5120, *ad2=prm+6144, *b2=prm+7168, *lg2=prm+8192, *lb2=prm+9216;
  float *as3=prm+10240, *ad3=prm+10752, *b3=prm+11264;

  const int TB = 256;
  int gbE = (EE + TB - 1)/TB;

  // ---- fused prep ----
  {
    PrepArgs A;
    A.xraw = d_in[0]; A.Xc = Xc;
    A.w1raw = d_in[2]; A.Wt1 = Wt1;
    A.w2raw = d_in[8]; A.Wt2 = Wt2;
    A.w3raw = d_in[14]; A.Wt3 = Wt3;
    A.eiraw = (const int*)d_in[1]; A.eic = eic;
    const int idx[13] = {3,4,5,6,7, 9,10,11,12,13, 15,16,17};
    const int off[13] = {0,1024,2048,3072,4096, 5120,6144,7168,8192,9216, 10240,10752,11264};
    const int nn [13] = {1024,1024,1024,1024,1024, 1024,1024,1024,1024,1024, 512,512,512};
    for (int i=0;i<13;i++){ A.p13.src[i]=d_in[idx[i]]; A.p13.off[i]=off[i]; A.p13.n[i]=nn[i]; }
    A.prm = prm; A.counts = cnt; A.esA = esA; A.edA = edA;
    k_prep<<<13006 + 313, TB, 0, stream>>>(A);
  }

  // ---- CSR ----
  k_hist<<<gbE, TB, 0, stream>>>(eic, cnt);
  k_scan<<<1, 1024, 0, stream>>>(cnt, rp, cursor, col);
  k_scatter<<<gbE, TB, 0, stream>>>(eic, cursor, col);

  const int RB = (NN + 63)/64;                    // 313 row-bands of 64
  const int R8 = ((RB + 7)/8)*8;                  // 320 (padded, guard in kernel)
  dim3 g12(1024/128, R8);
  dim3 g3 (512/128,  R8);

  // ---- layer 1 (K=128) ----
  k_gemm_mfma<<<g12, TB, 0, stream>>>(Xc, Wt1, xw, as1, ad1, esA, edA, 128, 1024, 256, 4);
  k_aggln<<<NN/4, TB, 0, stream>>>(rp, col, xw, esA, edA, b1, lg1, lb1, act, esB, edB, 4);

  // ---- layer 2 (K=1024) ----
  k_gemm_mfma<<<g12, TB, 0, stream>>>(act, Wt2, xw, as2, ad2, esB, edB, 1024, 1024, 256, 4);
  k_aggln<<<NN/4, TB, 0, stream>>>(rp, col, xw, esB, edB, b2, lg2, lb2, act, esC, edC, 1);

  // ---- layer 3 (K=1024, M=512) ----
  k_gemm_mfma<<<g3, TB, 0, stream>>>(act, Wt3, xw, as3, ad3, esC, edC, 1024, 512, 512, 1);
  k_agg3<<<NN/4, TB, 0, stream>>>(rp, col, xw, esC, edC, b3, out);
}